// Round 10
// baseline (923.315 us; speedup 1.0000x reference)
//
#include <hip/hip_runtime.h>
#include <hip/hip_bf16.h>

#define BEPS 1e-5f
#define FC1_KS 98
#define FC1_KC 256
#define C1NB 2017

typedef __attribute__((ext_vector_type(8))) short short8v;
typedef __attribute__((ext_vector_type(4))) float f32x4;
typedef unsigned short ushort_t;

__device__ __forceinline__ float bf2f(ushort_t u) {
    unsigned int x = ((unsigned int)u) << 16;
    return __builtin_bit_cast(float, x);
}
__device__ __forceinline__ ushort_t f2bf(float v) {
    __hip_bfloat16 h = __float2bfloat16(v);
    return *(ushort_t*)&h;
}

// ---------------- conv1: direct fp32, NHWC bf16 out -------------------------
// out[(b*16129+pp)*32 + co]
__global__ __launch_bounds__(256) void conv1_direct(
    const float* __restrict__ in, const float* __restrict__ w,
    const float* __restrict__ bias, ushort_t* __restrict__ out) {
    __shared__ float ws[864];
    __shared__ float bs[32];
    const int tid = threadIdx.x;
    for (int i = tid; i < 864; i += 256) ws[i] = w[i];
    if (tid < 32) bs[tid] = bias[tid];
    __syncthreads();

    const int TOT = 32 * 16129;
    int p = blockIdx.x * 256 + tid;
    if (p >= TOT) return;
    int b = p / 16129, pp = p - b * 16129;
    int i = pp / 127, j = pp - i * 127;
    const float* ib = in + ((long long)b * 3) * 65536 + (2 * i) * 256 + 2 * j;
    float patch[27];
#pragma unroll
    for (int ci = 0; ci < 3; ++ci)
#pragma unroll
        for (int di = 0; di < 3; ++di) {
            const float* rp = ib + ci * 65536 + di * 256;
            float2 v01 = *(const float2*)rp;
            patch[ci * 9 + di * 3 + 0] = v01.x;
            patch[ci * 9 + di * 3 + 1] = v01.y;
            patch[ci * 9 + di * 3 + 2] = rp[2];
        }

    ushort_t res[32];
#pragma unroll
    for (int co = 0; co < 32; co += 4) {
        float a0 = bs[co], a1 = bs[co + 1], a2 = bs[co + 2], a3 = bs[co + 3];
#pragma unroll
        for (int t = 0; t < 27; ++t) {
            float pv = patch[t];
            a0 = fmaf(pv, ws[(co + 0) * 27 + t], a0);
            a1 = fmaf(pv, ws[(co + 1) * 27 + t], a1);
            a2 = fmaf(pv, ws[(co + 2) * 27 + t], a2);
            a3 = fmaf(pv, ws[(co + 3) * 27 + t], a3);
        }
        res[co + 0] = f2bf(fmaxf(a0, 0.f));
        res[co + 1] = f2bf(fmaxf(a1, 0.f));
        res[co + 2] = f2bf(fmaxf(a2, 0.f));
        res[co + 3] = f2bf(fmaxf(a3, 0.f));
    }
    ushort_t* ob = out + (long long)p * 32;
#pragma unroll
    for (int v = 0; v < 4; ++v)
        *(short8v*)&ob[v * 8] = *(const short8v*)&res[v * 8];
}

// ---------------- convs 2-5: NHWC bf16 MFMA implicit GEMM -------------------
// act layout [pix][Ci]; weights [co][Kp] with k = tap*Ci+ci (pad zeros).
// block tile 64co x 128px x K64; LDS XOR-swizzled; 4 waves = 2co x 2px.
__global__ __launch_bounds__(256) void conv_mfma(
    const ushort_t* __restrict__ in, const ushort_t* __restrict__ wf,
    const float* __restrict__ effb, ushort_t* __restrict__ out,
    float* __restrict__ pacc,
    int B, int Ci, int lgCi, int Hi, int Wi, int Co, int Ho, int Wo,
    int K, int Kp, int kcount) {
    const int HoWo = Ho * Wo;
    const int N = B * HoWo;
    __shared__ __align__(16) ushort_t As[64 * 64];
    __shared__ __align__(16) ushort_t Bs[128 * 64];
    const int tid = threadIdx.x;
    const int m0 = blockIdx.y * 64;
    const int n0 = blockIdx.x * 128;
    const int kbeg = blockIdx.z * kcount;

    // A staging: 64 rows x 4 thr x 16 k
    const int rowA = tid >> 2;
    const int kqA = (tid & 3) * 16;
    const ushort_t* wrowA = wf + (long long)(m0 + rowA) * Kp + kbeg + kqA;
    const int swA = (rowA & 7) << 3;
    // B staging: 128 rows x 2 thr x 32 k
    const int rowB = tid >> 1;
    const int kqB = (tid & 1) * 32;
    const int n = n0 + rowB;
    const int nn = (n < N) ? n : (N - 1);
    const int pb = nn / HoWo, pp = nn - pb * HoWo;
    const int pi = pp / Wo, pj = pp - pi * Wo;
    const long long base0 = ((long long)pb * Hi + 2 * pi) * Wi + 2 * pj;
    const int swB = (rowB & 7) << 3;

    const int w = tid >> 6;
    const int lane = tid & 63;
    const int wco = (w >> 1) * 32, wpx = (w & 1) * 64;
    const int lm = lane & 15, lk = lane >> 4;

    f32x4 acc[2][4] = {};
    for (int k0 = 0; k0 < kcount; k0 += 64) {
        // stage A: two 16B vector loads -> swizzled LDS
        {
            short8v a0 = *(const short8v*)(wrowA + k0);
            short8v a1 = *(const short8v*)(wrowA + k0 + 8);
            *(short8v*)&As[rowA * 64 + ((kqA + 0) ^ swA)] = a0;
            *(short8v*)&As[rowA * 64 + ((kqA + 8) ^ swA)] = a1;
        }
        // stage B: 2 chunks of 16 contiguous k (= contiguous ci at one tap)
#pragma unroll
        for (int ch = 0; ch < 2; ++ch) {
            int c16 = kqB + ch * 16;
            int kg = kbeg + k0 + c16;
            int tap = kg >> lgCi;
            tap = tap > 8 ? 8 : tap;
            int ci0 = kg & (Ci - 1);
            int dy = tap / 3, dx = tap - dy * 3;
            const ushort_t* src = in + (base0 + dy * Wi + dx) * Ci + ci0;
            short8v v0 = *(const short8v*)src;
            short8v v1 = *(const short8v*)(src + 8);
            *(short8v*)&Bs[rowB * 64 + ((c16 + 0) ^ swB)] = v0;
            *(short8v*)&Bs[rowB * 64 + ((c16 + 8) ^ swB)] = v1;
        }
        __syncthreads();
#pragma unroll
        for (int kk = 0; kk < 2; ++kk) {
            const int kb = kk * 32 + lk * 8;
            const int ra0 = wco + lm, ra1 = wco + 16 + lm;
            short8v a0 = *(const short8v*)&As[ra0 * 64 + (kb ^ ((ra0 & 7) << 3))];
            short8v a1 = *(const short8v*)&As[ra1 * 64 + (kb ^ ((ra1 & 7) << 3))];
            const int rb0 = wpx + lm, rb1 = wpx + 16 + lm;
            const int rb2 = wpx + 32 + lm, rb3 = wpx + 48 + lm;
            short8v b0 = *(const short8v*)&Bs[rb0 * 64 + (kb ^ ((rb0 & 7) << 3))];
            short8v b1 = *(const short8v*)&Bs[rb1 * 64 + (kb ^ ((rb1 & 7) << 3))];
            short8v b2 = *(const short8v*)&Bs[rb2 * 64 + (kb ^ ((rb2 & 7) << 3))];
            short8v b3 = *(const short8v*)&Bs[rb3 * 64 + (kb ^ ((rb3 & 7) << 3))];
            acc[0][0] = __builtin_amdgcn_mfma_f32_16x16x32_bf16(a0, b0, acc[0][0], 0, 0, 0);
            acc[0][1] = __builtin_amdgcn_mfma_f32_16x16x32_bf16(a0, b1, acc[0][1], 0, 0, 0);
            acc[0][2] = __builtin_amdgcn_mfma_f32_16x16x32_bf16(a0, b2, acc[0][2], 0, 0, 0);
            acc[0][3] = __builtin_amdgcn_mfma_f32_16x16x32_bf16(a0, b3, acc[0][3], 0, 0, 0);
            acc[1][0] = __builtin_amdgcn_mfma_f32_16x16x32_bf16(a1, b0, acc[1][0], 0, 0, 0);
            acc[1][1] = __builtin_amdgcn_mfma_f32_16x16x32_bf16(a1, b1, acc[1][1], 0, 0, 0);
            acc[1][2] = __builtin_amdgcn_mfma_f32_16x16x32_bf16(a1, b2, acc[1][2], 0, 0, 0);
            acc[1][3] = __builtin_amdgcn_mfma_f32_16x16x32_bf16(a1, b3, acc[1][3], 0, 0, 0);
        }
        __syncthreads();
    }
    // D: col(lane&15)=pixel, row((lane>>4)*4+r)=co. NHWC out[(np)*Co + co].
    if (pacc) {
        float* pbuf = pacc + ((long long)blockIdx.z * N) * Co;
#pragma unroll
        for (int nb = 0; nb < 4; ++nb) {
            int np = n0 + wpx + nb * 16 + lm;
            if (np >= N) continue;
#pragma unroll
            for (int amr = 0; amr < 2; ++amr) {
                int cobase = m0 + wco + amr * 16 + lk * 4;
                float4 vv = make_float4(acc[amr][nb][0], acc[amr][nb][1],
                                        acc[amr][nb][2], acc[amr][nb][3]);
                *(float4*)&pbuf[(long long)np * Co + cobase] = vv;
            }
        }
    } else {
#pragma unroll
        for (int nb = 0; nb < 4; ++nb) {
            int np = n0 + wpx + nb * 16 + lm;
            if (np >= N) continue;
#pragma unroll
            for (int amr = 0; amr < 2; ++amr) {
                int cobase = m0 + wco + amr * 16 + lk * 4;
                float4 eb = *(const float4*)&effb[cobase];
                ushort4 u;
                u.x = f2bf(fmaxf(acc[amr][nb][0] + eb.x, 0.f));
                u.y = f2bf(fmaxf(acc[amr][nb][1] + eb.y, 0.f));
                u.z = f2bf(fmaxf(acc[amr][nb][2] + eb.z, 0.f));
                u.w = f2bf(fmaxf(acc[amr][nb][3] + eb.w, 0.f));
                *(ushort4*)&out[(long long)np * Co + cobase] = u;
            }
        }
    }
}

// reduce K-split fp32 partials + bias + relu -> NHWC bf16
__global__ void convz_reduce(const float* __restrict__ pacc, const float* __restrict__ effb,
                             ushort_t* __restrict__ out, int N, int Co, int lgCo, int Z,
                             int total) {
    int idx = blockIdx.x * 256 + threadIdx.x;
    if (idx >= total) return;
    int c = idx & (Co - 1);
    float s = effb[c];
    for (int z = 0; z < Z; ++z) s += pacc[((long long)z * N << lgCo) + idx];
    out[idx] = f2bf(fmaxf(s, 0.f));
}

// ---------------- BN stats, NHWC coalesced ----------------------------------
__global__ __launch_bounds__(256) void stats_nhwc(
    const ushort_t* __restrict__ y, float* __restrict__ part,
    long long P, int C, int S, int lgCW) {
    const int CW = 1 << lgCW;
    const int PS = 256 >> lgCW;
    const int c0 = blockIdx.x << lgCW;
    const int s = blockIdx.y;
    const int tid = threadIdx.x;
    const int cl = tid & (CW - 1);
    const int ps = tid >> lgCW;
    const int c = c0 + cl;
    float sum = 0.f, sq = 0.f;
    for (long long p = (long long)s * PS + ps; p < P; p += (long long)S * PS) {
        float v = bf2f(y[p * C + c]);
        sum += v;
        sq = fmaf(v, v, sq);
    }
    __shared__ float ls[256], lq[256];
    ls[tid] = sum; lq[tid] = sq;
    __syncthreads();
    for (int o = 128; o >= CW; o >>= 1) {
        if (tid < o) { ls[tid] += ls[tid + o]; lq[tid] += lq[tid + o]; }
        __syncthreads();
    }
    if (tid < CW) {
        part[((c0 + tid) * S + s) * 2 + 0] = ls[tid];
        part[((c0 + tid) * S + s) * 2 + 1] = lq[tid];
    }
}

// wave-parallel stats finalize (handles S up to 64)
__global__ __launch_bounds__(256) void stats_final_w(
    const float* __restrict__ part, const float* __restrict__ g,
    const float* __restrict__ be, float* __restrict__ scale,
    float* __restrict__ shift, int C, int S, float invN) {
    int c = blockIdx.x * 4 + (threadIdx.x >> 6);
    int lane = threadIdx.x & 63;
    if (c >= C) return;
    float s = 0.f, q = 0.f;
    for (int i = lane; i < S; i += 64) {
        s += part[(c * S + i) * 2 + 0];
        q += part[(c * S + i) * 2 + 1];
    }
#pragma unroll
    for (int off = 32; off > 0; off >>= 1) {
        s += __shfl_down(s, off, 64);
        q += __shfl_down(q, off, 64);
    }
    if (lane == 0) {
        float m = s * invN;
        float v = q * invN - m * m;
        float inv = rsqrtf(v + BEPS);
        float sc = g[c] * inv;
        scale[c] = sc;
        shift[c] = be[c] - m * sc;
    }
}

// ---------------- BN fold: weights -> [co][Kp] k=tap*Ci+ci (pad zeros) ------
__global__ void fold_w_nhwc(const float* __restrict__ w, const float* __restrict__ scale,
                            ushort_t* __restrict__ wout, int Ci, int lgCi, int K, int Kp) {
    int k = blockIdx.x * 256 + threadIdx.x;
    int co = blockIdx.y;
    if (k >= Kp) return;
    ushort_t o = 0;
    if (k < K) {
        int tap = k >> lgCi;
        int ci = k & (Ci - 1);
        o = f2bf(w[((long long)co * Ci + ci) * 9 + tap] * scale[ci]);
    }
    wout[(long long)co * Kp + k] = o;
}

// ---------------- BN fold: bias via wave-per-co reduction -------------------
__global__ __launch_bounds__(256) void fold_b_v2(
    const float* __restrict__ w, const float* __restrict__ shift,
    const float* __restrict__ bias, float* __restrict__ effb, int Co, int Ci) {
    const int co = blockIdx.x * 4 + (threadIdx.x >> 6);
    const int lane = threadIdx.x & 63;
    if (co >= Co) return;
    const int CK = Ci * 9;
    const float* wr = w + (long long)co * CK;
    float acc = 0.f;
    for (int k = lane; k < CK; k += 64) acc = fmaf(wr[k], shift[k / 9], acc);
#pragma unroll
    for (int off = 32; off > 0; off >>= 1) acc += __shfl_down(acc, off, 64);
    if (lane == 0) effb[co] = acc + bias[co];
}

// ---------------- BN apply conv5 NHWC out -> xT fp32 [k][32] ----------------
__global__ void bn_apply_t(const ushort_t* __restrict__ y, const float* __restrict__ scale,
                           const float* __restrict__ shift, float* __restrict__ xT) {
    int idx = blockIdx.x * blockDim.x + threadIdx.x;
    if (idx >= 802816) return;
    int k = idx >> 5, b = idx & 31;
    int c = k / 49, p = k - c * 49;
    float v = bf2f(y[((long long)b * 49 + p) * 512 + c]);
    xT[idx] = fmaf(v, scale[c], shift[c]);
}

// ---------------- fc1 split-K GEMM ------------------------------------------
__global__ __launch_bounds__(256) void fc1_gemm(const float* __restrict__ xT,
                                                const float* __restrict__ w,
                                                float* __restrict__ part) {
    const int K = 25088;
    __shared__ __align__(16) float As[16][64];
    __shared__ __align__(16) float Bs[16][32];
    const int tid = threadIdx.x;
    const int m0 = blockIdx.y * 64;
    const int kbeg = blockIdx.x * FC1_KC;
    const int cA = tid >> 2;
    const int kqA = (tid & 3) * 4;
    const int kkB = tid >> 5;
    const int bB = tid & 31;
    const int tm = tid >> 4;
    const int tn = tid & 15;

    const int mrow = m0 + cA;
    const bool mvalid = (mrow < 1000);
    const float* wrow = w + (long long)mrow * K + kbeg + kqA;

    float acc[4][2] = {};
    for (int k0 = 0; k0 < FC1_KC; k0 += 16) {
        float4 av = mvalid ? *(const float4*)(wrow + k0)
                           : make_float4(0.f, 0.f, 0.f, 0.f);
        As[kqA + 0][cA] = av.x;
        As[kqA + 1][cA] = av.y;
        As[kqA + 2][cA] = av.z;
        As[kqA + 3][cA] = av.w;
#pragma unroll
        for (int e = 0; e < 2; ++e) {
            int kk = kkB + e * 8;
            Bs[kk][bB] = xT[(kbeg + k0 + kk) * 32 + bB];
        }
        __syncthreads();
#pragma unroll
        for (int kk = 0; kk < 16; ++kk) {
            float4 a = *(const float4*)&As[kk][tm * 4];
            float b0 = Bs[kk][tn * 2 + 0];
            float b1 = Bs[kk][tn * 2 + 1];
            float a4[4] = {a.x, a.y, a.z, a.w};
#pragma unroll
            for (int mi = 0; mi < 4; ++mi) {
                acc[mi][0] = fmaf(a4[mi], b0, acc[mi][0]);
                acc[mi][1] = fmaf(a4[mi], b1, acc[mi][1]);
            }
        }
        __syncthreads();
    }
    float* pb = part + ((long long)blockIdx.y * FC1_KS + blockIdx.x) * 2048;
#pragma unroll
    for (int mi = 0; mi < 4; ++mi) {
        pb[(tm * 4 + mi) * 32 + tn * 2 + 0] = acc[mi][0];
        pb[(tm * 4 + mi) * 32 + tn * 2 + 1] = acc[mi][1];
    }
}

__global__ void fc1_reduce(const float* __restrict__ part, const float* __restrict__ bias,
                           float* __restrict__ z) {
    int idx = blockIdx.x * blockDim.x + threadIdx.x;
    if (idx >= 32000) return;
    int o = idx >> 5, b = idx & 31;
    int mt = o >> 6, mr = o & 63;
    const float* p = part + ((long long)mt * FC1_KS) * 2048 + mr * 32 + b;
    float s0 = 0.f, s1 = 0.f;
    int ks = 0;
    for (; ks + 1 < FC1_KS; ks += 2) {
        s0 += p[(long long)ks * 2048];
        s1 += p[(long long)(ks + 1) * 2048];
    }
    for (; ks < FC1_KS; ++ks) s0 += p[(long long)ks * 2048];
    z[b * 1000 + o] = fmaxf(s0 + s1 + bias[o], 0.f);
}

// ---------------- fc2 -------------------------------------------------------
__global__ __launch_bounds__(256) void fc2_v2(const float* __restrict__ z,
                                              const float* __restrict__ w,
                                              const float* __restrict__ bias,
                                              float* __restrict__ ys) {
    int gid = blockIdx.x * 4 + (threadIdx.x >> 6);
    int lane = threadIdx.x & 63;
    if (gid >= 960) return;
    int b = gid / 30, o = gid - b * 30;
    const float* zr = z + (long long)b * 1000;
    const float* wr = w + (long long)o * 1000;
    float acc = 0.f;
    for (int k = lane; k < 1000; k += 64) acc = fmaf(zr[k], wr[k], acc);
    for (int off = 32; off > 0; off >>= 1) acc += __shfl_down(acc, off, 64);
    if (lane == 0) ys[gid] = acc + bias[o];
}

// ---------------- spline coefficients -> float4 per segment -----------------
__global__ void spline_coeff(const float* __restrict__ ysraw, const float* __restrict__ matrix,
                             float4* __restrict__ coef) {
    int r = threadIdx.x;
    if (r >= 96) return;
    const float h = 1.0f / 9.0f;
    float ya[10];
    int b = r / 3, ch = r % 3;
#pragma unroll
    for (int j = 0; j < 10; ++j)
        ya[j] = ysraw[b * 30 + ch * 10 + j] / 100.0f + (float)j / 9.0f;
    float M[10];
#pragma unroll
    for (int i = 0; i < 10; ++i) {
        float acc = 0.f;
#pragma unroll
        for (int j = 0; j < 10; ++j) acc = fmaf(matrix[i * 10 + j], ya[j], acc);
        M[i] = acc;
    }
#pragma unroll
    for (int k = 0; k < 9; ++k) {
        float a = (M[k + 1] - M[k]) / (6.0f * h);
        float bb = M[k] * 0.5f;
        float cc = (ya[k + 1] - ya[k]) / h - (M[k + 1] + 2.0f * M[k]) * (h / 6.0f);
        float dd = ya[k];
        coef[r * 9 + k] = make_float4(a, bb, cc, dd);
    }
}

// ---------------- spline eval on the image (float4) -------------------------
__global__ void eval_img4(const float4* __restrict__ batch4, const float4* __restrict__ coef,
                          float4* __restrict__ out4) {
    int idx = blockIdx.x * blockDim.x + threadIdx.x;
    if (idx >= 1572864) return;
    int plane = idx >> 14;
    float4 xv4 = batch4[idx];
    const float h = 1.0f / 9.0f;
    float xin[4] = {xv4.x, xv4.y, xv4.z, xv4.w};
    float xout[4];
#pragma unroll
    for (int e = 0; e < 4; ++e) {
        float xv = xin[e];
        int xi = (int)floorf(xv / h);
        xi = min(max(xi, 0), 8);
        float xf = xv - (float)xi * h;
        float4 cf = coef[plane * 9 + xi];
        xout[e] = fmaf(fmaf(fmaf(cf.x, xf, cf.y), xf, cf.z), xf, cf.w);
    }
    out4[idx] = make_float4(xout[0], xout[1], xout[2], xout[3]);
}

// ---------------- spline eval on the 255-value table ------------------------
__global__ void eval_tab(const float4* __restrict__ coef, float* __restrict__ out, int total) {
    int idx = blockIdx.x * blockDim.x + threadIdx.x;
    if (idx >= total) return;
    int plane = idx / 255;
    int j = idx % 255;
    float xv = (float)j / 255.0f;
    const float h = 1.0f / 9.0f;
    int xi = (int)floorf(xv / h);
    xi = min(max(xi, 0), 8);
    float xf = xv - (float)xi * h;
    float4 cf = coef[plane * 9 + xi];
    out[idx] = fmaf(fmaf(fmaf(cf.x, xf, cf.y), xf, cf.z), xf, cf.w);
}

extern "C" void kernel_launch(void* const* d_in, const int* in_sizes, int n_in,
                              void* d_out, int out_size, void* d_ws, size_t ws_size,
                              hipStream_t stream) {
    const int B = 32;
    const float* batch = (const float*)d_in[0];
    const float* cw[5] = {(const float*)d_in[1], (const float*)d_in[5], (const float*)d_in[9],
                          (const float*)d_in[13], (const float*)d_in[17]};
    const float* cb[5] = {(const float*)d_in[2], (const float*)d_in[6], (const float*)d_in[10],
                          (const float*)d_in[14], (const float*)d_in[18]};
    const float* bg[5] = {(const float*)d_in[3], (const float*)d_in[7], (const float*)d_in[11],
                          (const float*)d_in[15], (const float*)d_in[19]};
    const float* bb[5] = {(const float*)d_in[4], (const float*)d_in[8], (const float*)d_in[12],
                          (const float*)d_in[16], (const float*)d_in[20]};
    const float* l1w = (const float*)d_in[21];
    const float* l1b = (const float*)d_in[22];
    const float* l2w = (const float*)d_in[23];
    const float* l2b = (const float*)d_in[24];
    const float* matrix = (const float*)d_in[25];

    float* f = (float*)d_ws;
    const size_t A_F = 8258048;    // NHWC act buf A (bf16, 16.5M elts)
    const size_t Bq_F = 4064256;   // NHWC act buf B
    const size_t W_F = 589824;     // folded weights bf16 (max 512*2304)
    ushort_t* bufA = (ushort_t*)f;
    ushort_t* bufB = (ushort_t*)(f + A_F);
    ushort_t* Wf_bf = (ushort_t*)(f + A_F + Bq_F);
    float* effb  = f + A_F + Bq_F + W_F;   // 512
    float* scale = effb + 512;             // 512
    float* shift = scale + 512;            // 512
    float* part  = shift + 512;            // 8192
    float* x5    = part + 8192;            // 802,816
    float* pacc  = x5 + 802816;            // 3,686,400 (conv partials + fc1 partials)
    float* z1    = pacc + 3686400;         // 32,000
    float* ysb   = z1 + 32000;             // 960
    float4* coef = (float4*)(ysb + 960);   // 96*9 float4

    const int Ci[5]   = {3, 32, 64, 128, 256};
    const int lgCi[5] = {0, 5, 6, 7, 8};
    const int Co[5]   = {32, 64, 128, 256, 512};
    const int Hi[5]   = {256, 127, 63, 31, 15};
    const int Ho[5]   = {127, 63, 31, 15, 7};
    const int Sl[5]   = {64, 32, 16, 8, 8};
    const int lgCW[5] = {5, 6, 6, 6, 6};
    const int Zl[5]   = {1, 1, 1, 2, 3};

    ushort_t* bufs[2] = {bufA, bufB};

    // layer 1: direct conv (NHWC out) + coalesced stats
    conv1_direct<<<C1NB, 256, 0, stream>>>(batch, cw[0], cb[0], bufA);
    {
        long long P = (long long)B * 16129;
        stats_nhwc<<<dim3(1, Sl[0]), 256, 0, stream>>>(bufA, part, P, 32, Sl[0], lgCW[0]);
        stats_final_w<<<8, 256, 0, stream>>>(part, bg[0], bb[0], scale, shift, 32, Sl[0],
                                             1.0f / (float)P);
    }

    // layers 2..5: NHWC MFMA bf16
    const ushort_t* cur = bufA;
    for (int l = 1; l < 5; ++l) {
        ushort_t* outb = bufs[l % 2];
        int K = Ci[l] * 9;
        int Kp = (K + 63) & ~63;
        fold_w_nhwc<<<dim3((Kp + 255) / 256, Co[l]), 256, 0, stream>>>(
            cw[l], scale, Wf_bf, Ci[l], lgCi[l], K, Kp);
        fold_b_v2<<<(Co[l] + 3) / 4, 256, 0, stream>>>(cw[l], shift, cb[l], effb, Co[l], Ci[l]);
        int N = B * Ho[l] * Ho[l];
        int Z = Zl[l];
        int kcount = Kp / Z;
        dim3 grid((N + 127) / 128, Co[l] / 64, Z);
        if (Z == 1) {
            conv_mfma<<<grid, 256, 0, stream>>>(cur, Wf_bf, effb, outb, nullptr,
                                                B, Ci[l], lgCi[l], Hi[l], Hi[l], Co[l],
                                                Ho[l], Ho[l], K, Kp, kcount);
        } else {
            conv_mfma<<<grid, 256, 0, stream>>>(cur, Wf_bf, effb, nullptr, pacc,
                                                B, Ci[l], lgCi[l], Hi[l], Hi[l], Co[l],
                                                Ho[l], Ho[l], K, Kp, kcount);
            int total = N * Co[l];
            int lgCo = (Co[l] == 256) ? 8 : 9;
            convz_reduce<<<(total + 255) / 256, 256, 0, stream>>>(pacc, effb, outb,
                                                                  N, Co[l], lgCo, Z, total);
        }
        long long P = (long long)N;
        stats_nhwc<<<dim3(Co[l] >> lgCW[l], Sl[l]), 256, 0, stream>>>(
            outb, part, P, Co[l], Sl[l], lgCW[l]);
        stats_final_w<<<(Co[l] + 3) / 4, 256, 0, stream>>>(part, bg[l], bb[l], scale, shift,
                                                           Co[l], Sl[l], 1.0f / (float)P);
        cur = outb;
    }

    bn_apply_t<<<(802816 + 255) / 256, 256, 0, stream>>>(cur, scale, shift, x5);
    {
        dim3 grid(FC1_KS, 16);
        fc1_gemm<<<grid, 256, 0, stream>>>(x5, l1w, pacc);
    }
    fc1_reduce<<<(32000 + 255) / 256, 256, 0, stream>>>(pacc, l1b, z1);
    fc2_v2<<<240, 256, 0, stream>>>(z1, l2w, l2b, ysb);
    spline_coeff<<<1, 96, 0, stream>>>(ysb, matrix, coef);

    float* out = (float*)d_out;
    eval_img4<<<(1572864 + 255) / 256, 256, 0, stream>>>((const float4*)batch, coef,
                                                         (float4*)out);
    eval_tab<<<(96 * 255 + 255) / 256, 256, 0, stream>>>(coef, out + 6291456, 96 * 255);
}

// Round 11
// 287.215 us; speedup vs baseline: 3.2147x; 3.2147x over previous
//
#include <hip/hip_runtime.h>
#include <hip/hip_bf16.h>

#define BEPS 1e-5f
#define FC1_KS 98
#define FC1_KC 256
#define C1NB 2017
#define STS 512

typedef __attribute__((ext_vector_type(8))) short short8v;
typedef __attribute__((ext_vector_type(4))) float f32x4;
typedef unsigned short ushort_t;

__device__ __forceinline__ float bf2f(ushort_t u) {
    unsigned int x = ((unsigned int)u) << 16;
    return __builtin_bit_cast(float, x);
}
__device__ __forceinline__ ushort_t f2bf(float v) {
    __hip_bfloat16 h = __float2bfloat16(v);
    return *(ushort_t*)&h;
}

// ---------------- conv1: direct fp32, NHWC bf16 out -------------------------
__global__ __launch_bounds__(256) void conv1_direct(
    const float* __restrict__ in, const float* __restrict__ w,
    const float* __restrict__ bias, ushort_t* __restrict__ out) {
    __shared__ float ws[864];
    __shared__ float bs[32];
    const int tid = threadIdx.x;
    for (int i = tid; i < 864; i += 256) ws[i] = w[i];
    if (tid < 32) bs[tid] = bias[tid];
    __syncthreads();

    const int TOT = 32 * 16129;
    int p = blockIdx.x * 256 + tid;
    if (p >= TOT) return;
    int b = p / 16129, pp = p - b * 16129;
    int i = pp / 127, j = pp - i * 127;
    const float* ib = in + ((long long)b * 3) * 65536 + (2 * i) * 256 + 2 * j;
    float patch[27];
#pragma unroll
    for (int ci = 0; ci < 3; ++ci)
#pragma unroll
        for (int di = 0; di < 3; ++di) {
            const float* rp = ib + ci * 65536 + di * 256;
            float2 v01 = *(const float2*)rp;
            patch[ci * 9 + di * 3 + 0] = v01.x;
            patch[ci * 9 + di * 3 + 1] = v01.y;
            patch[ci * 9 + di * 3 + 2] = rp[2];
        }

    ushort_t res[32];
#pragma unroll
    for (int co = 0; co < 32; co += 4) {
        float a0 = bs[co], a1 = bs[co + 1], a2 = bs[co + 2], a3 = bs[co + 3];
#pragma unroll
        for (int t = 0; t < 27; ++t) {
            float pv = patch[t];
            a0 = fmaf(pv, ws[(co + 0) * 27 + t], a0);
            a1 = fmaf(pv, ws[(co + 1) * 27 + t], a1);
            a2 = fmaf(pv, ws[(co + 2) * 27 + t], a2);
            a3 = fmaf(pv, ws[(co + 3) * 27 + t], a3);
        }
        res[co + 0] = f2bf(fmaxf(a0, 0.f));
        res[co + 1] = f2bf(fmaxf(a1, 0.f));
        res[co + 2] = f2bf(fmaxf(a2, 0.f));
        res[co + 3] = f2bf(fmaxf(a3, 0.f));
    }
    ushort_t* ob = out + (long long)p * 32;
#pragma unroll
    for (int v = 0; v < 4; ++v)
        *(short8v*)&ob[v * 8] = *(const short8v*)&res[v * 8];
}

// ---------------- convs 2-5: NHWC bf16 MFMA implicit GEMM -------------------
__global__ __launch_bounds__(256) void conv_mfma(
    const ushort_t* __restrict__ in, const ushort_t* __restrict__ wf,
    const float* __restrict__ effb, ushort_t* __restrict__ out,
    float* __restrict__ pacc,
    int B, int Ci, int lgCi, int Hi, int Wi, int Co, int Ho, int Wo,
    int K, int Kp, int kcount) {
    const int HoWo = Ho * Wo;
    const int N = B * HoWo;
    __shared__ __align__(16) ushort_t As[64 * 64];
    __shared__ __align__(16) ushort_t Bs[128 * 64];
    const int tid = threadIdx.x;
    const int m0 = blockIdx.y * 64;
    const int n0 = blockIdx.x * 128;
    const int kbeg = blockIdx.z * kcount;

    const int rowA = tid >> 2;
    const int kqA = (tid & 3) * 16;
    const ushort_t* wrowA = wf + (long long)(m0 + rowA) * Kp + kbeg + kqA;
    const int swA = (rowA & 7) << 3;
    const int rowB = tid >> 1;
    const int kqB = (tid & 1) * 32;
    const int n = n0 + rowB;
    const int nn = (n < N) ? n : (N - 1);
    const int pb = nn / HoWo, pp = nn - pb * HoWo;
    const int pi = pp / Wo, pj = pp - pi * Wo;
    const long long base0 = ((long long)pb * Hi + 2 * pi) * Wi + 2 * pj;
    const int swB = (rowB & 7) << 3;

    const int w = tid >> 6;
    const int lane = tid & 63;
    const int wco = (w >> 1) * 32, wpx = (w & 1) * 64;
    const int lm = lane & 15, lk = lane >> 4;

    f32x4 acc[2][4] = {};
    for (int k0 = 0; k0 < kcount; k0 += 64) {
        {
            short8v a0 = *(const short8v*)(wrowA + k0);
            short8v a1 = *(const short8v*)(wrowA + k0 + 8);
            *(short8v*)&As[rowA * 64 + ((kqA + 0) ^ swA)] = a0;
            *(short8v*)&As[rowA * 64 + ((kqA + 8) ^ swA)] = a1;
        }
#pragma unroll
        for (int ch = 0; ch < 2; ++ch) {
            int c16 = kqB + ch * 16;
            int kg = kbeg + k0 + c16;
            int tap = kg >> lgCi;
            tap = tap > 8 ? 8 : tap;
            int ci0 = kg & (Ci - 1);
            int dy = tap / 3, dx = tap - dy * 3;
            const ushort_t* src = in + (base0 + dy * Wi + dx) * Ci + ci0;
            short8v v0 = *(const short8v*)src;
            short8v v1 = *(const short8v*)(src + 8);
            *(short8v*)&Bs[rowB * 64 + ((c16 + 0) ^ swB)] = v0;
            *(short8v*)&Bs[rowB * 64 + ((c16 + 8) ^ swB)] = v1;
        }
        __syncthreads();
#pragma unroll
        for (int kk = 0; kk < 2; ++kk) {
            const int kb = kk * 32 + lk * 8;
            const int ra0 = wco + lm, ra1 = wco + 16 + lm;
            short8v a0 = *(const short8v*)&As[ra0 * 64 + (kb ^ ((ra0 & 7) << 3))];
            short8v a1 = *(const short8v*)&As[ra1 * 64 + (kb ^ ((ra1 & 7) << 3))];
            const int rb0 = wpx + lm, rb1 = wpx + 16 + lm;
            const int rb2 = wpx + 32 + lm, rb3 = wpx + 48 + lm;
            short8v b0 = *(const short8v*)&Bs[rb0 * 64 + (kb ^ ((rb0 & 7) << 3))];
            short8v b1 = *(const short8v*)&Bs[rb1 * 64 + (kb ^ ((rb1 & 7) << 3))];
            short8v b2 = *(const short8v*)&Bs[rb2 * 64 + (kb ^ ((rb2 & 7) << 3))];
            short8v b3 = *(const short8v*)&Bs[rb3 * 64 + (kb ^ ((rb3 & 7) << 3))];
            acc[0][0] = __builtin_amdgcn_mfma_f32_16x16x32_bf16(a0, b0, acc[0][0], 0, 0, 0);
            acc[0][1] = __builtin_amdgcn_mfma_f32_16x16x32_bf16(a0, b1, acc[0][1], 0, 0, 0);
            acc[0][2] = __builtin_amdgcn_mfma_f32_16x16x32_bf16(a0, b2, acc[0][2], 0, 0, 0);
            acc[0][3] = __builtin_amdgcn_mfma_f32_16x16x32_bf16(a0, b3, acc[0][3], 0, 0, 0);
            acc[1][0] = __builtin_amdgcn_mfma_f32_16x16x32_bf16(a1, b0, acc[1][0], 0, 0, 0);
            acc[1][1] = __builtin_amdgcn_mfma_f32_16x16x32_bf16(a1, b1, acc[1][1], 0, 0, 0);
            acc[1][2] = __builtin_amdgcn_mfma_f32_16x16x32_bf16(a1, b2, acc[1][2], 0, 0, 0);
            acc[1][3] = __builtin_amdgcn_mfma_f32_16x16x32_bf16(a1, b3, acc[1][3], 0, 0, 0);
        }
        __syncthreads();
    }
    if (pacc) {
        float* pbuf = pacc + ((long long)blockIdx.z * N) * Co;
#pragma unroll
        for (int nb = 0; nb < 4; ++nb) {
            int np = n0 + wpx + nb * 16 + lm;
            if (np >= N) continue;
#pragma unroll
            for (int amr = 0; amr < 2; ++amr) {
                int cobase = m0 + wco + amr * 16 + lk * 4;
                float4 vv = make_float4(acc[amr][nb][0], acc[amr][nb][1],
                                        acc[amr][nb][2], acc[amr][nb][3]);
                *(float4*)&pbuf[(long long)np * Co + cobase] = vv;
            }
        }
    } else {
#pragma unroll
        for (int nb = 0; nb < 4; ++nb) {
            int np = n0 + wpx + nb * 16 + lm;
            if (np >= N) continue;
#pragma unroll
            for (int amr = 0; amr < 2; ++amr) {
                int cobase = m0 + wco + amr * 16 + lk * 4;
                float4 eb = *(const float4*)&effb[cobase];
                ushort4 u;
                u.x = f2bf(fmaxf(acc[amr][nb][0] + eb.x, 0.f));
                u.y = f2bf(fmaxf(acc[amr][nb][1] + eb.y, 0.f));
                u.z = f2bf(fmaxf(acc[amr][nb][2] + eb.z, 0.f));
                u.w = f2bf(fmaxf(acc[amr][nb][3] + eb.w, 0.f));
                *(ushort4*)&out[(long long)np * Co + cobase] = u;
            }
        }
    }
}

// reduce K-split fp32 partials + bias + relu -> NHWC bf16
__global__ void convz_reduce(const float* __restrict__ pacc, const float* __restrict__ effb,
                             ushort_t* __restrict__ out, int N, int Co, int lgCo, int Z,
                             int total) {
    int idx = blockIdx.x * 256 + threadIdx.x;
    if (idx >= total) return;
    int c = idx & (Co - 1);
    float s = effb[c];
    for (int z = 0; z < Z; ++z) s += pacc[((long long)z * N << lgCo) + idx];
    out[idx] = f2bf(fmaxf(s, 0.f));
}

// ---------------- BN stats: flat NHWC, short8 loads, fixed 8-ch per thread --
// chunk = 2048 elts; thread's channel group cg = tid mod (C/8) is constant.
__global__ __launch_bounds__(256) void stats_flat(
    const ushort_t* __restrict__ y, float* __restrict__ part,
    long long total, int C, int S) {
    const int tid = threadIdx.x;
    float sum[8] = {}, sq[8] = {};
    const long long nchunk = (total + 2047) >> 11;
    for (long long g = blockIdx.x; g < nchunk; g += S) {
        long long off = (g << 11) + tid * 8;
        if (off + 8 <= total) {
            short8v v8 = *(const short8v*)(y + off);
#pragma unroll
            for (int j = 0; j < 8; ++j) {
                float v = bf2f((ushort_t)v8[j]);
                sum[j] += v;
                sq[j] = fmaf(v, v, sq[j]);
            }
        }
    }
    __shared__ float rs[256][8], rq[256][8];
#pragma unroll
    for (int j = 0; j < 8; ++j) { rs[tid][j] = sum[j]; rq[tid][j] = sq[j]; }
    __syncthreads();
    const int G = C >> 3;       // channel groups per chunk period
    const int TPG = 256 / G;    // threads sharing a group
    for (int c = tid; c < C; c += 256) {
        int grp = c >> 3, j = c & 7;
        float s = 0.f, q = 0.f;
        for (int i = 0; i < TPG; ++i) {
            s += rs[grp + i * G][j];
            q += rq[grp + i * G][j];
        }
        part[(c * S + blockIdx.x) * 2 + 0] = s;
        part[(c * S + blockIdx.x) * 2 + 1] = q;
    }
}

// wave-parallel stats finalize
__global__ __launch_bounds__(256) void stats_final_w(
    const float* __restrict__ part, const float* __restrict__ g,
    const float* __restrict__ be, float* __restrict__ scale,
    float* __restrict__ shift, int C, int S, float invN) {
    int c = blockIdx.x * 4 + (threadIdx.x >> 6);
    int lane = threadIdx.x & 63;
    if (c >= C) return;
    float s = 0.f, q = 0.f;
    for (int i = lane; i < S; i += 64) {
        s += part[(c * S + i) * 2 + 0];
        q += part[(c * S + i) * 2 + 1];
    }
#pragma unroll
    for (int off = 32; off > 0; off >>= 1) {
        s += __shfl_down(s, off, 64);
        q += __shfl_down(q, off, 64);
    }
    if (lane == 0) {
        float m = s * invN;
        float v = q * invN - m * m;
        float inv = rsqrtf(v + BEPS);
        float sc = g[c] * inv;
        scale[c] = sc;
        shift[c] = be[c] - m * sc;
    }
}

// ---------------- BN fold: weights -> [co][Kp] k=tap*Ci+ci (pad zeros) ------
__global__ void fold_w_nhwc(const float* __restrict__ w, const float* __restrict__ scale,
                            ushort_t* __restrict__ wout, int Ci, int lgCi, int K, int Kp) {
    int k = blockIdx.x * 256 + threadIdx.x;
    int co = blockIdx.y;
    if (k >= Kp) return;
    ushort_t o = 0;
    if (k < K) {
        int tap = k >> lgCi;
        int ci = k & (Ci - 1);
        o = f2bf(w[((long long)co * Ci + ci) * 9 + tap] * scale[ci]);
    }
    wout[(long long)co * Kp + k] = o;
}

// ---------------- BN fold: bias via wave-per-co reduction -------------------
__global__ __launch_bounds__(256) void fold_b_v2(
    const float* __restrict__ w, const float* __restrict__ shift,
    const float* __restrict__ bias, float* __restrict__ effb, int Co, int Ci) {
    const int co = blockIdx.x * 4 + (threadIdx.x >> 6);
    const int lane = threadIdx.x & 63;
    if (co >= Co) return;
    const int CK = Ci * 9;
    const float* wr = w + (long long)co * CK;
    float acc = 0.f;
    for (int k = lane; k < CK; k += 64) acc = fmaf(wr[k], shift[k / 9], acc);
#pragma unroll
    for (int off = 32; off > 0; off >>= 1) acc += __shfl_down(acc, off, 64);
    if (lane == 0) effb[co] = acc + bias[co];
}

// ---------------- BN apply conv5 NHWC out -> xT fp32 [k][32] ----------------
__global__ void bn_apply_t(const ushort_t* __restrict__ y, const float* __restrict__ scale,
                           const float* __restrict__ shift, float* __restrict__ xT) {
    int idx = blockIdx.x * blockDim.x + threadIdx.x;
    if (idx >= 802816) return;
    int k = idx >> 5, b = idx & 31;
    int c = k / 49, p = k - c * 49;
    float v = bf2f(y[((long long)b * 49 + p) * 512 + c]);
    xT[idx] = fmaf(v, scale[c], shift[c]);
}

// ---------------- fc1 split-K GEMM ------------------------------------------
__global__ __launch_bounds__(256) void fc1_gemm(const float* __restrict__ xT,
                                                const float* __restrict__ w,
                                                float* __restrict__ part) {
    const int K = 25088;
    __shared__ __align__(16) float As[16][64];
    __shared__ __align__(16) float Bs[16][32];
    const int tid = threadIdx.x;
    const int m0 = blockIdx.y * 64;
    const int kbeg = blockIdx.x * FC1_KC;
    const int cA = tid >> 2;
    const int kqA = (tid & 3) * 4;
    const int kkB = tid >> 5;
    const int bB = tid & 31;
    const int tm = tid >> 4;
    const int tn = tid & 15;

    const int mrow = m0 + cA;
    const bool mvalid = (mrow < 1000);
    const float* wrow = w + (long long)mrow * K + kbeg + kqA;

    float acc[4][2] = {};
    for (int k0 = 0; k0 < FC1_KC; k0 += 16) {
        float4 av = mvalid ? *(const float4*)(wrow + k0)
                           : make_float4(0.f, 0.f, 0.f, 0.f);
        As[kqA + 0][cA] = av.x;
        As[kqA + 1][cA] = av.y;
        As[kqA + 2][cA] = av.z;
        As[kqA + 3][cA] = av.w;
#pragma unroll
        for (int e = 0; e < 2; ++e) {
            int kk = kkB + e * 8;
            Bs[kk][bB] = xT[(kbeg + k0 + kk) * 32 + bB];
        }
        __syncthreads();
#pragma unroll
        for (int kk = 0; kk < 16; ++kk) {
            float4 a = *(const float4*)&As[kk][tm * 4];
            float b0 = Bs[kk][tn * 2 + 0];
            float b1 = Bs[kk][tn * 2 + 1];
            float a4[4] = {a.x, a.y, a.z, a.w};
#pragma unroll
            for (int mi = 0; mi < 4; ++mi) {
                acc[mi][0] = fmaf(a4[mi], b0, acc[mi][0]);
                acc[mi][1] = fmaf(a4[mi], b1, acc[mi][1]);
            }
        }
        __syncthreads();
    }
    float* pb = part + ((long long)blockIdx.y * FC1_KS + blockIdx.x) * 2048;
#pragma unroll
    for (int mi = 0; mi < 4; ++mi) {
        pb[(tm * 4 + mi) * 32 + tn * 2 + 0] = acc[mi][0];
        pb[(tm * 4 + mi) * 32 + tn * 2 + 1] = acc[mi][1];
    }
}

__global__ void fc1_reduce(const float* __restrict__ part, const float* __restrict__ bias,
                           float* __restrict__ z) {
    int idx = blockIdx.x * blockDim.x + threadIdx.x;
    if (idx >= 32000) return;
    int o = idx >> 5, b = idx & 31;
    int mt = o >> 6, mr = o & 63;
    const float* p = part + ((long long)mt * FC1_KS) * 2048 + mr * 32 + b;
    float s0 = 0.f, s1 = 0.f;
    int ks = 0;
    for (; ks + 1 < FC1_KS; ks += 2) {
        s0 += p[(long long)ks * 2048];
        s1 += p[(long long)(ks + 1) * 2048];
    }
    for (; ks < FC1_KS; ++ks) s0 += p[(long long)ks * 2048];
    z[b * 1000 + o] = fmaxf(s0 + s1 + bias[o], 0.f);
}

// ---------------- fc2 -------------------------------------------------------
__global__ __launch_bounds__(256) void fc2_v2(const float* __restrict__ z,
                                              const float* __restrict__ w,
                                              const float* __restrict__ bias,
                                              float* __restrict__ ys) {
    int gid = blockIdx.x * 4 + (threadIdx.x >> 6);
    int lane = threadIdx.x & 63;
    if (gid >= 960) return;
    int b = gid / 30, o = gid - b * 30;
    const float* zr = z + (long long)b * 1000;
    const float* wr = w + (long long)o * 1000;
    float acc = 0.f;
    for (int k = lane; k < 1000; k += 64) acc = fmaf(zr[k], wr[k], acc);
    for (int off = 32; off > 0; off >>= 1) acc += __shfl_down(acc, off, 64);
    if (lane == 0) ys[gid] = acc + bias[o];
}

// ---------------- spline coefficients -> float4 per segment -----------------
__global__ void spline_coeff(const float* __restrict__ ysraw, const float* __restrict__ matrix,
                             float4* __restrict__ coef) {
    int r = threadIdx.x;
    if (r >= 96) return;
    const float h = 1.0f / 9.0f;
    float ya[10];
    int b = r / 3, ch = r % 3;
#pragma unroll
    for (int j = 0; j < 10; ++j)
        ya[j] = ysraw[b * 30 + ch * 10 + j] / 100.0f + (float)j / 9.0f;
    float M[10];
#pragma unroll
    for (int i = 0; i < 10; ++i) {
        float acc = 0.f;
#pragma unroll
        for (int j = 0; j < 10; ++j) acc = fmaf(matrix[i * 10 + j], ya[j], acc);
        M[i] = acc;
    }
#pragma unroll
    for (int k = 0; k < 9; ++k) {
        float a = (M[k + 1] - M[k]) / (6.0f * h);
        float bb = M[k] * 0.5f;
        float cc = (ya[k + 1] - ya[k]) / h - (M[k + 1] + 2.0f * M[k]) * (h / 6.0f);
        float dd = ya[k];
        coef[r * 9 + k] = make_float4(a, bb, cc, dd);
    }
}

// ---------------- spline eval on the image (float4) -------------------------
__global__ void eval_img4(const float4* __restrict__ batch4, const float4* __restrict__ coef,
                          float4* __restrict__ out4) {
    int idx = blockIdx.x * blockDim.x + threadIdx.x;
    if (idx >= 1572864) return;
    int plane = idx >> 14;
    float4 xv4 = batch4[idx];
    const float h = 1.0f / 9.0f;
    float xin[4] = {xv4.x, xv4.y, xv4.z, xv4.w};
    float xout[4];
#pragma unroll
    for (int e = 0; e < 4; ++e) {
        float xv = xin[e];
        int xi = (int)floorf(xv / h);
        xi = min(max(xi, 0), 8);
        float xf = xv - (float)xi * h;
        float4 cf = coef[plane * 9 + xi];
        xout[e] = fmaf(fmaf(fmaf(cf.x, xf, cf.y), xf, cf.z), xf, cf.w);
    }
    out4[idx] = make_float4(xout[0], xout[1], xout[2], xout[3]);
}

// ---------------- spline eval on the 255-value table ------------------------
__global__ void eval_tab(const float4* __restrict__ coef, float* __restrict__ out, int total) {
    int idx = blockIdx.x * blockDim.x + threadIdx.x;
    if (idx >= total) return;
    int plane = idx / 255;
    int j = idx % 255;
    float xv = (float)j / 255.0f;
    const float h = 1.0f / 9.0f;
    int xi = (int)floorf(xv / h);
    xi = min(max(xi, 0), 8);
    float xf = xv - (float)xi * h;
    float4 cf = coef[plane * 9 + xi];
    out[idx] = fmaf(fmaf(fmaf(cf.x, xf, cf.y), xf, cf.z), xf, cf.w);
}

extern "C" void kernel_launch(void* const* d_in, const int* in_sizes, int n_in,
                              void* d_out, int out_size, void* d_ws, size_t ws_size,
                              hipStream_t stream) {
    const int B = 32;
    const float* batch = (const float*)d_in[0];
    const float* cw[5] = {(const float*)d_in[1], (const float*)d_in[5], (const float*)d_in[9],
                          (const float*)d_in[13], (const float*)d_in[17]};
    const float* cb[5] = {(const float*)d_in[2], (const float*)d_in[6], (const float*)d_in[10],
                          (const float*)d_in[14], (const float*)d_in[18]};
    const float* bg[5] = {(const float*)d_in[3], (const float*)d_in[7], (const float*)d_in[11],
                          (const float*)d_in[15], (const float*)d_in[19]};
    const float* bb[5] = {(const float*)d_in[4], (const float*)d_in[8], (const float*)d_in[12],
                          (const float*)d_in[16], (const float*)d_in[20]};
    const float* l1w = (const float*)d_in[21];
    const float* l1b = (const float*)d_in[22];
    const float* l2w = (const float*)d_in[23];
    const float* l2b = (const float*)d_in[24];
    const float* matrix = (const float*)d_in[25];

    float* f = (float*)d_ws;
    const size_t A_F = 8258048;
    const size_t Bq_F = 4064256;
    const size_t W_F = 589824;
    ushort_t* bufA = (ushort_t*)f;
    ushort_t* bufB = (ushort_t*)(f + A_F);
    ushort_t* Wf_bf = (ushort_t*)(f + A_F + Bq_F);
    float* effb  = f + A_F + Bq_F + W_F;   // 512
    float* scale = effb + 512;             // 512
    float* shift = scale + 512;            // 512
    float* part  = shift + 512;            // 512*STS*2 = 524,288
    float* x5    = part + 524288;          // 802,816
    float* pacc  = x5 + 802816;            // 3,686,400
    float* z1    = pacc + 3686400;         // 32,000
    float* ysb   = z1 + 32000;             // 960
    float4* coef = (float4*)(ysb + 960);   // 96*9 float4

    const int Ci[5]   = {3, 32, 64, 128, 256};
    const int lgCi[5] = {0, 5, 6, 7, 8};
    const int Co[5]   = {32, 64, 128, 256, 512};
    const int Hi[5]   = {256, 127, 63, 31, 15};
    const int Ho[5]   = {127, 63, 31, 15, 7};
    const int Zl[5]   = {1, 1, 1, 2, 3};

    ushort_t* bufs[2] = {bufA, bufB};

    // layer 1: direct conv (NHWC out) + flat vectorized stats
    conv1_direct<<<C1NB, 256, 0, stream>>>(batch, cw[0], cb[0], bufA);
    {
        long long total = (long long)B * 16129 * 32;
        stats_flat<<<STS, 256, 0, stream>>>(bufA, part, total, 32, STS);
        stats_final_w<<<8, 256, 0, stream>>>(part, bg[0], bb[0], scale, shift, 32, STS,
                                             32.0f / (float)total);
    }

    // layers 2..5: NHWC MFMA bf16
    const ushort_t* cur = bufA;
    for (int l = 1; l < 5; ++l) {
        ushort_t* outb = bufs[l % 2];
        int K = Ci[l] * 9;
        int Kp = (K + 63) & ~63;
        fold_w_nhwc<<<dim3((Kp + 255) / 256, Co[l]), 256, 0, stream>>>(
            cw[l], scale, Wf_bf, Ci[l], lgCi[l], K, Kp);
        fold_b_v2<<<(Co[l] + 3) / 4, 256, 0, stream>>>(cw[l], shift, cb[l], effb, Co[l], Ci[l]);
        int N = B * Ho[l] * Ho[l];
        int Z = Zl[l];
        int kcount = Kp / Z;
        dim3 grid((N + 127) / 128, Co[l] / 64, Z);
        if (Z == 1) {
            conv_mfma<<<grid, 256, 0, stream>>>(cur, Wf_bf, effb, outb, nullptr,
                                                B, Ci[l], lgCi[l], Hi[l], Hi[l], Co[l],
                                                Ho[l], Ho[l], K, Kp, kcount);
        } else {
            conv_mfma<<<grid, 256, 0, stream>>>(cur, Wf_bf, effb, nullptr, pacc,
                                                B, Ci[l], lgCi[l], Hi[l], Hi[l], Co[l],
                                                Ho[l], Ho[l], K, Kp, kcount);
            int total = N * Co[l];
            int lgCo = (Co[l] == 256) ? 8 : 9;
            convz_reduce<<<(total + 255) / 256, 256, 0, stream>>>(pacc, effb, outb,
                                                                  N, Co[l], lgCo, Z, total);
        }
        long long total = (long long)N * Co[l];
        stats_flat<<<STS, 256, 0, stream>>>(outb, part, total, Co[l], STS);
        stats_final_w<<<(Co[l] + 3) / 4, 256, 0, stream>>>(part, bg[l], bb[l], scale, shift,
                                                           Co[l], STS, (float)Co[l] / (float)total);
        cur = outb;
    }

    bn_apply_t<<<(802816 + 255) / 256, 256, 0, stream>>>(cur, scale, shift, x5);
    {
        dim3 grid(FC1_KS, 16);
        fc1_gemm<<<grid, 256, 0, stream>>>(x5, l1w, pacc);
    }
    fc1_reduce<<<(32000 + 255) / 256, 256, 0, stream>>>(pacc, l1b, z1);
    fc2_v2<<<240, 256, 0, stream>>>(z1, l2w, l2b, ysb);
    spline_coeff<<<1, 96, 0, stream>>>(ysb, matrix, coef);

    float* out = (float*)d_out;
    eval_img4<<<(1572864 + 255) / 256, 256, 0, stream>>>((const float4*)batch, coef,
                                                         (float4*)out);
    eval_tab<<<(96 * 255 + 255) / 256, 256, 0, stream>>>(coef, out + 6291456, 96 * 255);
}

// Round 12
// 258.728 us; speedup vs baseline: 3.5687x; 1.1101x over previous
//
#include <hip/hip_runtime.h>
#include <hip/hip_bf16.h>

#define BEPS 1e-5f
#define FC1_KS 98
#define FC1_KC 256
#define C1NB 2017
#define STS 512

typedef __attribute__((ext_vector_type(8))) short short8v;
typedef __attribute__((ext_vector_type(4))) float f32x4;
typedef unsigned short ushort_t;

__device__ __forceinline__ float bf2f(ushort_t u) {
    unsigned int x = ((unsigned int)u) << 16;
    return __builtin_bit_cast(float, x);
}
__device__ __forceinline__ ushort_t f2bf(float v) {
    __hip_bfloat16 h = __float2bfloat16(v);
    return *(ushort_t*)&h;
}

// ---------------- conv1: direct fp32, NHWC bf16 out -------------------------
__global__ __launch_bounds__(256) void conv1_direct(
    const float* __restrict__ in, const float* __restrict__ w,
    const float* __restrict__ bias, ushort_t* __restrict__ out) {
    __shared__ float ws[864];
    __shared__ float bs[32];
    const int tid = threadIdx.x;
    for (int i = tid; i < 864; i += 256) ws[i] = w[i];
    if (tid < 32) bs[tid] = bias[tid];
    __syncthreads();

    const int TOT = 32 * 16129;
    int p = blockIdx.x * 256 + tid;
    if (p >= TOT) return;
    int b = p / 16129, pp = p - b * 16129;
    int i = pp / 127, j = pp - i * 127;
    const float* ib = in + ((long long)b * 3) * 65536 + (2 * i) * 256 + 2 * j;
    float patch[27];
#pragma unroll
    for (int ci = 0; ci < 3; ++ci)
#pragma unroll
        for (int di = 0; di < 3; ++di) {
            const float* rp = ib + ci * 65536 + di * 256;
            float2 v01 = *(const float2*)rp;
            patch[ci * 9 + di * 3 + 0] = v01.x;
            patch[ci * 9 + di * 3 + 1] = v01.y;
            patch[ci * 9 + di * 3 + 2] = rp[2];
        }

    ushort_t res[32];
#pragma unroll
    for (int co = 0; co < 32; co += 4) {
        float a0 = bs[co], a1 = bs[co + 1], a2 = bs[co + 2], a3 = bs[co + 3];
#pragma unroll
        for (int t = 0; t < 27; ++t) {
            float pv = patch[t];
            a0 = fmaf(pv, ws[(co + 0) * 27 + t], a0);
            a1 = fmaf(pv, ws[(co + 1) * 27 + t], a1);
            a2 = fmaf(pv, ws[(co + 2) * 27 + t], a2);
            a3 = fmaf(pv, ws[(co + 3) * 27 + t], a3);
        }
        res[co + 0] = f2bf(fmaxf(a0, 0.f));
        res[co + 1] = f2bf(fmaxf(a1, 0.f));
        res[co + 2] = f2bf(fmaxf(a2, 0.f));
        res[co + 3] = f2bf(fmaxf(a3, 0.f));
    }
    ushort_t* ob = out + (long long)p * 32;
#pragma unroll
    for (int v = 0; v < 4; ++v)
        *(short8v*)&ob[v * 8] = *(const short8v*)&res[v * 8];
}

// ---------------- convs 2-5: NHWC bf16 MFMA implicit GEMM -------------------
__global__ __launch_bounds__(256) void conv_mfma(
    const ushort_t* __restrict__ in, const ushort_t* __restrict__ wf,
    const float* __restrict__ effb, ushort_t* __restrict__ out,
    float* __restrict__ pacc,
    int B, int Ci, int lgCi, int Hi, int Wi, int Co, int Ho, int Wo,
    int K, int Kp, int kcount) {
    const int HoWo = Ho * Wo;
    const int N = B * HoWo;
    __shared__ __align__(16) ushort_t As[64 * 64];
    __shared__ __align__(16) ushort_t Bs[128 * 64];
    const int tid = threadIdx.x;
    const int m0 = blockIdx.y * 64;
    const int n0 = blockIdx.x * 128;
    const int kbeg = blockIdx.z * kcount;

    const int rowA = tid >> 2;
    const int kqA = (tid & 3) * 16;
    const ushort_t* wrowA = wf + (long long)(m0 + rowA) * Kp + kbeg + kqA;
    const int swA = (rowA & 7) << 3;
    const int rowB = tid >> 1;
    const int kqB = (tid & 1) * 32;
    const int n = n0 + rowB;
    const int nn = (n < N) ? n : (N - 1);
    const int pb = nn / HoWo, pp = nn - pb * HoWo;
    const int pi = pp / Wo, pj = pp - pi * Wo;
    const long long base0 = ((long long)pb * Hi + 2 * pi) * Wi + 2 * pj;
    const int swB = (rowB & 7) << 3;

    const int w = tid >> 6;
    const int lane = tid & 63;
    const int wco = (w >> 1) * 32, wpx = (w & 1) * 64;
    const int lm = lane & 15, lk = lane >> 4;

    f32x4 acc[2][4] = {};
    for (int k0 = 0; k0 < kcount; k0 += 64) {
        {
            short8v a0 = *(const short8v*)(wrowA + k0);
            short8v a1 = *(const short8v*)(wrowA + k0 + 8);
            *(short8v*)&As[rowA * 64 + ((kqA + 0) ^ swA)] = a0;
            *(short8v*)&As[rowA * 64 + ((kqA + 8) ^ swA)] = a1;
        }
#pragma unroll
        for (int ch = 0; ch < 2; ++ch) {
            int c16 = kqB + ch * 16;
            int kg = kbeg + k0 + c16;
            int tap = kg >> lgCi;
            tap = tap > 8 ? 8 : tap;
            int ci0 = kg & (Ci - 1);
            int dy = tap / 3, dx = tap - dy * 3;
            const ushort_t* src = in + (base0 + dy * Wi + dx) * Ci + ci0;
            short8v v0 = *(const short8v*)src;
            short8v v1 = *(const short8v*)(src + 8);
            *(short8v*)&Bs[rowB * 64 + ((c16 + 0) ^ swB)] = v0;
            *(short8v*)&Bs[rowB * 64 + ((c16 + 8) ^ swB)] = v1;
        }
        __syncthreads();
#pragma unroll
        for (int kk = 0; kk < 2; ++kk) {
            const int kb = kk * 32 + lk * 8;
            const int ra0 = wco + lm, ra1 = wco + 16 + lm;
            short8v a0 = *(const short8v*)&As[ra0 * 64 + (kb ^ ((ra0 & 7) << 3))];
            short8v a1 = *(const short8v*)&As[ra1 * 64 + (kb ^ ((ra1 & 7) << 3))];
            const int rb0 = wpx + lm, rb1 = wpx + 16 + lm;
            const int rb2 = wpx + 32 + lm, rb3 = wpx + 48 + lm;
            short8v b0 = *(const short8v*)&Bs[rb0 * 64 + (kb ^ ((rb0 & 7) << 3))];
            short8v b1 = *(const short8v*)&Bs[rb1 * 64 + (kb ^ ((rb1 & 7) << 3))];
            short8v b2 = *(const short8v*)&Bs[rb2 * 64 + (kb ^ ((rb2 & 7) << 3))];
            short8v b3 = *(const short8v*)&Bs[rb3 * 64 + (kb ^ ((rb3 & 7) << 3))];
            acc[0][0] = __builtin_amdgcn_mfma_f32_16x16x32_bf16(a0, b0, acc[0][0], 0, 0, 0);
            acc[0][1] = __builtin_amdgcn_mfma_f32_16x16x32_bf16(a0, b1, acc[0][1], 0, 0, 0);
            acc[0][2] = __builtin_amdgcn_mfma_f32_16x16x32_bf16(a0, b2, acc[0][2], 0, 0, 0);
            acc[0][3] = __builtin_amdgcn_mfma_f32_16x16x32_bf16(a0, b3, acc[0][3], 0, 0, 0);
            acc[1][0] = __builtin_amdgcn_mfma_f32_16x16x32_bf16(a1, b0, acc[1][0], 0, 0, 0);
            acc[1][1] = __builtin_amdgcn_mfma_f32_16x16x32_bf16(a1, b1, acc[1][1], 0, 0, 0);
            acc[1][2] = __builtin_amdgcn_mfma_f32_16x16x32_bf16(a1, b2, acc[1][2], 0, 0, 0);
            acc[1][3] = __builtin_amdgcn_mfma_f32_16x16x32_bf16(a1, b3, acc[1][3], 0, 0, 0);
        }
        __syncthreads();
    }
    if (pacc) {
        float* pbuf = pacc + ((long long)blockIdx.z * N) * Co;
#pragma unroll
        for (int nb = 0; nb < 4; ++nb) {
            int np = n0 + wpx + nb * 16 + lm;
            if (np >= N) continue;
#pragma unroll
            for (int amr = 0; amr < 2; ++amr) {
                int cobase = m0 + wco + amr * 16 + lk * 4;
                float4 vv = make_float4(acc[amr][nb][0], acc[amr][nb][1],
                                        acc[amr][nb][2], acc[amr][nb][3]);
                *(float4*)&pbuf[(long long)np * Co + cobase] = vv;
            }
        }
    } else {
#pragma unroll
        for (int nb = 0; nb < 4; ++nb) {
            int np = n0 + wpx + nb * 16 + lm;
            if (np >= N) continue;
#pragma unroll
            for (int amr = 0; amr < 2; ++amr) {
                int cobase = m0 + wco + amr * 16 + lk * 4;
                float4 eb = *(const float4*)&effb[cobase];
                ushort4 u;
                u.x = f2bf(fmaxf(acc[amr][nb][0] + eb.x, 0.f));
                u.y = f2bf(fmaxf(acc[amr][nb][1] + eb.y, 0.f));
                u.z = f2bf(fmaxf(acc[amr][nb][2] + eb.z, 0.f));
                u.w = f2bf(fmaxf(acc[amr][nb][3] + eb.w, 0.f));
                *(ushort4*)&out[(long long)np * Co + cobase] = u;
            }
        }
    }
}

// reduce K-split fp32 partials + bias + relu -> NHWC bf16
__global__ void convz_reduce(const float* __restrict__ pacc, const float* __restrict__ effb,
                             ushort_t* __restrict__ out, int N, int Co, int lgCo, int Z,
                             int total) {
    int idx = blockIdx.x * 256 + threadIdx.x;
    if (idx >= total) return;
    int c = idx & (Co - 1);
    float s = effb[c];
    for (int z = 0; z < Z; ++z) s += pacc[((long long)z * N << lgCo) + idx];
    out[idx] = f2bf(fmaxf(s, 0.f));
}

// ---------------- BN stats: flat NHWC, short8 loads -------------------------
__global__ __launch_bounds__(256) void stats_flat(
    const ushort_t* __restrict__ y, float* __restrict__ part,
    long long total, int C, int S) {
    const int tid = threadIdx.x;
    float sum[8] = {}, sq[8] = {};
    const long long nchunk = (total + 2047) >> 11;
    for (long long g = blockIdx.x; g < nchunk; g += S) {
        long long off = (g << 11) + tid * 8;
        if (off + 8 <= total) {
            short8v v8 = *(const short8v*)(y + off);
#pragma unroll
            for (int j = 0; j < 8; ++j) {
                float v = bf2f((ushort_t)v8[j]);
                sum[j] += v;
                sq[j] = fmaf(v, v, sq[j]);
            }
        }
    }
    __shared__ float rs[256][8], rq[256][8];
#pragma unroll
    for (int j = 0; j < 8; ++j) { rs[tid][j] = sum[j]; rq[tid][j] = sq[j]; }
    __syncthreads();
    const int G = C >> 3;
    const int TPG = 256 / G;
    for (int c = tid; c < C; c += 256) {
        int grp = c >> 3, j = c & 7;
        float s = 0.f, q = 0.f;
        for (int i = 0; i < TPG; ++i) {
            s += rs[grp + i * G][j];
            q += rq[grp + i * G][j];
        }
        part[(c * S + blockIdx.x) * 2 + 0] = s;
        part[(c * S + blockIdx.x) * 2 + 1] = q;
    }
}

// wave-parallel stats finalize
__global__ __launch_bounds__(256) void stats_final_w(
    const float* __restrict__ part, const float* __restrict__ g,
    const float* __restrict__ be, float* __restrict__ scale,
    float* __restrict__ shift, int C, int S, float invN) {
    int c = blockIdx.x * 4 + (threadIdx.x >> 6);
    int lane = threadIdx.x & 63;
    if (c >= C) return;
    float s = 0.f, q = 0.f;
    for (int i = lane; i < S; i += 64) {
        s += part[(c * S + i) * 2 + 0];
        q += part[(c * S + i) * 2 + 1];
    }
#pragma unroll
    for (int off = 32; off > 0; off >>= 1) {
        s += __shfl_down(s, off, 64);
        q += __shfl_down(q, off, 64);
    }
    if (lane == 0) {
        float m = s * invN;
        float v = q * invN - m * m;
        float inv = rsqrtf(v + BEPS);
        float sc = g[c] * inv;
        scale[c] = sc;
        shift[c] = be[c] - m * sc;
    }
}

// ---------------- fused BN fold: weights (grid head) + bias (grid tail) -----
__global__ __launch_bounds__(256) void fold_fused(
    const float* __restrict__ w, const float* __restrict__ scale,
    const float* __restrict__ shift, const float* __restrict__ bias,
    ushort_t* __restrict__ wout, float* __restrict__ effb,
    int Ci, int lgCi, int K, int Kp, int Co, int WB) {
    if ((int)blockIdx.x < WB) {
        int idx = blockIdx.x * 256 + threadIdx.x;
        if (idx >= Co * Kp) return;
        int co = idx / Kp, k = idx - co * Kp;
        ushort_t o = 0;
        if (k < K) {
            int tap = k >> lgCi;
            int ci = k & (Ci - 1);
            o = f2bf(w[((long long)co * Ci + ci) * 9 + tap] * scale[ci]);
        }
        wout[idx] = o;
    } else {
        int co = ((int)blockIdx.x - WB) * 4 + (threadIdx.x >> 6);
        int lane = threadIdx.x & 63;
        if (co >= Co) return;
        const int CK = Ci * 9;
        const float* wr = w + (long long)co * CK;
        float acc = 0.f;
        for (int k = lane; k < CK; k += 64) acc = fmaf(wr[k], shift[k / 9], acc);
#pragma unroll
        for (int off = 32; off > 0; off >>= 1) acc += __shfl_down(acc, off, 64);
        if (lane == 0) effb[co] = acc + bias[co];
    }
}

// ---------------- BN apply conv5 NHWC out -> xB bf16 [32][25088] ------------
__global__ void bn_apply_x(const ushort_t* __restrict__ y, const float* __restrict__ scale,
                           const float* __restrict__ shift, ushort_t* __restrict__ xB) {
    int idx = blockIdx.x * blockDim.x + threadIdx.x;
    if (idx >= 802816) return;
    int b = idx / 25088, k = idx - b * 25088;
    int c = k / 49, p = k - c * 49;
    float v = bf2f(y[((long long)b * 49 + p) * 512 + c]);
    xB[idx] = f2bf(fmaf(v, scale[c], shift[c]));
}

// ---------------- fc1 split-K MFMA GEMM (W fp32 -> bf16 inline) -------------
// per block: 64 M-rows x 32 batch x 256 K. 4 waves, each 16 M-rows.
__global__ __launch_bounds__(256) void fc1_mfma(
    const float* __restrict__ w, const ushort_t* __restrict__ xB,
    float* __restrict__ part) {
    const int K = 25088;
    __shared__ __align__(16) ushort_t As[64 * 256];
    __shared__ __align__(16) ushort_t Bs[32 * 256];
    const int tid = threadIdx.x;
    const int m0 = blockIdx.y * 64;
    const int kbeg = blockIdx.x * FC1_KC;

    // stage A: row r, 64 fp32 k per thread -> bf16 swizzled
    {
        const int r = tid >> 2;
        const int kq = (tid & 3) * 64;
        const int m = m0 + r;
        const bool mv = (m < 1000);
        const float* wr = w + (long long)m * K + kbeg + kq;
        const int sw = (r & 7) << 3;
#pragma unroll
        for (int g = 0; g < 8; ++g) {
            short8v o = {0, 0, 0, 0, 0, 0, 0, 0};
            if (mv) {
                float4 f0 = *(const float4*)(wr + g * 8);
                float4 f1 = *(const float4*)(wr + g * 8 + 4);
                o[0] = (short)f2bf(f0.x); o[1] = (short)f2bf(f0.y);
                o[2] = (short)f2bf(f0.z); o[3] = (short)f2bf(f0.w);
                o[4] = (short)f2bf(f1.x); o[5] = (short)f2bf(f1.y);
                o[6] = (short)f2bf(f1.z); o[7] = (short)f2bf(f1.w);
            }
            *(short8v*)&As[r * 256 + ((kq + g * 8) ^ sw)] = o;
        }
    }
    // stage B: row b (batch), 32 bf16 k per thread
    {
        const int b = tid >> 3;
        const int kq = (tid & 7) * 32;
        const ushort_t* xr = xB + (long long)b * K + kbeg + kq;
        const int sw = (b & 7) << 3;
#pragma unroll
        for (int g = 0; g < 4; ++g) {
            short8v v = *(const short8v*)(xr + g * 8);
            *(short8v*)&Bs[b * 256 + ((kq + g * 8) ^ sw)] = v;
        }
    }
    __syncthreads();
    const int wv = tid >> 6, lane = tid & 63;
    const int lm = lane & 15, lk = lane >> 4;
    const int wm = wv * 16;
    f32x4 acc0 = {}, acc1 = {};
    const int ra = wm + lm;
    const int swa = (ra & 7) << 3;
    const int swb = (lm & 7) << 3;
#pragma unroll
    for (int s = 0; s < 8; ++s) {
        int kb = s * 32 + lk * 8;
        short8v av = *(const short8v*)&As[ra * 256 + (kb ^ swa)];
        short8v b0 = *(const short8v*)&Bs[lm * 256 + (kb ^ swb)];
        short8v b1 = *(const short8v*)&Bs[(16 + lm) * 256 + (kb ^ swb)];
        acc0 = __builtin_amdgcn_mfma_f32_16x16x32_bf16(av, b0, acc0, 0, 0, 0);
        acc1 = __builtin_amdgcn_mfma_f32_16x16x32_bf16(av, b1, acc1, 0, 0, 0);
    }
    float* pb = part + ((long long)blockIdx.y * FC1_KS + blockIdx.x) * 2048;
#pragma unroll
    for (int r = 0; r < 4; ++r) {
        pb[(wm + lk * 4 + r) * 32 + lm] = acc0[r];
        pb[(wm + lk * 4 + r) * 32 + 16 + lm] = acc1[r];
    }
}

__global__ void fc1_reduce(const float* __restrict__ part, const float* __restrict__ bias,
                           float* __restrict__ z) {
    int idx = blockIdx.x * blockDim.x + threadIdx.x;
    if (idx >= 32000) return;
    int o = idx >> 5, b = idx & 31;
    int mt = o >> 6, mr = o & 63;
    const float* p = part + ((long long)mt * FC1_KS) * 2048 + mr * 32 + b;
    float s0 = 0.f, s1 = 0.f;
    int ks = 0;
    for (; ks + 1 < FC1_KS; ks += 2) {
        s0 += p[(long long)ks * 2048];
        s1 += p[(long long)(ks + 1) * 2048];
    }
    for (; ks < FC1_KS; ++ks) s0 += p[(long long)ks * 2048];
    z[b * 1000 + o] = fmaxf(s0 + s1 + bias[o], 0.f);
}

// ---------------- fc2 -------------------------------------------------------
__global__ __launch_bounds__(256) void fc2_v2(const float* __restrict__ z,
                                              const float* __restrict__ w,
                                              const float* __restrict__ bias,
                                              float* __restrict__ ys) {
    int gid = blockIdx.x * 4 + (threadIdx.x >> 6);
    int lane = threadIdx.x & 63;
    if (gid >= 960) return;
    int b = gid / 30, o = gid - b * 30;
    const float* zr = z + (long long)b * 1000;
    const float* wr = w + (long long)o * 1000;
    float acc = 0.f;
    for (int k = lane; k < 1000; k += 64) acc = fmaf(zr[k], wr[k], acc);
    for (int off = 32; off > 0; off >>= 1) acc += __shfl_down(acc, off, 64);
    if (lane == 0) ys[gid] = acc + bias[o];
}

// ---------------- spline coefficients -> float4 per segment -----------------
__global__ void spline_coeff(const float* __restrict__ ysraw, const float* __restrict__ matrix,
                             float4* __restrict__ coef) {
    int r = threadIdx.x;
    if (r >= 96) return;
    const float h = 1.0f / 9.0f;
    float ya[10];
    int b = r / 3, ch = r % 3;
#pragma unroll
    for (int j = 0; j < 10; ++j)
        ya[j] = ysraw[b * 30 + ch * 10 + j] / 100.0f + (float)j / 9.0f;
    float M[10];
#pragma unroll
    for (int i = 0; i < 10; ++i) {
        float acc = 0.f;
#pragma unroll
        for (int j = 0; j < 10; ++j) acc = fmaf(matrix[i * 10 + j], ya[j], acc);
        M[i] = acc;
    }
#pragma unroll
    for (int k = 0; k < 9; ++k) {
        float a = (M[k + 1] - M[k]) / (6.0f * h);
        float bb = M[k] * 0.5f;
        float cc = (ya[k + 1] - ya[k]) / h - (M[k + 1] + 2.0f * M[k]) * (h / 6.0f);
        float dd = ya[k];
        coef[r * 9 + k] = make_float4(a, bb, cc, dd);
    }
}

// ---------------- spline eval: image (float4) + table in one kernel ---------
__global__ void eval_all(const float4* __restrict__ batch4, const float4* __restrict__ coef,
                         float4* __restrict__ out4, float* __restrict__ outt) {
    int idx = blockIdx.x * blockDim.x + threadIdx.x;
    const float h = 1.0f / 9.0f;
    if (idx < 1572864) {
        int plane = idx >> 14;
        float4 xv4 = batch4[idx];
        float xin[4] = {xv4.x, xv4.y, xv4.z, xv4.w};
        float xout[4];
#pragma unroll
        for (int e = 0; e < 4; ++e) {
            float xv = xin[e];
            int xi = (int)floorf(xv / h);
            xi = min(max(xi, 0), 8);
            float xf = xv - (float)xi * h;
            float4 cf = coef[plane * 9 + xi];
            xout[e] = fmaf(fmaf(fmaf(cf.x, xf, cf.y), xf, cf.z), xf, cf.w);
        }
        out4[idx] = make_float4(xout[0], xout[1], xout[2], xout[3]);
    } else {
        int t = idx - 1572864;
        if (t >= 96 * 255) return;
        int plane = t / 255;
        int j = t - plane * 255;
        float xv = (float)j / 255.0f;
        int xi = (int)floorf(xv / h);
        xi = min(max(xi, 0), 8);
        float xf = xv - (float)xi * h;
        float4 cf = coef[plane * 9 + xi];
        outt[t] = fmaf(fmaf(fmaf(cf.x, xf, cf.y), xf, cf.z), xf, cf.w);
    }
}

extern "C" void kernel_launch(void* const* d_in, const int* in_sizes, int n_in,
                              void* d_out, int out_size, void* d_ws, size_t ws_size,
                              hipStream_t stream) {
    const int B = 32;
    const float* batch = (const float*)d_in[0];
    const float* cw[5] = {(const float*)d_in[1], (const float*)d_in[5], (const float*)d_in[9],
                          (const float*)d_in[13], (const float*)d_in[17]};
    const float* cb[5] = {(const float*)d_in[2], (const float*)d_in[6], (const float*)d_in[10],
                          (const float*)d_in[14], (const float*)d_in[18]};
    const float* bg[5] = {(const float*)d_in[3], (const float*)d_in[7], (const float*)d_in[11],
                          (const float*)d_in[15], (const float*)d_in[19]};
    const float* bb[5] = {(const float*)d_in[4], (const float*)d_in[8], (const float*)d_in[12],
                          (const float*)d_in[16], (const float*)d_in[20]};
    const float* l1w = (const float*)d_in[21];
    const float* l1b = (const float*)d_in[22];
    const float* l2w = (const float*)d_in[23];
    const float* l2b = (const float*)d_in[24];
    const float* matrix = (const float*)d_in[25];

    float* f = (float*)d_ws;
    const size_t A_F = 8258048;
    const size_t Bq_F = 4064256;
    const size_t W_F = 589824;
    ushort_t* bufA = (ushort_t*)f;
    ushort_t* bufB = (ushort_t*)(f + A_F);
    ushort_t* Wf_bf = (ushort_t*)(f + A_F + Bq_F);
    float* effb  = f + A_F + Bq_F + W_F;   // 512
    float* scale = effb + 512;             // 512
    float* shift = scale + 512;            // 512
    float* part  = shift + 512;            // 512*STS*2 = 524,288
    float* x5    = part + 524288;          // 802,816 (as bf16 xB: 1.6 MB)
    float* pacc  = x5 + 802816;            // 3,686,400
    float* z1    = pacc + 3686400;         // 32,000
    float* ysb   = z1 + 32000;             // 960
    float4* coef = (float4*)(ysb + 960);   // 96*9 float4

    const int Ci[5]   = {3, 32, 64, 128, 256};
    const int lgCi[5] = {0, 5, 6, 7, 8};
    const int Co[5]   = {32, 64, 128, 256, 512};
    const int Hi[5]   = {256, 127, 63, 31, 15};
    const int Ho[5]   = {127, 63, 31, 15, 7};
    const int Zl[5]   = {1, 1, 1, 2, 3};

    ushort_t* bufs[2] = {bufA, bufB};

    // layer 1
    conv1_direct<<<C1NB, 256, 0, stream>>>(batch, cw[0], cb[0], bufA);
    {
        long long total = (long long)B * 16129 * 32;
        stats_flat<<<STS, 256, 0, stream>>>(bufA, part, total, 32, STS);
        stats_final_w<<<8, 256, 0, stream>>>(part, bg[0], bb[0], scale, shift, 32, STS,
                                             32.0f / (float)total);
    }

    // layers 2..5
    const ushort_t* cur = bufA;
    for (int l = 1; l < 5; ++l) {
        ushort_t* outb = bufs[l % 2];
        int K = Ci[l] * 9;
        int Kp = (K + 63) & ~63;
        int WB = (Co[l] * Kp + 255) / 256;
        int BBk = (Co[l] + 3) / 4;
        fold_fused<<<WB + BBk, 256, 0, stream>>>(cw[l], scale, shift, cb[l], Wf_bf, effb,
                                                 Ci[l], lgCi[l], K, Kp, Co[l], WB);
        int N = B * Ho[l] * Ho[l];
        int Z = Zl[l];
        int kcount = Kp / Z;
        dim3 grid((N + 127) / 128, Co[l] / 64, Z);
        if (Z == 1) {
            conv_mfma<<<grid, 256, 0, stream>>>(cur, Wf_bf, effb, outb, nullptr,
                                                B, Ci[l], lgCi[l], Hi[l], Hi[l], Co[l],
                                                Ho[l], Ho[l], K, Kp, kcount);
        } else {
            conv_mfma<<<grid, 256, 0, stream>>>(cur, Wf_bf, effb, nullptr, pacc,
                                                B, Ci[l], lgCi[l], Hi[l], Hi[l], Co[l],
                                                Ho[l], Ho[l], K, Kp, kcount);
            int total = N * Co[l];
            int lgCo = (Co[l] == 256) ? 8 : 9;
            convz_reduce<<<(total + 255) / 256, 256, 0, stream>>>(pacc, effb, outb,
                                                                  N, Co[l], lgCo, Z, total);
        }
        long long total = (long long)N * Co[l];
        stats_flat<<<STS, 256, 0, stream>>>(outb, part, total, Co[l], STS);
        stats_final_w<<<(Co[l] + 3) / 4, 256, 0, stream>>>(part, bg[l], bb[l], scale, shift,
                                                           Co[l], STS, (float)Co[l] / (float)total);
        cur = outb;
    }

    ushort_t* xB = (ushort_t*)x5;
    bn_apply_x<<<(802816 + 255) / 256, 256, 0, stream>>>(cur, scale, shift, xB);
    {
        dim3 grid(FC1_KS, 16);
        fc1_mfma<<<grid, 256, 0, stream>>>(l1w, xB, pacc);
    }
    fc1_reduce<<<(32000 + 255) / 256, 256, 0, stream>>>(pacc, l1b, z1);
    fc2_v2<<<240, 256, 0, stream>>>(z1, l2w, l2b, ysb);
    spline_coeff<<<1, 96, 0, stream>>>(ysb, matrix, coef);

    float* out = (float*)d_out;
    int evtot = 1572864 + 96 * 255;
    eval_all<<<(evtot + 255) / 256, 256, 0, stream>>>((const float4*)batch, coef,
                                                      (float4*)out, out + 6291456);
}

// Round 13
// 245.810 us; speedup vs baseline: 3.7562x; 1.0526x over previous
//
#include <hip/hip_runtime.h>
#include <hip/hip_bf16.h>

#define BEPS 1e-5f
#define FC1_KS 98
#define FC1_KC 256
#define C1NB 2017
#define STS 512

typedef __attribute__((ext_vector_type(8))) short short8v;
typedef __attribute__((ext_vector_type(4))) float f32x4;
typedef unsigned short ushort_t;

__device__ __forceinline__ float bf2f(ushort_t u) {
    unsigned int x = ((unsigned int)u) << 16;
    return __builtin_bit_cast(float, x);
}
__device__ __forceinline__ ushort_t f2bf(float v) {
    __hip_bfloat16 h = __float2bfloat16(v);
    return *(ushort_t*)&h;
}

// ---------------- conv1: direct fp32, NHWC bf16 out -------------------------
__global__ __launch_bounds__(256) void conv1_direct(
    const float* __restrict__ in, const float* __restrict__ w,
    const float* __restrict__ bias, ushort_t* __restrict__ out) {
    __shared__ float ws[864];
    __shared__ float bs[32];
    const int tid = threadIdx.x;
    for (int i = tid; i < 864; i += 256) ws[i] = w[i];
    if (tid < 32) bs[tid] = bias[tid];
    __syncthreads();

    const int TOT = 32 * 16129;
    int p = blockIdx.x * 256 + tid;
    if (p >= TOT) return;
    int b = p / 16129, pp = p - b * 16129;
    int i = pp / 127, j = pp - i * 127;
    const float* ib = in + ((long long)b * 3) * 65536 + (2 * i) * 256 + 2 * j;
    float patch[27];
#pragma unroll
    for (int ci = 0; ci < 3; ++ci)
#pragma unroll
        for (int di = 0; di < 3; ++di) {
            const float* rp = ib + ci * 65536 + di * 256;
            float2 v01 = *(const float2*)rp;
            patch[ci * 9 + di * 3 + 0] = v01.x;
            patch[ci * 9 + di * 3 + 1] = v01.y;
            patch[ci * 9 + di * 3 + 2] = rp[2];
        }

    ushort_t res[32];
#pragma unroll
    for (int co = 0; co < 32; co += 4) {
        float a0 = bs[co], a1 = bs[co + 1], a2 = bs[co + 2], a3 = bs[co + 3];
#pragma unroll
        for (int t = 0; t < 27; ++t) {
            float pv = patch[t];
            a0 = fmaf(pv, ws[(co + 0) * 27 + t], a0);
            a1 = fmaf(pv, ws[(co + 1) * 27 + t], a1);
            a2 = fmaf(pv, ws[(co + 2) * 27 + t], a2);
            a3 = fmaf(pv, ws[(co + 3) * 27 + t], a3);
        }
        res[co + 0] = f2bf(fmaxf(a0, 0.f));
        res[co + 1] = f2bf(fmaxf(a1, 0.f));
        res[co + 2] = f2bf(fmaxf(a2, 0.f));
        res[co + 3] = f2bf(fmaxf(a3, 0.f));
    }
    ushort_t* ob = out + (long long)p * 32;
#pragma unroll
    for (int v = 0; v < 4; ++v)
        *(short8v*)&ob[v * 8] = *(const short8v*)&res[v * 8];
}

// ---------------- convs 2-5: NHWC bf16 MFMA implicit GEMM -------------------
// Z==1 epilogue also emits per-block channel stats partials into spart.
__global__ __launch_bounds__(256) void conv_mfma(
    const ushort_t* __restrict__ in, const ushort_t* __restrict__ wf,
    const float* __restrict__ effb, ushort_t* __restrict__ out,
    float* __restrict__ pacc, float* __restrict__ spart,
    int B, int Ci, int lgCi, int Hi, int Wi, int Co, int Ho, int Wo,
    int K, int Kp, int kcount, int Spart) {
    const int HoWo = Ho * Wo;
    const int N = B * HoWo;
    __shared__ __align__(16) ushort_t As[64 * 64];
    __shared__ __align__(16) ushort_t Bs[128 * 64];
    const int tid = threadIdx.x;
    const int m0 = blockIdx.y * 64;
    const int n0 = blockIdx.x * 128;
    const int kbeg = blockIdx.z * kcount;

    const int rowA = tid >> 2;
    const int kqA = (tid & 3) * 16;
    const ushort_t* wrowA = wf + (long long)(m0 + rowA) * Kp + kbeg + kqA;
    const int swA = (rowA & 7) << 3;
    const int rowB = tid >> 1;
    const int kqB = (tid & 1) * 32;
    const int n = n0 + rowB;
    const int nn = (n < N) ? n : (N - 1);
    const int pb = nn / HoWo, pp = nn - pb * HoWo;
    const int pi = pp / Wo, pj = pp - pi * Wo;
    const long long base0 = ((long long)pb * Hi + 2 * pi) * Wi + 2 * pj;
    const int swB = (rowB & 7) << 3;

    const int w = tid >> 6;
    const int lane = tid & 63;
    const int wco = (w >> 1) * 32, wpx = (w & 1) * 64;
    const int lm = lane & 15, lk = lane >> 4;

    f32x4 acc[2][4] = {};
    for (int k0 = 0; k0 < kcount; k0 += 64) {
        {
            short8v a0 = *(const short8v*)(wrowA + k0);
            short8v a1 = *(const short8v*)(wrowA + k0 + 8);
            *(short8v*)&As[rowA * 64 + ((kqA + 0) ^ swA)] = a0;
            *(short8v*)&As[rowA * 64 + ((kqA + 8) ^ swA)] = a1;
        }
#pragma unroll
        for (int ch = 0; ch < 2; ++ch) {
            int c16 = kqB + ch * 16;
            int kg = kbeg + k0 + c16;
            int tap = kg >> lgCi;
            tap = tap > 8 ? 8 : tap;
            int ci0 = kg & (Ci - 1);
            int dy = tap / 3, dx = tap - dy * 3;
            const ushort_t* src = in + (base0 + dy * Wi + dx) * Ci + ci0;
            short8v v0 = *(const short8v*)src;
            short8v v1 = *(const short8v*)(src + 8);
            *(short8v*)&Bs[rowB * 64 + ((c16 + 0) ^ swB)] = v0;
            *(short8v*)&Bs[rowB * 64 + ((c16 + 8) ^ swB)] = v1;
        }
        __syncthreads();
#pragma unroll
        for (int kk = 0; kk < 2; ++kk) {
            const int kb = kk * 32 + lk * 8;
            const int ra0 = wco + lm, ra1 = wco + 16 + lm;
            short8v a0 = *(const short8v*)&As[ra0 * 64 + (kb ^ ((ra0 & 7) << 3))];
            short8v a1 = *(const short8v*)&As[ra1 * 64 + (kb ^ ((ra1 & 7) << 3))];
            const int rb0 = wpx + lm, rb1 = wpx + 16 + lm;
            const int rb2 = wpx + 32 + lm, rb3 = wpx + 48 + lm;
            short8v b0 = *(const short8v*)&Bs[rb0 * 64 + (kb ^ ((rb0 & 7) << 3))];
            short8v b1 = *(const short8v*)&Bs[rb1 * 64 + (kb ^ ((rb1 & 7) << 3))];
            short8v b2 = *(const short8v*)&Bs[rb2 * 64 + (kb ^ ((rb2 & 7) << 3))];
            short8v b3 = *(const short8v*)&Bs[rb3 * 64 + (kb ^ ((rb3 & 7) << 3))];
            acc[0][0] = __builtin_amdgcn_mfma_f32_16x16x32_bf16(a0, b0, acc[0][0], 0, 0, 0);
            acc[0][1] = __builtin_amdgcn_mfma_f32_16x16x32_bf16(a0, b1, acc[0][1], 0, 0, 0);
            acc[0][2] = __builtin_amdgcn_mfma_f32_16x16x32_bf16(a0, b2, acc[0][2], 0, 0, 0);
            acc[0][3] = __builtin_amdgcn_mfma_f32_16x16x32_bf16(a0, b3, acc[0][3], 0, 0, 0);
            acc[1][0] = __builtin_amdgcn_mfma_f32_16x16x32_bf16(a1, b0, acc[1][0], 0, 0, 0);
            acc[1][1] = __builtin_amdgcn_mfma_f32_16x16x32_bf16(a1, b1, acc[1][1], 0, 0, 0);
            acc[1][2] = __builtin_amdgcn_mfma_f32_16x16x32_bf16(a1, b2, acc[1][2], 0, 0, 0);
            acc[1][3] = __builtin_amdgcn_mfma_f32_16x16x32_bf16(a1, b3, acc[1][3], 0, 0, 0);
        }
        __syncthreads();
    }
    if (pacc) {
        float* pbuf = pacc + ((long long)blockIdx.z * N) * Co;
#pragma unroll
        for (int nb = 0; nb < 4; ++nb) {
            int np = n0 + wpx + nb * 16 + lm;
            if (np >= N) continue;
#pragma unroll
            for (int amr = 0; amr < 2; ++amr) {
                int cobase = m0 + wco + amr * 16 + lk * 4;
                float4 vv = make_float4(acc[amr][nb][0], acc[amr][nb][1],
                                        acc[amr][nb][2], acc[amr][nb][3]);
                *(float4*)&pbuf[(long long)np * Co + cobase] = vv;
            }
        }
    } else {
        float ssum[2][4] = {}, ssq[2][4] = {};
#pragma unroll
        for (int nb = 0; nb < 4; ++nb) {
            int np = n0 + wpx + nb * 16 + lm;
            bool val = (np < N);
#pragma unroll
            for (int amr = 0; amr < 2; ++amr) {
                int cobase = m0 + wco + amr * 16 + lk * 4;
                float4 eb = *(const float4*)&effb[cobase];
                float v0 = fmaxf(acc[amr][nb][0] + eb.x, 0.f);
                float v1 = fmaxf(acc[amr][nb][1] + eb.y, 0.f);
                float v2 = fmaxf(acc[amr][nb][2] + eb.z, 0.f);
                float v3 = fmaxf(acc[amr][nb][3] + eb.w, 0.f);
                if (val) {
                    ushort4 u;
                    u.x = f2bf(v0); u.y = f2bf(v1); u.z = f2bf(v2); u.w = f2bf(v3);
                    *(ushort4*)&out[(long long)np * Co + cobase] = u;
                    ssum[amr][0] += v0; ssq[amr][0] = fmaf(v0, v0, ssq[amr][0]);
                    ssum[amr][1] += v1; ssq[amr][1] = fmaf(v1, v1, ssq[amr][1]);
                    ssum[amr][2] += v2; ssq[amr][2] = fmaf(v2, v2, ssq[amr][2]);
                    ssum[amr][3] += v3; ssq[amr][3] = fmaf(v3, v3, ssq[amr][3]);
                }
            }
        }
        // reduce across the 16 pixel-lanes (lm) of each lk-group
#pragma unroll
        for (int mm = 1; mm < 16; mm <<= 1) {
#pragma unroll
            for (int amr = 0; amr < 2; ++amr)
#pragma unroll
                for (int r = 0; r < 4; ++r) {
                    ssum[amr][r] += __shfl_xor(ssum[amr][r], mm, 64);
                    ssq[amr][r] += __shfl_xor(ssq[amr][r], mm, 64);
                }
        }
        __shared__ float lss[4][32], lsq[4][32];
        if (lm == 0) {
#pragma unroll
            for (int amr = 0; amr < 2; ++amr)
#pragma unroll
                for (int r = 0; r < 4; ++r) {
                    lss[w][amr * 16 + lk * 4 + r] = ssum[amr][r];
                    lsq[w][amr * 16 + lk * 4 + r] = ssq[amr][r];
                }
        }
        __syncthreads();
        if (tid < 64) {
            int half = tid >> 5, c32 = tid & 31;
            float s = lss[half * 2][c32] + lss[half * 2 + 1][c32];
            float q = lsq[half * 2][c32] + lsq[half * 2 + 1][c32];
            int c = m0 + half * 32 + c32;
            spart[((long long)c * Spart + blockIdx.x) * 2 + 0] = s;
            spart[((long long)c * Spart + blockIdx.x) * 2 + 1] = q;
        }
    }
}

// ---- K-split reduce + bias + relu + stats partials (l4/l5), grid-stride ----
__global__ __launch_bounds__(256) void convz_stats(
    const float* __restrict__ pacc, const float* __restrict__ effb,
    ushort_t* __restrict__ out, float* __restrict__ part,
    long long total, int Co, int Z) {
    const int tid = threadIdx.x;
    const int c0 = (tid * 8) & (Co - 1);
    float eb[8];
    {
        float4 e0 = *(const float4*)&effb[c0];
        float4 e1 = *(const float4*)&effb[c0 + 4];
        eb[0] = e0.x; eb[1] = e0.y; eb[2] = e0.z; eb[3] = e0.w;
        eb[4] = e1.x; eb[5] = e1.y; eb[6] = e1.z; eb[7] = e1.w;
    }
    float sum[8] = {}, sq[8] = {};
    const long long nchunk = total >> 11;
    for (long long g = blockIdx.x; g < nchunk; g += 512) {
        long long off = (g << 11) + tid * 8;
        float v[8];
#pragma unroll
        for (int j = 0; j < 8; ++j) v[j] = eb[j];
        for (int z = 0; z < Z; ++z) {
            const float* pz = pacc + (long long)z * total + off;
            float4 a = *(const float4*)pz;
            float4 b2 = *(const float4*)(pz + 4);
            v[0] += a.x; v[1] += a.y; v[2] += a.z; v[3] += a.w;
            v[4] += b2.x; v[5] += b2.y; v[6] += b2.z; v[7] += b2.w;
        }
        short8v o;
#pragma unroll
        for (int j = 0; j < 8; ++j) {
            float r = fmaxf(v[j], 0.f);
            o[j] = (short)f2bf(r);
            sum[j] += r;
            sq[j] = fmaf(r, r, sq[j]);
        }
        *(short8v*)&out[off] = o;
    }
    __shared__ float rs[256][8], rq[256][8];
#pragma unroll
    for (int j = 0; j < 8; ++j) { rs[tid][j] = sum[j]; rq[tid][j] = sq[j]; }
    __syncthreads();
    const int G = Co >> 3;
    const int TPG = 256 / G;
    for (int c = tid; c < Co; c += 256) {
        int grp = c >> 3, j = c & 7;
        float s = 0.f, q = 0.f;
        for (int i = 0; i < TPG; ++i) {
            s += rs[grp + i * G][j];
            q += rq[grp + i * G][j];
        }
        part[(c * 512 + blockIdx.x) * 2 + 0] = s;
        part[(c * 512 + blockIdx.x) * 2 + 1] = q;
    }
}

// ---------------- BN stats: flat NHWC, short8 loads (layer 1) ---------------
__global__ __launch_bounds__(256) void stats_flat(
    const ushort_t* __restrict__ y, float* __restrict__ part,
    long long total, int C, int S) {
    const int tid = threadIdx.x;
    float sum[8] = {}, sq[8] = {};
    const long long nchunk = (total + 2047) >> 11;
    for (long long g = blockIdx.x; g < nchunk; g += S) {
        long long off = (g << 11) + tid * 8;
        if (off + 8 <= total) {
            short8v v8 = *(const short8v*)(y + off);
#pragma unroll
            for (int j = 0; j < 8; ++j) {
                float v = bf2f((ushort_t)v8[j]);
                sum[j] += v;
                sq[j] = fmaf(v, v, sq[j]);
            }
        }
    }
    __shared__ float rs[256][8], rq[256][8];
#pragma unroll
    for (int j = 0; j < 8; ++j) { rs[tid][j] = sum[j]; rq[tid][j] = sq[j]; }
    __syncthreads();
    const int G = C >> 3;
    const int TPG = 256 / G;
    for (int c = tid; c < C; c += 256) {
        int grp = c >> 3, j = c & 7;
        float s = 0.f, q = 0.f;
        for (int i = 0; i < TPG; ++i) {
            s += rs[grp + i * G][j];
            q += rq[grp + i * G][j];
        }
        part[(c * S + blockIdx.x) * 2 + 0] = s;
        part[(c * S + blockIdx.x) * 2 + 1] = q;
    }
}

// wave-parallel stats finalize
__global__ __launch_bounds__(256) void stats_final_w(
    const float* __restrict__ part, const float* __restrict__ g,
    const float* __restrict__ be, float* __restrict__ scale,
    float* __restrict__ shift, int C, int S, float invN) {
    int c = blockIdx.x * 4 + (threadIdx.x >> 6);
    int lane = threadIdx.x & 63;
    if (c >= C) return;
    float s = 0.f, q = 0.f;
    for (int i = lane; i < S; i += 64) {
        s += part[((long long)c * S + i) * 2 + 0];
        q += part[((long long)c * S + i) * 2 + 1];
    }
#pragma unroll
    for (int off = 32; off > 0; off >>= 1) {
        s += __shfl_down(s, off, 64);
        q += __shfl_down(q, off, 64);
    }
    if (lane == 0) {
        float m = s * invN;
        float v = q * invN - m * m;
        float inv = rsqrtf(v + BEPS);
        float sc = g[c] * inv;
        scale[c] = sc;
        shift[c] = be[c] - m * sc;
    }
}

// ---------------- fused BN fold: weights (grid head) + bias (grid tail) -----
__global__ __launch_bounds__(256) void fold_fused(
    const float* __restrict__ w, const float* __restrict__ scale,
    const float* __restrict__ shift, const float* __restrict__ bias,
    ushort_t* __restrict__ wout, float* __restrict__ effb,
    int Ci, int lgCi, int K, int Kp, int Co, int WB) {
    if ((int)blockIdx.x < WB) {
        int idx = blockIdx.x * 256 + threadIdx.x;
        if (idx >= Co * Kp) return;
        int co = idx / Kp, k = idx - co * Kp;
        ushort_t o = 0;
        if (k < K) {
            int tap = k >> lgCi;
            int ci = k & (Ci - 1);
            o = f2bf(w[((long long)co * Ci + ci) * 9 + tap] * scale[ci]);
        }
        wout[idx] = o;
    } else {
        int co = ((int)blockIdx.x - WB) * 4 + (threadIdx.x >> 6);
        int lane = threadIdx.x & 63;
        if (co >= Co) return;
        const int CK = Ci * 9;
        const float* wr = w + (long long)co * CK;
        float acc = 0.f;
        for (int k = lane; k < CK; k += 64) acc = fmaf(wr[k], shift[k / 9], acc);
#pragma unroll
        for (int off = 32; off > 0; off >>= 1) acc += __shfl_down(acc, off, 64);
        if (lane == 0) effb[co] = acc + bias[co];
    }
}

// ---------------- BN apply conv5 NHWC out -> xB bf16 [32][25088] ------------
__global__ void bn_apply_x(const ushort_t* __restrict__ y, const float* __restrict__ scale,
                           const float* __restrict__ shift, ushort_t* __restrict__ xB) {
    int idx = blockIdx.x * blockDim.x + threadIdx.x;
    if (idx >= 802816) return;
    int b = idx / 25088, k = idx - b * 25088;
    int c = k / 49, p = k - c * 49;
    float v = bf2f(y[((long long)b * 49 + p) * 512 + c]);
    xB[idx] = f2bf(fmaf(v, scale[c], shift[c]));
}

// ---------------- fc1 split-K MFMA GEMM (W fp32 -> bf16 inline) -------------
__global__ __launch_bounds__(256) void fc1_mfma(
    const float* __restrict__ w, const ushort_t* __restrict__ xB,
    float* __restrict__ part) {
    const int K = 25088;
    __shared__ __align__(16) ushort_t As[64 * 256];
    __shared__ __align__(16) ushort_t Bs[32 * 256];
    const int tid = threadIdx.x;
    const int m0 = blockIdx.y * 64;
    const int kbeg = blockIdx.x * FC1_KC;

    {
        const int r = tid >> 2;
        const int kq = (tid & 3) * 64;
        const int m = m0 + r;
        const bool mv = (m < 1000);
        const float* wr = w + (long long)m * K + kbeg + kq;
        const int sw = (r & 7) << 3;
#pragma unroll
        for (int g = 0; g < 8; ++g) {
            short8v o = {0, 0, 0, 0, 0, 0, 0, 0};
            if (mv) {
                float4 f0 = *(const float4*)(wr + g * 8);
                float4 f1 = *(const float4*)(wr + g * 8 + 4);
                o[0] = (short)f2bf(f0.x); o[1] = (short)f2bf(f0.y);
                o[2] = (short)f2bf(f0.z); o[3] = (short)f2bf(f0.w);
                o[4] = (short)f2bf(f1.x); o[5] = (short)f2bf(f1.y);
                o[6] = (short)f2bf(f1.z); o[7] = (short)f2bf(f1.w);
            }
            *(short8v*)&As[r * 256 + ((kq + g * 8) ^ sw)] = o;
        }
    }
    {
        const int b = tid >> 3;
        const int kq = (tid & 7) * 32;
        const ushort_t* xr = xB + (long long)b * K + kbeg + kq;
        const int sw = (b & 7) << 3;
#pragma unroll
        for (int g = 0; g < 4; ++g) {
            short8v v = *(const short8v*)(xr + g * 8);
            *(short8v*)&Bs[b * 256 + ((kq + g * 8) ^ sw)] = v;
        }
    }
    __syncthreads();
    const int wv = tid >> 6, lane = tid & 63;
    const int lm = lane & 15, lk = lane >> 4;
    const int wm = wv * 16;
    f32x4 acc0 = {}, acc1 = {};
    const int ra = wm + lm;
    const int swa = (ra & 7) << 3;
    const int swb = (lm & 7) << 3;
#pragma unroll
    for (int s = 0; s < 8; ++s) {
        int kb = s * 32 + lk * 8;
        short8v av = *(const short8v*)&As[ra * 256 + (kb ^ swa)];
        short8v b0 = *(const short8v*)&Bs[lm * 256 + (kb ^ swb)];
        short8v b1 = *(const short8v*)&Bs[(16 + lm) * 256 + (kb ^ swb)];
        acc0 = __builtin_amdgcn_mfma_f32_16x16x32_bf16(av, b0, acc0, 0, 0, 0);
        acc1 = __builtin_amdgcn_mfma_f32_16x16x32_bf16(av, b1, acc1, 0, 0, 0);
    }
    float* pb = part + ((long long)blockIdx.y * FC1_KS + blockIdx.x) * 2048;
#pragma unroll
    for (int r = 0; r < 4; ++r) {
        pb[(wm + lk * 4 + r) * 32 + lm] = acc0[r];
        pb[(wm + lk * 4 + r) * 32 + 16 + lm] = acc1[r];
    }
}

__global__ void fc1_reduce(const float* __restrict__ part, const float* __restrict__ bias,
                           float* __restrict__ z) {
    int idx = blockIdx.x * blockDim.x + threadIdx.x;
    if (idx >= 32000) return;
    int o = idx >> 5, b = idx & 31;
    int mt = o >> 6, mr = o & 63;
    const float* p = part + ((long long)mt * FC1_KS) * 2048 + mr * 32 + b;
    float s0 = 0.f, s1 = 0.f;
    int ks = 0;
    for (; ks + 1 < FC1_KS; ks += 2) {
        s0 += p[(long long)ks * 2048];
        s1 += p[(long long)(ks + 1) * 2048];
    }
    for (; ks < FC1_KS; ++ks) s0 += p[(long long)ks * 2048];
    z[b * 1000 + o] = fmaxf(s0 + s1 + bias[o], 0.f);
}

// ---------------- fc2 -------------------------------------------------------
__global__ __launch_bounds__(256) void fc2_v2(const float* __restrict__ z,
                                              const float* __restrict__ w,
                                              const float* __restrict__ bias,
                                              float* __restrict__ ys) {
    int gid = blockIdx.x * 4 + (threadIdx.x >> 6);
    int lane = threadIdx.x & 63;
    if (gid >= 960) return;
    int b = gid / 30, o = gid - b * 30;
    const float* zr = z + (long long)b * 1000;
    const float* wr = w + (long long)o * 1000;
    float acc = 0.f;
    for (int k = lane; k < 1000; k += 64) acc = fmaf(zr[k], wr[k], acc);
    for (int off = 32; off > 0; off >>= 1) acc += __shfl_down(acc, off, 64);
    if (lane == 0) ys[gid] = acc + bias[o];
}

// ---------------- spline coefficients -> float4 per segment -----------------
__global__ void spline_coeff(const float* __restrict__ ysraw, const float* __restrict__ matrix,
                             float4* __restrict__ coef) {
    int r = threadIdx.x;
    if (r >= 96) return;
    const float h = 1.0f / 9.0f;
    float ya[10];
    int b = r / 3, ch = r % 3;
#pragma unroll
    for (int j = 0; j < 10; ++j)
        ya[j] = ysraw[b * 30 + ch * 10 + j] / 100.0f + (float)j / 9.0f;
    float M[10];
#pragma unroll
    for (int i = 0; i < 10; ++i) {
        float acc = 0.f;
#pragma unroll
        for (int j = 0; j < 10; ++j) acc = fmaf(matrix[i * 10 + j], ya[j], acc);
        M[i] = acc;
    }
#pragma unroll
    for (int k = 0; k < 9; ++k) {
        float a = (M[k + 1] - M[k]) / (6.0f * h);
        float bb = M[k] * 0.5f;
        float cc = (ya[k + 1] - ya[k]) / h - (M[k + 1] + 2.0f * M[k]) * (h / 6.0f);
        float dd = ya[k];
        coef[r * 9 + k] = make_float4(a, bb, cc, dd);
    }
}

// ---------------- spline eval: image (float4) + table in one kernel ---------
__global__ void eval_all(const float4* __restrict__ batch4, const float4* __restrict__ coef,
                         float4* __restrict__ out4, float* __restrict__ outt) {
    int idx = blockIdx.x * blockDim.x + threadIdx.x;
    const float h = 1.0f / 9.0f;
    if (idx < 1572864) {
        int plane = idx >> 14;
        float4 xv4 = batch4[idx];
        float xin[4] = {xv4.x, xv4.y, xv4.z, xv4.w};
        float xout[4];
#pragma unroll
        for (int e = 0; e < 4; ++e) {
            float xv = xin[e];
            int xi = (int)floorf(xv / h);
            xi = min(max(xi, 0), 8);
            float xf = xv - (float)xi * h;
            float4 cf = coef[plane * 9 + xi];
            xout[e] = fmaf(fmaf(fmaf(cf.x, xf, cf.y), xf, cf.z), xf, cf.w);
        }
        out4[idx] = make_float4(xout[0], xout[1], xout[2], xout[3]);
    } else {
        int t = idx - 1572864;
        if (t >= 96 * 255) return;
        int plane = t / 255;
        int j = t - plane * 255;
        float xv = (float)j / 255.0f;
        int xi = (int)floorf(xv / h);
        xi = min(max(xi, 0), 8);
        float xf = xv - (float)xi * h;
        float4 cf = coef[plane * 9 + xi];
        outt[t] = fmaf(fmaf(fmaf(cf.x, xf, cf.y), xf, cf.z), xf, cf.w);
    }
}

extern "C" void kernel_launch(void* const* d_in, const int* in_sizes, int n_in,
                              void* d_out, int out_size, void* d_ws, size_t ws_size,
                              hipStream_t stream) {
    const int B = 32;
    const float* batch = (const float*)d_in[0];
    const float* cw[5] = {(const float*)d_in[1], (const float*)d_in[5], (const float*)d_in[9],
                          (const float*)d_in[13], (const float*)d_in[17]};
    const float* cb[5] = {(const float*)d_in[2], (const float*)d_in[6], (const float*)d_in[10],
                          (const float*)d_in[14], (const float*)d_in[18]};
    const float* bg[5] = {(const float*)d_in[3], (const float*)d_in[7], (const float*)d_in[11],
                          (const float*)d_in[15], (const float*)d_in[19]};
    const float* bb[5] = {(const float*)d_in[4], (const float*)d_in[8], (const float*)d_in[12],
                          (const float*)d_in[16], (const float*)d_in[20]};
    const float* l1w = (const float*)d_in[21];
    const float* l1b = (const float*)d_in[22];
    const float* l2w = (const float*)d_in[23];
    const float* l2b = (const float*)d_in[24];
    const float* matrix = (const float*)d_in[25];

    float* f = (float*)d_ws;
    const size_t A_F = 8258048;
    const size_t Bq_F = 4064256;
    const size_t W_F = 589824;
    ushort_t* bufA = (ushort_t*)f;
    ushort_t* bufB = (ushort_t*)(f + A_F);
    ushort_t* Wf_bf = (ushort_t*)(f + A_F + Bq_F);
    float* effb  = f + A_F + Bq_F + W_F;   // 512
    float* scale = effb + 512;             // 512
    float* shift = scale + 512;            // 512
    float* part  = shift + 512;            // 524,288
    float* x5    = part + 524288;          // 802,816 (bf16 xB)
    float* pacc  = x5 + 802816;            // 3,686,400
    float* z1    = pacc + 3686400;         // 32,000
    float* ysb   = z1 + 32000;             // 960
    float4* coef = (float4*)(ysb + 960);

    const int Ci[5]   = {3, 32, 64, 128, 256};
    const int lgCi[5] = {0, 5, 6, 7, 8};
    const int Co[5]   = {32, 64, 128, 256, 512};
    const int Hi[5]   = {256, 127, 63, 31, 15};
    const int Ho[5]   = {127, 63, 31, 15, 7};
    const int Zl[5]   = {1, 1, 1, 2, 3};

    ushort_t* bufs[2] = {bufA, bufB};

    // layer 1
    conv1_direct<<<C1NB, 256, 0, stream>>>(batch, cw[0], cb[0], bufA);
    {
        long long total = (long long)B * 16129 * 32;
        stats_flat<<<STS, 256, 0, stream>>>(bufA, part, total, 32, STS);
        stats_final_w<<<8, 256, 0, stream>>>(part, bg[0], bb[0], scale, shift, 32, STS,
                                             1.0f / (float)(B * 16129));
    }

    // layers 2..5
    const ushort_t* cur = bufA;
    for (int l = 1; l < 5; ++l) {
        ushort_t* outb = bufs[l % 2];
        int K = Ci[l] * 9;
        int Kp = (K + 63) & ~63;
        int WB = (Co[l] * Kp + 255) / 256;
        int BBk = (Co[l] + 3) / 4;
        fold_fused<<<WB + BBk, 256, 0, stream>>>(cw[l], scale, shift, cb[l], Wf_bf, effb,
                                                 Ci[l], lgCi[l], K, Kp, Co[l], WB);
        int N = B * Ho[l] * Ho[l];
        int Z = Zl[l];
        int kcount = Kp / Z;
        dim3 grid((N + 127) / 128, Co[l] / 64, Z);
        if (Z == 1) {
            // conv epilogue emits per-block stats partials
            conv_mfma<<<grid, 256, 0, stream>>>(cur, Wf_bf, effb, outb, nullptr, part,
                                                B, Ci[l], lgCi[l], Hi[l], Hi[l], Co[l],
                                                Ho[l], Ho[l], K, Kp, kcount, grid.x);
            stats_final_w<<<(Co[l] + 3) / 4, 256, 0, stream>>>(
                part, bg[l], bb[l], scale, shift, Co[l], grid.x, 1.0f / (float)N);
        } else {
            conv_mfma<<<grid, 256, 0, stream>>>(cur, Wf_bf, effb, nullptr, pacc, nullptr,
                                                B, Ci[l], lgCi[l], Hi[l], Hi[l], Co[l],
                                                Ho[l], Ho[l], K, Kp, kcount, 0);
            long long total = (long long)N * Co[l];
            convz_stats<<<512, 256, 0, stream>>>(pacc, effb, outb, part, total, Co[l], Z);
            stats_final_w<<<(Co[l] + 3) / 4, 256, 0, stream>>>(
                part, bg[l], bb[l], scale, shift, Co[l], 512, 1.0f / (float)N);
        }
        cur = outb;
    }

    ushort_t* xB = (ushort_t*)x5;
    bn_apply_x<<<(802816 + 255) / 256, 256, 0, stream>>>(cur, scale, shift, xB);
    {
        dim3 grid(FC1_KS, 16);
        fc1_mfma<<<grid, 256, 0, stream>>>(l1w, xB, pacc);
    }
    fc1_reduce<<<(32000 + 255) / 256, 256, 0, stream>>>(pacc, l1b, z1);
    fc2_v2<<<240, 256, 0, stream>>>(z1, l2w, l2b, ysb);
    spline_coeff<<<1, 96, 0, stream>>>(ysb, matrix, coef);

    float* out = (float*)d_out;
    int evtot = 1572864 + 96 * 255;
    eval_all<<<(evtot + 255) / 256, 256, 0, stream>>>((const float4*)batch, coef,
                                                      (float4*)out, out + 6291456);
}

// Round 14
// 238.313 us; speedup vs baseline: 3.8744x; 1.0315x over previous
//
#include <hip/hip_runtime.h>
#include <hip/hip_bf16.h>

#define BEPS 1e-5f
#define FC1_KS 98
#define FC1_KC 256
#define C1NB 2017
#define STS 512

typedef __attribute__((ext_vector_type(8))) short short8v;
typedef __attribute__((ext_vector_type(4))) float f32x4;
typedef unsigned short ushort_t;

__device__ __forceinline__ float bf2f(ushort_t u) {
    unsigned int x = ((unsigned int)u) << 16;
    return __builtin_bit_cast(float, x);
}
__device__ __forceinline__ ushort_t f2bf(float v) {
    __hip_bfloat16 h = __float2bfloat16(v);
    return *(ushort_t*)&h;
}

// ---------------- conv1: direct fp32, NHWC bf16 out -------------------------
__global__ __launch_bounds__(256) void conv1_direct(
    const float* __restrict__ in, const float* __restrict__ w,
    const float* __restrict__ bias, ushort_t* __restrict__ out) {
    __shared__ float ws[864];
    __shared__ float bs[32];
    const int tid = threadIdx.x;
    for (int i = tid; i < 864; i += 256) ws[i] = w[i];
    if (tid < 32) bs[tid] = bias[tid];
    __syncthreads();

    const int TOT = 32 * 16129;
    int p = blockIdx.x * 256 + tid;
    if (p >= TOT) return;
    int b = p / 16129, pp = p - b * 16129;
    int i = pp / 127, j = pp - i * 127;
    const float* ib = in + ((long long)b * 3) * 65536 + (2 * i) * 256 + 2 * j;
    float patch[27];
#pragma unroll
    for (int ci = 0; ci < 3; ++ci)
#pragma unroll
        for (int di = 0; di < 3; ++di) {
            const float* rp = ib + ci * 65536 + di * 256;
            float2 v01 = *(const float2*)rp;
            patch[ci * 9 + di * 3 + 0] = v01.x;
            patch[ci * 9 + di * 3 + 1] = v01.y;
            patch[ci * 9 + di * 3 + 2] = rp[2];
        }

    ushort_t res[32];
#pragma unroll
    for (int co = 0; co < 32; co += 4) {
        float a0 = bs[co], a1 = bs[co + 1], a2 = bs[co + 2], a3 = bs[co + 3];
#pragma unroll
        for (int t = 0; t < 27; ++t) {
            float pv = patch[t];
            a0 = fmaf(pv, ws[(co + 0) * 27 + t], a0);
            a1 = fmaf(pv, ws[(co + 1) * 27 + t], a1);
            a2 = fmaf(pv, ws[(co + 2) * 27 + t], a2);
            a3 = fmaf(pv, ws[(co + 3) * 27 + t], a3);
        }
        res[co + 0] = f2bf(fmaxf(a0, 0.f));
        res[co + 1] = f2bf(fmaxf(a1, 0.f));
        res[co + 2] = f2bf(fmaxf(a2, 0.f));
        res[co + 3] = f2bf(fmaxf(a3, 0.f));
    }
    ushort_t* ob = out + (long long)p * 32;
#pragma unroll
    for (int v = 0; v < 4; ++v)
        *(short8v*)&ob[v * 8] = *(const short8v*)&res[v * 8];
}

// ---------------- convs 2-5: NHWC bf16 MFMA, register-prefetch pipeline -----
__global__ __launch_bounds__(256) void conv_mfma(
    const ushort_t* __restrict__ in, const ushort_t* __restrict__ wf,
    const float* __restrict__ effb, ushort_t* __restrict__ out,
    float* __restrict__ pacc, float* __restrict__ spart,
    int B, int Ci, int lgCi, int Hi, int Wi, int Co, int Ho, int Wo,
    int K, int Kp, int kcount, int Spart) {
    const int HoWo = Ho * Wo;
    const int N = B * HoWo;
    __shared__ __align__(16) ushort_t As[64 * 64];
    __shared__ __align__(16) ushort_t Bs[128 * 64];
    const int tid = threadIdx.x;
    const int m0 = blockIdx.y * 64;
    const int n0 = blockIdx.x * 128;
    const int kbeg = blockIdx.z * kcount;

    const int rowA = tid >> 2;
    const int kqA = (tid & 3) * 16;
    const ushort_t* wrowA = wf + (long long)(m0 + rowA) * Kp + kbeg + kqA;
    const int swA = (rowA & 7) << 3;
    const int rowB = tid >> 1;
    const int kqB = (tid & 1) * 32;
    const int n = n0 + rowB;
    const int nn = (n < N) ? n : (N - 1);
    const int pb = nn / HoWo, pp = nn - pb * HoWo;
    const int pi = pp / Wo, pj = pp - pi * Wo;
    const long long base0 = ((long long)pb * Hi + 2 * pi) * Wi + 2 * pj;
    const int swB = (rowB & 7) << 3;

    const int w = tid >> 6;
    const int lane = tid & 63;
    const int wco = (w >> 1) * 32, wpx = (w & 1) * 64;
    const int lm = lane & 15, lk = lane >> 4;

    short8v rA0, rA1, rB[4];
    // prologue: load k0=0 into regs
    rA0 = *(const short8v*)(wrowA);
    rA1 = *(const short8v*)(wrowA + 8);
#pragma unroll
    for (int ch = 0; ch < 2; ++ch) {
        int c16 = kqB + ch * 16;
        int kg = kbeg + c16;
        int tap = kg >> lgCi;
        tap = tap > 8 ? 8 : tap;
        int ci0 = kg & (Ci - 1);
        int dy = tap / 3, dx = tap - dy * 3;
        const ushort_t* src = in + (base0 + dy * Wi + dx) * Ci + ci0;
        rB[ch * 2] = *(const short8v*)src;
        rB[ch * 2 + 1] = *(const short8v*)(src + 8);
    }

    f32x4 acc[2][4] = {};
    for (int k0 = 0; k0 < kcount; k0 += 64) {
        // write prefetched regs to LDS
        *(short8v*)&As[rowA * 64 + ((kqA + 0) ^ swA)] = rA0;
        *(short8v*)&As[rowA * 64 + ((kqA + 8) ^ swA)] = rA1;
#pragma unroll
        for (int ch = 0; ch < 2; ++ch) {
            int c16 = kqB + ch * 16;
            *(short8v*)&Bs[rowB * 64 + ((c16 + 0) ^ swB)] = rB[ch * 2];
            *(short8v*)&Bs[rowB * 64 + ((c16 + 8) ^ swB)] = rB[ch * 2 + 1];
        }
        __syncthreads();
        // issue next K-step's global loads; latency hides under MFMA below
        int k1 = k0 + 64;
        if (k1 < kcount) {
            rA0 = *(const short8v*)(wrowA + k1);
            rA1 = *(const short8v*)(wrowA + k1 + 8);
#pragma unroll
            for (int ch = 0; ch < 2; ++ch) {
                int c16 = kqB + ch * 16;
                int kg = kbeg + k1 + c16;
                int tap = kg >> lgCi;
                tap = tap > 8 ? 8 : tap;
                int ci0 = kg & (Ci - 1);
                int dy = tap / 3, dx = tap - dy * 3;
                const ushort_t* src = in + (base0 + dy * Wi + dx) * Ci + ci0;
                rB[ch * 2] = *(const short8v*)src;
                rB[ch * 2 + 1] = *(const short8v*)(src + 8);
            }
        }
#pragma unroll
        for (int kk = 0; kk < 2; ++kk) {
            const int kb = kk * 32 + lk * 8;
            const int ra0 = wco + lm, ra1 = wco + 16 + lm;
            short8v a0 = *(const short8v*)&As[ra0 * 64 + (kb ^ ((ra0 & 7) << 3))];
            short8v a1 = *(const short8v*)&As[ra1 * 64 + (kb ^ ((ra1 & 7) << 3))];
            const int rb0 = wpx + lm, rb1 = wpx + 16 + lm;
            const int rb2 = wpx + 32 + lm, rb3 = wpx + 48 + lm;
            short8v b0 = *(const short8v*)&Bs[rb0 * 64 + (kb ^ ((rb0 & 7) << 3))];
            short8v b1 = *(const short8v*)&Bs[rb1 * 64 + (kb ^ ((rb1 & 7) << 3))];
            short8v b2 = *(const short8v*)&Bs[rb2 * 64 + (kb ^ ((rb2 & 7) << 3))];
            short8v b3 = *(const short8v*)&Bs[rb3 * 64 + (kb ^ ((rb3 & 7) << 3))];
            acc[0][0] = __builtin_amdgcn_mfma_f32_16x16x32_bf16(a0, b0, acc[0][0], 0, 0, 0);
            acc[0][1] = __builtin_amdgcn_mfma_f32_16x16x32_bf16(a0, b1, acc[0][1], 0, 0, 0);
            acc[0][2] = __builtin_amdgcn_mfma_f32_16x16x32_bf16(a0, b2, acc[0][2], 0, 0, 0);
            acc[0][3] = __builtin_amdgcn_mfma_f32_16x16x32_bf16(a0, b3, acc[0][3], 0, 0, 0);
            acc[1][0] = __builtin_amdgcn_mfma_f32_16x16x32_bf16(a1, b0, acc[1][0], 0, 0, 0);
            acc[1][1] = __builtin_amdgcn_mfma_f32_16x16x32_bf16(a1, b1, acc[1][1], 0, 0, 0);
            acc[1][2] = __builtin_amdgcn_mfma_f32_16x16x32_bf16(a1, b2, acc[1][2], 0, 0, 0);
            acc[1][3] = __builtin_amdgcn_mfma_f32_16x16x32_bf16(a1, b3, acc[1][3], 0, 0, 0);
        }
        __syncthreads();
    }
    if (pacc) {
        float* pbuf = pacc + ((long long)blockIdx.z * N) * Co;
#pragma unroll
        for (int nb = 0; nb < 4; ++nb) {
            int np = n0 + wpx + nb * 16 + lm;
            if (np >= N) continue;
#pragma unroll
            for (int amr = 0; amr < 2; ++amr) {
                int cobase = m0 + wco + amr * 16 + lk * 4;
                float4 vv = make_float4(acc[amr][nb][0], acc[amr][nb][1],
                                        acc[amr][nb][2], acc[amr][nb][3]);
                *(float4*)&pbuf[(long long)np * Co + cobase] = vv;
            }
        }
    } else {
        float ssum[2][4] = {}, ssq[2][4] = {};
#pragma unroll
        for (int nb = 0; nb < 4; ++nb) {
            int np = n0 + wpx + nb * 16 + lm;
            bool val = (np < N);
#pragma unroll
            for (int amr = 0; amr < 2; ++amr) {
                int cobase = m0 + wco + amr * 16 + lk * 4;
                float4 eb = *(const float4*)&effb[cobase];
                float v0 = fmaxf(acc[amr][nb][0] + eb.x, 0.f);
                float v1 = fmaxf(acc[amr][nb][1] + eb.y, 0.f);
                float v2 = fmaxf(acc[amr][nb][2] + eb.z, 0.f);
                float v3 = fmaxf(acc[amr][nb][3] + eb.w, 0.f);
                if (val) {
                    ushort4 u;
                    u.x = f2bf(v0); u.y = f2bf(v1); u.z = f2bf(v2); u.w = f2bf(v3);
                    *(ushort4*)&out[(long long)np * Co + cobase] = u;
                    ssum[amr][0] += v0; ssq[amr][0] = fmaf(v0, v0, ssq[amr][0]);
                    ssum[amr][1] += v1; ssq[amr][1] = fmaf(v1, v1, ssq[amr][1]);
                    ssum[amr][2] += v2; ssq[amr][2] = fmaf(v2, v2, ssq[amr][2]);
                    ssum[amr][3] += v3; ssq[amr][3] = fmaf(v3, v3, ssq[amr][3]);
                }
            }
        }
#pragma unroll
        for (int mm = 1; mm < 16; mm <<= 1) {
#pragma unroll
            for (int amr = 0; amr < 2; ++amr)
#pragma unroll
                for (int r = 0; r < 4; ++r) {
                    ssum[amr][r] += __shfl_xor(ssum[amr][r], mm, 64);
                    ssq[amr][r] += __shfl_xor(ssq[amr][r], mm, 64);
                }
        }
        __shared__ float lss[4][32], lsq[4][32];
        if (lm == 0) {
#pragma unroll
            for (int amr = 0; amr < 2; ++amr)
#pragma unroll
                for (int r = 0; r < 4; ++r) {
                    lss[w][amr * 16 + lk * 4 + r] = ssum[amr][r];
                    lsq[w][amr * 16 + lk * 4 + r] = ssq[amr][r];
                }
        }
        __syncthreads();
        if (tid < 64) {
            int half = tid >> 5, c32 = tid & 31;
            float s = lss[half * 2][c32] + lss[half * 2 + 1][c32];
            float q = lsq[half * 2][c32] + lsq[half * 2 + 1][c32];
            int c = m0 + half * 32 + c32;
            spart[((long long)c * Spart + blockIdx.x) * 2 + 0] = s;
            spart[((long long)c * Spart + blockIdx.x) * 2 + 1] = q;
        }
    }
}

// ---- K-split reduce + bias + relu + stats partials (l5), grid-stride -------
__global__ __launch_bounds__(256) void convz_stats(
    const float* __restrict__ pacc, const float* __restrict__ effb,
    ushort_t* __restrict__ out, float* __restrict__ part,
    long long total, int Co, int Z) {
    const int tid = threadIdx.x;
    const int c0 = (tid * 8) & (Co - 1);
    float eb[8];
    {
        float4 e0 = *(const float4*)&effb[c0];
        float4 e1 = *(const float4*)&effb[c0 + 4];
        eb[0] = e0.x; eb[1] = e0.y; eb[2] = e0.z; eb[3] = e0.w;
        eb[4] = e1.x; eb[5] = e1.y; eb[6] = e1.z; eb[7] = e1.w;
    }
    float sum[8] = {}, sq[8] = {};
    const long long nchunk = total >> 11;
    for (long long g = blockIdx.x; g < nchunk; g += 512) {
        long long off = (g << 11) + tid * 8;
        float v[8];
#pragma unroll
        for (int j = 0; j < 8; ++j) v[j] = eb[j];
        for (int z = 0; z < Z; ++z) {
            const float* pz = pacc + (long long)z * total + off;
            float4 a = *(const float4*)pz;
            float4 b2 = *(const float4*)(pz + 4);
            v[0] += a.x; v[1] += a.y; v[2] += a.z; v[3] += a.w;
            v[4] += b2.x; v[5] += b2.y; v[6] += b2.z; v[7] += b2.w;
        }
        short8v o;
#pragma unroll
        for (int j = 0; j < 8; ++j) {
            float r = fmaxf(v[j], 0.f);
            o[j] = (short)f2bf(r);
            sum[j] += r;
            sq[j] = fmaf(r, r, sq[j]);
        }
        *(short8v*)&out[off] = o;
    }
    __shared__ float rs[256][8], rq[256][8];
#pragma unroll
    for (int j = 0; j < 8; ++j) { rs[tid][j] = sum[j]; rq[tid][j] = sq[j]; }
    __syncthreads();
    const int G = Co >> 3;
    const int TPG = 256 / G;
    for (int c = tid; c < Co; c += 256) {
        int grp = c >> 3, j = c & 7;
        float s = 0.f, q = 0.f;
        for (int i = 0; i < TPG; ++i) {
            s += rs[grp + i * G][j];
            q += rq[grp + i * G][j];
        }
        part[(c * 512 + blockIdx.x) * 2 + 0] = s;
        part[(c * 512 + blockIdx.x) * 2 + 1] = q;
    }
}

// ---------------- BN stats: flat NHWC, short8 loads (layer 1) ---------------
__global__ __launch_bounds__(256) void stats_flat(
    const ushort_t* __restrict__ y, float* __restrict__ part,
    long long total, int C, int S) {
    const int tid = threadIdx.x;
    float sum[8] = {}, sq[8] = {};
    const long long nchunk = (total + 2047) >> 11;
    for (long long g = blockIdx.x; g < nchunk; g += S) {
        long long off = (g << 11) + tid * 8;
        if (off + 8 <= total) {
            short8v v8 = *(const short8v*)(y + off);
#pragma unroll
            for (int j = 0; j < 8; ++j) {
                float v = bf2f((ushort_t)v8[j]);
                sum[j] += v;
                sq[j] = fmaf(v, v, sq[j]);
            }
        }
    }
    __shared__ float rs[256][8], rq[256][8];
#pragma unroll
    for (int j = 0; j < 8; ++j) { rs[tid][j] = sum[j]; rq[tid][j] = sq[j]; }
    __syncthreads();
    const int G = C >> 3;
    const int TPG = 256 / G;
    for (int c = tid; c < C; c += 256) {
        int grp = c >> 3, j = c & 7;
        float s = 0.f, q = 0.f;
        for (int i = 0; i < TPG; ++i) {
            s += rs[grp + i * G][j];
            q += rq[grp + i * G][j];
        }
        part[(c * S + blockIdx.x) * 2 + 0] = s;
        part[(c * S + blockIdx.x) * 2 + 1] = q;
    }
}

// wave-parallel stats finalize
__global__ __launch_bounds__(256) void stats_final_w(
    const float* __restrict__ part, const float* __restrict__ g,
    const float* __restrict__ be, float* __restrict__ scale,
    float* __restrict__ shift, int C, int S, float invN) {
    int c = blockIdx.x * 4 + (threadIdx.x >> 6);
    int lane = threadIdx.x & 63;
    if (c >= C) return;
    float s = 0.f, q = 0.f;
    for (int i = lane; i < S; i += 64) {
        s += part[((long long)c * S + i) * 2 + 0];
        q += part[((long long)c * S + i) * 2 + 1];
    }
#pragma unroll
    for (int off = 32; off > 0; off >>= 1) {
        s += __shfl_down(s, off, 64);
        q += __shfl_down(q, off, 64);
    }
    if (lane == 0) {
        float m = s * invN;
        float v = q * invN - m * m;
        float inv = rsqrtf(v + BEPS);
        float sc = g[c] * inv;
        scale[c] = sc;
        shift[c] = be[c] - m * sc;
    }
}

// ---------------- fused BN fold: weights (grid head) + bias (grid tail) -----
__global__ __launch_bounds__(256) void fold_fused(
    const float* __restrict__ w, const float* __restrict__ scale,
    const float* __restrict__ shift, const float* __restrict__ bias,
    ushort_t* __restrict__ wout, float* __restrict__ effb,
    int Ci, int lgCi, int K, int Kp, int Co, int WB) {
    if ((int)blockIdx.x < WB) {
        int idx = blockIdx.x * 256 + threadIdx.x;
        if (idx >= Co * Kp) return;
        int co = idx / Kp, k = idx - co * Kp;
        ushort_t o = 0;
        if (k < K) {
            int tap = k >> lgCi;
            int ci = k & (Ci - 1);
            o = f2bf(w[((long long)co * Ci + ci) * 9 + tap] * scale[ci]);
        }
        wout[idx] = o;
    } else {
        int co = ((int)blockIdx.x - WB) * 4 + (threadIdx.x >> 6);
        int lane = threadIdx.x & 63;
        if (co >= Co) return;
        const int CK = Ci * 9;
        const float* wr = w + (long long)co * CK;
        float acc = 0.f;
        for (int k = lane; k < CK; k += 64) acc = fmaf(wr[k], shift[k / 9], acc);
#pragma unroll
        for (int off = 32; off > 0; off >>= 1) acc += __shfl_down(acc, off, 64);
        if (lane == 0) effb[co] = acc + bias[co];
    }
}

// ---------------- BN apply conv5 NHWC out -> xB bf16 [32][25088] ------------
__global__ void bn_apply_x(const ushort_t* __restrict__ y, const float* __restrict__ scale,
                           const float* __restrict__ shift, ushort_t* __restrict__ xB) {
    int idx = blockIdx.x * blockDim.x + threadIdx.x;
    if (idx >= 802816) return;
    int b = idx / 25088, k = idx - b * 25088;
    int c = k / 49, p = k - c * 49;
    float v = bf2f(y[((long long)b * 49 + p) * 512 + c]);
    xB[idx] = f2bf(fmaf(v, scale[c], shift[c]));
}

// ---------------- fc1 split-K MFMA GEMM (W fp32 -> bf16 inline) -------------
__global__ __launch_bounds__(256) void fc1_mfma(
    const float* __restrict__ w, const ushort_t* __restrict__ xB,
    float* __restrict__ part) {
    const int K = 25088;
    __shared__ __align__(16) ushort_t As[64 * 256];
    __shared__ __align__(16) ushort_t Bs[32 * 256];
    const int tid = threadIdx.x;
    const int m0 = blockIdx.y * 64;
    const int kbeg = blockIdx.x * FC1_KC;

    {
        const int r = tid >> 2;
        const int kq = (tid & 3) * 64;
        const int m = m0 + r;
        const bool mv = (m < 1000);
        const float* wr = w + (long long)m * K + kbeg + kq;
        const int sw = (r & 7) << 3;
#pragma unroll
        for (int g = 0; g < 8; ++g) {
            short8v o = {0, 0, 0, 0, 0, 0, 0, 0};
            if (mv) {
                float4 f0 = *(const float4*)(wr + g * 8);
                float4 f1 = *(const float4*)(wr + g * 8 + 4);
                o[0] = (short)f2bf(f0.x); o[1] = (short)f2bf(f0.y);
                o[2] = (short)f2bf(f0.z); o[3] = (short)f2bf(f0.w);
                o[4] = (short)f2bf(f1.x); o[5] = (short)f2bf(f1.y);
                o[6] = (short)f2bf(f1.z); o[7] = (short)f2bf(f1.w);
            }
            *(short8v*)&As[r * 256 + ((kq + g * 8) ^ sw)] = o;
        }
    }
    {
        const int b = tid >> 3;
        const int kq = (tid & 7) * 32;
        const ushort_t* xr = xB + (long long)b * K + kbeg + kq;
        const int sw = (b & 7) << 3;
#pragma unroll
        for (int g = 0; g < 4; ++g) {
            short8v v = *(const short8v*)(xr + g * 8);
            *(short8v*)&Bs[b * 256 + ((kq + g * 8) ^ sw)] = v;
        }
    }
    __syncthreads();
    const int wv = tid >> 6, lane = tid & 63;
    const int lm = lane & 15, lk = lane >> 4;
    const int wm = wv * 16;
    f32x4 acc0 = {}, acc1 = {};
    const int ra = wm + lm;
    const int swa = (ra & 7) << 3;
    const int swb = (lm & 7) << 3;
#pragma unroll
    for (int s = 0; s < 8; ++s) {
        int kb = s * 32 + lk * 8;
        short8v av = *(const short8v*)&As[ra * 256 + (kb ^ swa)];
        short8v b0 = *(const short8v*)&Bs[lm * 256 + (kb ^ swb)];
        short8v b1 = *(const short8v*)&Bs[(16 + lm) * 256 + (kb ^ swb)];
        acc0 = __builtin_amdgcn_mfma_f32_16x16x32_bf16(av, b0, acc0, 0, 0, 0);
        acc1 = __builtin_amdgcn_mfma_f32_16x16x32_bf16(av, b1, acc1, 0, 0, 0);
    }
    float* pb = part + ((long long)blockIdx.y * FC1_KS + blockIdx.x) * 2048;
#pragma unroll
    for (int r = 0; r < 4; ++r) {
        pb[(wm + lk * 4 + r) * 32 + lm] = acc0[r];
        pb[(wm + lk * 4 + r) * 32 + 16 + lm] = acc1[r];
    }
}

__global__ void fc1_reduce(const float* __restrict__ part, const float* __restrict__ bias,
                           float* __restrict__ z) {
    int idx = blockIdx.x * blockDim.x + threadIdx.x;
    if (idx >= 32000) return;
    int o = idx >> 5, b = idx & 31;
    int mt = o >> 6, mr = o & 63;
    const float* p = part + ((long long)mt * FC1_KS) * 2048 + mr * 32 + b;
    float s0 = 0.f, s1 = 0.f;
    int ks = 0;
    for (; ks + 1 < FC1_KS; ks += 2) {
        s0 += p[(long long)ks * 2048];
        s1 += p[(long long)(ks + 1) * 2048];
    }
    for (; ks < FC1_KS; ++ks) s0 += p[(long long)ks * 2048];
    z[b * 1000 + o] = fmaxf(s0 + s1 + bias[o], 0.f);
}

// ---------------- fc2 -------------------------------------------------------
__global__ __launch_bounds__(256) void fc2_v2(const float* __restrict__ z,
                                              const float* __restrict__ w,
                                              const float* __restrict__ bias,
                                              float* __restrict__ ys) {
    int gid = blockIdx.x * 4 + (threadIdx.x >> 6);
    int lane = threadIdx.x & 63;
    if (gid >= 960) return;
    int b = gid / 30, o = gid - b * 30;
    const float* zr = z + (long long)b * 1000;
    const float* wr = w + (long long)o * 1000;
    float acc = 0.f;
    for (int k = lane; k < 1000; k += 64) acc = fmaf(zr[k], wr[k], acc);
    for (int off = 32; off > 0; off >>= 1) acc += __shfl_down(acc, off, 64);
    if (lane == 0) ys[gid] = acc + bias[o];
}

// ---------------- spline coefficients -> float4 per segment -----------------
__global__ void spline_coeff(const float* __restrict__ ysraw, const float* __restrict__ matrix,
                             float4* __restrict__ coef) {
    int r = threadIdx.x;
    if (r >= 96) return;
    const float h = 1.0f / 9.0f;
    float ya[10];
    int b = r / 3, ch = r % 3;
#pragma unroll
    for (int j = 0; j < 10; ++j)
        ya[j] = ysraw[b * 30 + ch * 10 + j] / 100.0f + (float)j / 9.0f;
    float M[10];
#pragma unroll
    for (int i = 0; i < 10; ++i) {
        float acc = 0.f;
#pragma unroll
        for (int j = 0; j < 10; ++j) acc = fmaf(matrix[i * 10 + j], ya[j], acc);
        M[i] = acc;
    }
#pragma unroll
    for (int k = 0; k < 9; ++k) {
        float a = (M[k + 1] - M[k]) / (6.0f * h);
        float bb = M[k] * 0.5f;
        float cc = (ya[k + 1] - ya[k]) / h - (M[k + 1] + 2.0f * M[k]) * (h / 6.0f);
        float dd = ya[k];
        coef[r * 9 + k] = make_float4(a, bb, cc, dd);
    }
}

// ---------------- spline eval: image (float4) + table in one kernel ---------
__global__ void eval_all(const float4* __restrict__ batch4, const float4* __restrict__ coef,
                         float4* __restrict__ out4, float* __restrict__ outt) {
    int idx = blockIdx.x * blockDim.x + threadIdx.x;
    const float h = 1.0f / 9.0f;
    if (idx < 1572864) {
        int plane = idx >> 14;
        float4 xv4 = batch4[idx];
        float xin[4] = {xv4.x, xv4.y, xv4.z, xv4.w};
        float xout[4];
#pragma unroll
        for (int e = 0; e < 4; ++e) {
            float xv = xin[e];
            int xi = (int)floorf(xv / h);
            xi = min(max(xi, 0), 8);
            float xf = xv - (float)xi * h;
            float4 cf = coef[plane * 9 + xi];
            xout[e] = fmaf(fmaf(fmaf(cf.x, xf, cf.y), xf, cf.z), xf, cf.w);
        }
        out4[idx] = make_float4(xout[0], xout[1], xout[2], xout[3]);
    } else {
        int t = idx - 1572864;
        if (t >= 96 * 255) return;
        int plane = t / 255;
        int j = t - plane * 255;
        float xv = (float)j / 255.0f;
        int xi = (int)floorf(xv / h);
        xi = min(max(xi, 0), 8);
        float xf = xv - (float)xi * h;
        float4 cf = coef[plane * 9 + xi];
        outt[t] = fmaf(fmaf(fmaf(cf.x, xf, cf.y), xf, cf.z), xf, cf.w);
    }
}

extern "C" void kernel_launch(void* const* d_in, const int* in_sizes, int n_in,
                              void* d_out, int out_size, void* d_ws, size_t ws_size,
                              hipStream_t stream) {
    const int B = 32;
    const float* batch = (const float*)d_in[0];
    const float* cw[5] = {(const float*)d_in[1], (const float*)d_in[5], (const float*)d_in[9],
                          (const float*)d_in[13], (const float*)d_in[17]};
    const float* cb[5] = {(const float*)d_in[2], (const float*)d_in[6], (const float*)d_in[10],
                          (const float*)d_in[14], (const float*)d_in[18]};
    const float* bg[5] = {(const float*)d_in[3], (const float*)d_in[7], (const float*)d_in[11],
                          (const float*)d_in[15], (const float*)d_in[19]};
    const float* bb[5] = {(const float*)d_in[4], (const float*)d_in[8], (const float*)d_in[12],
                          (const float*)d_in[16], (const float*)d_in[20]};
    const float* l1w = (const float*)d_in[21];
    const float* l1b = (const float*)d_in[22];
    const float* l2w = (const float*)d_in[23];
    const float* l2b = (const float*)d_in[24];
    const float* matrix = (const float*)d_in[25];

    float* f = (float*)d_ws;
    const size_t A_F = 8258048;
    const size_t Bq_F = 4064256;
    const size_t W_F = 589824;
    ushort_t* bufA = (ushort_t*)f;
    ushort_t* bufB = (ushort_t*)(f + A_F);
    ushort_t* Wf_bf = (ushort_t*)(f + A_F + Bq_F);
    float* effb  = f + A_F + Bq_F + W_F;   // 512
    float* scale = effb + 512;             // 512
    float* shift = scale + 512;            // 512
    float* part  = shift + 512;            // 524,288
    float* x5    = part + 524288;          // 802,816 (bf16 xB)
    float* pacc  = x5 + 802816;            // 3,686,400
    float* z1    = pacc + 3686400;         // 32,000
    float* ysb   = z1 + 32000;             // 960
    float4* coef = (float4*)(ysb + 960);

    const int Ci[5]   = {3, 32, 64, 128, 256};
    const int lgCi[5] = {0, 5, 6, 7, 8};
    const int Co[5]   = {32, 64, 128, 256, 512};
    const int Hi[5]   = {256, 127, 63, 31, 15};
    const int Ho[5]   = {127, 63, 31, 15, 7};
    const int Zl[5]   = {1, 1, 1, 1, 3};   // l4 now single-pass (fused stats)

    ushort_t* bufs[2] = {bufA, bufB};

    // layer 1
    conv1_direct<<<C1NB, 256, 0, stream>>>(batch, cw[0], cb[0], bufA);
    {
        long long total = (long long)B * 16129 * 32;
        stats_flat<<<STS, 256, 0, stream>>>(bufA, part, total, 32, STS);
        stats_final_w<<<8, 256, 0, stream>>>(part, bg[0], bb[0], scale, shift, 32, STS,
                                             1.0f / (float)(B * 16129));
    }

    // layers 2..5
    const ushort_t* cur = bufA;
    for (int l = 1; l < 5; ++l) {
        ushort_t* outb = bufs[l % 2];
        int K = Ci[l] * 9;
        int Kp = (K + 63) & ~63;
        int WB = (Co[l] * Kp + 255) / 256;
        int BBk = (Co[l] + 3) / 4;
        fold_fused<<<WB + BBk, 256, 0, stream>>>(cw[l], scale, shift, cb[l], Wf_bf, effb,
                                                 Ci[l], lgCi[l], K, Kp, Co[l], WB);
        int N = B * Ho[l] * Ho[l];
        int Z = Zl[l];
        int kcount = Kp / Z;
        dim3 grid((N + 127) / 128, Co[l] / 64, Z);
        if (Z == 1) {
            conv_mfma<<<grid, 256, 0, stream>>>(cur, Wf_bf, effb, outb, nullptr, part,
                                                B, Ci[l], lgCi[l], Hi[l], Hi[l], Co[l],
                                                Ho[l], Ho[l], K, Kp, kcount, grid.x);
            stats_final_w<<<(Co[l] + 3) / 4, 256, 0, stream>>>(
                part, bg[l], bb[l], scale, shift, Co[l], grid.x, 1.0f / (float)N);
        } else {
            conv_mfma<<<grid, 256, 0, stream>>>(cur, Wf_bf, effb, nullptr, pacc, nullptr,
                                                B, Ci[l], lgCi[l], Hi[l], Hi[l], Co[l],
                                                Ho[l], Ho[l], K, Kp, kcount, 0);
            long long total = (long long)N * Co[l];
            convz_stats<<<512, 256, 0, stream>>>(pacc, effb, outb, part, total, Co[l], Z);
            stats_final_w<<<(Co[l] + 3) / 4, 256, 0, stream>>>(
                part, bg[l], bb[l], scale, shift, Co[l], 512, 1.0f / (float)N);
        }
        cur = outb;
    }

    ushort_t* xB = (ushort_t*)x5;
    bn_apply_x<<<(802816 + 255) / 256, 256, 0, stream>>>(cur, scale, shift, xB);
    {
        dim3 grid(FC1_KS, 16);
        fc1_mfma<<<grid, 256, 0, stream>>>(l1w, xB, pacc);
    }
    fc1_reduce<<<(32000 + 255) / 256, 256, 0, stream>>>(pacc, l1b, z1);
    fc2_v2<<<240, 256, 0, stream>>>(z1, l2w, l2b, ysb);
    spline_coeff<<<1, 96, 0, stream>>>(ysb, matrix, coef);

    float* out = (float*)d_out;
    int evtot = 1572864 + 96 * 255;
    eval_all<<<(evtot + 255) / 256, 256, 0, stream>>>((const float4*)batch, coef,
                                                      (float4*)out, out + 6291456);
}

// Round 15
// 237.340 us; speedup vs baseline: 3.8903x; 1.0041x over previous
//
#include <hip/hip_runtime.h>
#include <hip/hip_bf16.h>

#define BEPS 1e-5f
#define FC1_KS 98
#define FC1_KC 256
#define C1NB 2017
#define STS 512

typedef __attribute__((ext_vector_type(8))) short short8v;
typedef __attribute__((ext_vector_type(4))) float f32x4;
typedef unsigned short ushort_t;

__device__ __forceinline__ float bf2f(ushort_t u) {
    unsigned int x = ((unsigned int)u) << 16;
    return __builtin_bit_cast(float, x);
}
__device__ __forceinline__ ushort_t f2bf(float v) {
    __hip_bfloat16 h = __float2bfloat16(v);
    return *(ushort_t*)&h;
}

// ---------------- conv1: direct fp32, NHWC bf16 out, fused BN-stats ---------
// stats via LDS transpose: tp[p][c] (pad 36), 8 threads/channel reduce.
__global__ __launch_bounds__(256) void conv1_direct(
    const float* __restrict__ in, const float* __restrict__ w,
    const float* __restrict__ bias, ushort_t* __restrict__ out,
    float* __restrict__ part) {
    __shared__ float ws[864];
    __shared__ float bs[32];
    __shared__ float tp[256 * 36];
    __shared__ float ps[8][32], pq[8][32];
    const int tid = threadIdx.x;
    for (int i = tid; i < 864; i += 256) ws[i] = w[i];
    if (tid < 32) bs[tid] = bias[tid];
    __syncthreads();

    const int TOT = 32 * 16129;
    int p = blockIdx.x * 256 + tid;
    const bool valid = (p < TOT);
    int pc = valid ? p : (TOT - 1);
    int b = pc / 16129, pp = pc - b * 16129;
    int i = pp / 127, j = pp - i * 127;
    const float* ib = in + ((long long)b * 3) * 65536 + (2 * i) * 256 + 2 * j;
    float patch[27];
#pragma unroll
    for (int ci = 0; ci < 3; ++ci)
#pragma unroll
        for (int di = 0; di < 3; ++di) {
            const float* rp = ib + ci * 65536 + di * 256;
            float2 v01 = *(const float2*)rp;
            patch[ci * 9 + di * 3 + 0] = v01.x;
            patch[ci * 9 + di * 3 + 1] = v01.y;
            patch[ci * 9 + di * 3 + 2] = rp[2];
        }

    float vals[32];
#pragma unroll
    for (int co = 0; co < 32; co += 4) {
        float a0 = bs[co], a1 = bs[co + 1], a2 = bs[co + 2], a3 = bs[co + 3];
#pragma unroll
        for (int t = 0; t < 27; ++t) {
            float pv = patch[t];
            a0 = fmaf(pv, ws[(co + 0) * 27 + t], a0);
            a1 = fmaf(pv, ws[(co + 1) * 27 + t], a1);
            a2 = fmaf(pv, ws[(co + 2) * 27 + t], a2);
            a3 = fmaf(pv, ws[(co + 3) * 27 + t], a3);
        }
        vals[co + 0] = fmaxf(a0, 0.f);
        vals[co + 1] = fmaxf(a1, 0.f);
        vals[co + 2] = fmaxf(a2, 0.f);
        vals[co + 3] = fmaxf(a3, 0.f);
    }
    if (valid) {
        ushort_t res[32];
#pragma unroll
        for (int c = 0; c < 32; ++c) res[c] = f2bf(vals[c]);
        ushort_t* ob = out + (long long)p * 32;
#pragma unroll
        for (int v = 0; v < 4; ++v)
            *(short8v*)&ob[v * 8] = *(const short8v*)&res[v * 8];
    } else {
#pragma unroll
        for (int c = 0; c < 32; ++c) vals[c] = 0.f;
    }
    // stats: transpose via LDS
#pragma unroll
    for (int v = 0; v < 8; ++v)
        *(float4*)&tp[tid * 36 + v * 4] = make_float4(vals[v * 4], vals[v * 4 + 1],
                                                      vals[v * 4 + 2], vals[v * 4 + 3]);
    __syncthreads();
    {
        const int c = tid & 31, s = tid >> 5;
        float sm = 0.f, sq = 0.f;
#pragma unroll 8
        for (int q = 0; q < 32; ++q) {
            float v = tp[(s * 32 + q) * 36 + c];
            sm += v;
            sq = fmaf(v, v, sq);
        }
        ps[s][c] = sm;
        pq[s][c] = sq;
    }
    __syncthreads();
    if (tid < 32) {
        float sm = 0.f, sq = 0.f;
#pragma unroll
        for (int s = 0; s < 8; ++s) { sm += ps[s][tid]; sq += pq[s][tid]; }
        part[((long long)tid * C1NB + blockIdx.x) * 2 + 0] = sm;
        part[((long long)tid * C1NB + blockIdx.x) * 2 + 1] = sq;
    }
}

// ---------------- convs 2-5: NHWC bf16 MFMA, register-prefetch pipeline -----
__global__ __launch_bounds__(256) void conv_mfma(
    const ushort_t* __restrict__ in, const ushort_t* __restrict__ wf,
    const float* __restrict__ effb, ushort_t* __restrict__ out,
    float* __restrict__ pacc, float* __restrict__ spart,
    int B, int Ci, int lgCi, int Hi, int Wi, int Co, int Ho, int Wo,
    int K, int Kp, int kcount, int Spart) {
    const int HoWo = Ho * Wo;
    const int N = B * HoWo;
    __shared__ __align__(16) ushort_t As[64 * 64];
    __shared__ __align__(16) ushort_t Bs[128 * 64];
    const int tid = threadIdx.x;
    const int m0 = blockIdx.y * 64;
    const int n0 = blockIdx.x * 128;
    const int kbeg = blockIdx.z * kcount;

    const int rowA = tid >> 2;
    const int kqA = (tid & 3) * 16;
    const ushort_t* wrowA = wf + (long long)(m0 + rowA) * Kp + kbeg + kqA;
    const int swA = (rowA & 7) << 3;
    const int rowB = tid >> 1;
    const int kqB = (tid & 1) * 32;
    const int n = n0 + rowB;
    const int nn = (n < N) ? n : (N - 1);
    const int pb = nn / HoWo, pp = nn - pb * HoWo;
    const int pi = pp / Wo, pj = pp - pi * Wo;
    const long long base0 = ((long long)pb * Hi + 2 * pi) * Wi + 2 * pj;
    const int swB = (rowB & 7) << 3;

    const int w = tid >> 6;
    const int lane = tid & 63;
    const int wco = (w >> 1) * 32, wpx = (w & 1) * 64;
    const int lm = lane & 15, lk = lane >> 4;

    short8v rA0, rA1, rB[4];
    rA0 = *(const short8v*)(wrowA);
    rA1 = *(const short8v*)(wrowA + 8);
#pragma unroll
    for (int ch = 0; ch < 2; ++ch) {
        int c16 = kqB + ch * 16;
        int kg = kbeg + c16;
        int tap = kg >> lgCi;
        tap = tap > 8 ? 8 : tap;
        int ci0 = kg & (Ci - 1);
        int dy = tap / 3, dx = tap - dy * 3;
        const ushort_t* src = in + (base0 + dy * Wi + dx) * Ci + ci0;
        rB[ch * 2] = *(const short8v*)src;
        rB[ch * 2 + 1] = *(const short8v*)(src + 8);
    }

    f32x4 acc[2][4] = {};
    for (int k0 = 0; k0 < kcount; k0 += 64) {
        *(short8v*)&As[rowA * 64 + ((kqA + 0) ^ swA)] = rA0;
        *(short8v*)&As[rowA * 64 + ((kqA + 8) ^ swA)] = rA1;
#pragma unroll
        for (int ch = 0; ch < 2; ++ch) {
            int c16 = kqB + ch * 16;
            *(short8v*)&Bs[rowB * 64 + ((c16 + 0) ^ swB)] = rB[ch * 2];
            *(short8v*)&Bs[rowB * 64 + ((c16 + 8) ^ swB)] = rB[ch * 2 + 1];
        }
        __syncthreads();
        int k1 = k0 + 64;
        if (k1 < kcount) {
            rA0 = *(const short8v*)(wrowA + k1);
            rA1 = *(const short8v*)(wrowA + k1 + 8);
#pragma unroll
            for (int ch = 0; ch < 2; ++ch) {
                int c16 = kqB + ch * 16;
                int kg = kbeg + k1 + c16;
                int tap = kg >> lgCi;
                tap = tap > 8 ? 8 : tap;
                int ci0 = kg & (Ci - 1);
                int dy = tap / 3, dx = tap - dy * 3;
                const ushort_t* src = in + (base0 + dy * Wi + dx) * Ci + ci0;
                rB[ch * 2] = *(const short8v*)src;
                rB[ch * 2 + 1] = *(const short8v*)(src + 8);
            }
        }
#pragma unroll
        for (int kk = 0; kk < 2; ++kk) {
            const int kb = kk * 32 + lk * 8;
            const int ra0 = wco + lm, ra1 = wco + 16 + lm;
            short8v a0 = *(const short8v*)&As[ra0 * 64 + (kb ^ ((ra0 & 7) << 3))];
            short8v a1 = *(const short8v*)&As[ra1 * 64 + (kb ^ ((ra1 & 7) << 3))];
            const int rb0 = wpx + lm, rb1 = wpx + 16 + lm;
            const int rb2 = wpx + 32 + lm, rb3 = wpx + 48 + lm;
            short8v b0 = *(const short8v*)&Bs[rb0 * 64 + (kb ^ ((rb0 & 7) << 3))];
            short8v b1 = *(const short8v*)&Bs[rb1 * 64 + (kb ^ ((rb1 & 7) << 3))];
            short8v b2 = *(const short8v*)&Bs[rb2 * 64 + (kb ^ ((rb2 & 7) << 3))];
            short8v b3 = *(const short8v*)&Bs[rb3 * 64 + (kb ^ ((rb3 & 7) << 3))];
            acc[0][0] = __builtin_amdgcn_mfma_f32_16x16x32_bf16(a0, b0, acc[0][0], 0, 0, 0);
            acc[0][1] = __builtin_amdgcn_mfma_f32_16x16x32_bf16(a0, b1, acc[0][1], 0, 0, 0);
            acc[0][2] = __builtin_amdgcn_mfma_f32_16x16x32_bf16(a0, b2, acc[0][2], 0, 0, 0);
            acc[0][3] = __builtin_amdgcn_mfma_f32_16x16x32_bf16(a0, b3, acc[0][3], 0, 0, 0);
            acc[1][0] = __builtin_amdgcn_mfma_f32_16x16x32_bf16(a1, b0, acc[1][0], 0, 0, 0);
            acc[1][1] = __builtin_amdgcn_mfma_f32_16x16x32_bf16(a1, b1, acc[1][1], 0, 0, 0);
            acc[1][2] = __builtin_amdgcn_mfma_f32_16x16x32_bf16(a1, b2, acc[1][2], 0, 0, 0);
            acc[1][3] = __builtin_amdgcn_mfma_f32_16x16x32_bf16(a1, b3, acc[1][3], 0, 0, 0);
        }
        __syncthreads();
    }
    if (pacc) {
        float* pbuf = pacc + ((long long)blockIdx.z * N) * Co;
#pragma unroll
        for (int nb = 0; nb < 4; ++nb) {
            int np = n0 + wpx + nb * 16 + lm;
            if (np >= N) continue;
#pragma unroll
            for (int amr = 0; amr < 2; ++amr) {
                int cobase = m0 + wco + amr * 16 + lk * 4;
                float4 vv = make_float4(acc[amr][nb][0], acc[amr][nb][1],
                                        acc[amr][nb][2], acc[amr][nb][3]);
                *(float4*)&pbuf[(long long)np * Co + cobase] = vv;
            }
        }
    } else {
        float ssum[2][4] = {}, ssq[2][4] = {};
#pragma unroll
        for (int nb = 0; nb < 4; ++nb) {
            int np = n0 + wpx + nb * 16 + lm;
            bool val = (np < N);
#pragma unroll
            for (int amr = 0; amr < 2; ++amr) {
                int cobase = m0 + wco + amr * 16 + lk * 4;
                float4 eb = *(const float4*)&effb[cobase];
                float v0 = fmaxf(acc[amr][nb][0] + eb.x, 0.f);
                float v1 = fmaxf(acc[amr][nb][1] + eb.y, 0.f);
                float v2 = fmaxf(acc[amr][nb][2] + eb.z, 0.f);
                float v3 = fmaxf(acc[amr][nb][3] + eb.w, 0.f);
                if (val) {
                    ushort4 u;
                    u.x = f2bf(v0); u.y = f2bf(v1); u.z = f2bf(v2); u.w = f2bf(v3);
                    *(ushort4*)&out[(long long)np * Co + cobase] = u;
                    ssum[amr][0] += v0; ssq[amr][0] = fmaf(v0, v0, ssq[amr][0]);
                    ssum[amr][1] += v1; ssq[amr][1] = fmaf(v1, v1, ssq[amr][1]);
                    ssum[amr][2] += v2; ssq[amr][2] = fmaf(v2, v2, ssq[amr][2]);
                    ssum[amr][3] += v3; ssq[amr][3] = fmaf(v3, v3, ssq[amr][3]);
                }
            }
        }
#pragma unroll
        for (int mm = 1; mm < 16; mm <<= 1) {
#pragma unroll
            for (int amr = 0; amr < 2; ++amr)
#pragma unroll
                for (int r = 0; r < 4; ++r) {
                    ssum[amr][r] += __shfl_xor(ssum[amr][r], mm, 64);
                    ssq[amr][r] += __shfl_xor(ssq[amr][r], mm, 64);
                }
        }
        __shared__ float lss[4][32], lsq[4][32];
        if (lm == 0) {
#pragma unroll
            for (int amr = 0; amr < 2; ++amr)
#pragma unroll
                for (int r = 0; r < 4; ++r) {
                    lss[w][amr * 16 + lk * 4 + r] = ssum[amr][r];
                    lsq[w][amr * 16 + lk * 4 + r] = ssq[amr][r];
                }
        }
        __syncthreads();
        if (tid < 64) {
            int half = tid >> 5, c32 = tid & 31;
            float s = lss[half * 2][c32] + lss[half * 2 + 1][c32];
            float q = lsq[half * 2][c32] + lsq[half * 2 + 1][c32];
            int c = m0 + half * 32 + c32;
            spart[((long long)c * Spart + blockIdx.x) * 2 + 0] = s;
            spart[((long long)c * Spart + blockIdx.x) * 2 + 1] = q;
        }
    }
}

// ---- K-split reduce + bias + relu + stats partials (l5), grid-stride -------
__global__ __launch_bounds__(256) void convz_stats(
    const float* __restrict__ pacc, const float* __restrict__ effb,
    ushort_t* __restrict__ out, float* __restrict__ part,
    long long total, int Co, int Z) {
    const int tid = threadIdx.x;
    const int c0 = (tid * 8) & (Co - 1);
    float eb[8];
    {
        float4 e0 = *(const float4*)&effb[c0];
        float4 e1 = *(const float4*)&effb[c0 + 4];
        eb[0] = e0.x; eb[1] = e0.y; eb[2] = e0.z; eb[3] = e0.w;
        eb[4] = e1.x; eb[5] = e1.y; eb[6] = e1.z; eb[7] = e1.w;
    }
    float sum[8] = {}, sq[8] = {};
    const long long nchunk = total >> 11;
    for (long long g = blockIdx.x; g < nchunk; g += 512) {
        long long off = (g << 11) + tid * 8;
        float v[8];
#pragma unroll
        for (int j = 0; j < 8; ++j) v[j] = eb[j];
        for (int z = 0; z < Z; ++z) {
            const float* pz = pacc + (long long)z * total + off;
            float4 a = *(const float4*)pz;
            float4 b2 = *(const float4*)(pz + 4);
            v[0] += a.x; v[1] += a.y; v[2] += a.z; v[3] += a.w;
            v[4] += b2.x; v[5] += b2.y; v[6] += b2.z; v[7] += b2.w;
        }
        short8v o;
#pragma unroll
        for (int j = 0; j < 8; ++j) {
            float r = fmaxf(v[j], 0.f);
            o[j] = (short)f2bf(r);
            sum[j] += r;
            sq[j] = fmaf(r, r, sq[j]);
        }
        *(short8v*)&out[off] = o;
    }
    __shared__ float rs[256][8], rq[256][8];
#pragma unroll
    for (int j = 0; j < 8; ++j) { rs[tid][j] = sum[j]; rq[tid][j] = sq[j]; }
    __syncthreads();
    const int G = Co >> 3;
    const int TPG = 256 / G;
    for (int c = tid; c < Co; c += 256) {
        int grp = c >> 3, j = c & 7;
        float s = 0.f, q = 0.f;
        for (int i = 0; i < TPG; ++i) {
            s += rs[grp + i * G][j];
            q += rq[grp + i * G][j];
        }
        part[(c * 512 + blockIdx.x) * 2 + 0] = s;
        part[(c * 512 + blockIdx.x) * 2 + 1] = q;
    }
}

// wave-parallel stats finalize
__global__ __launch_bounds__(256) void stats_final_w(
    const float* __restrict__ part, const float* __restrict__ g,
    const float* __restrict__ be, float* __restrict__ scale,
    float* __restrict__ shift, int C, int S, float invN) {
    int c = blockIdx.x * 4 + (threadIdx.x >> 6);
    int lane = threadIdx.x & 63;
    if (c >= C) return;
    float s = 0.f, q = 0.f;
    for (int i = lane; i < S; i += 64) {
        s += part[((long long)c * S + i) * 2 + 0];
        q += part[((long long)c * S + i) * 2 + 1];
    }
#pragma unroll
    for (int off = 32; off > 0; off >>= 1) {
        s += __shfl_down(s, off, 64);
        q += __shfl_down(q, off, 64);
    }
    if (lane == 0) {
        float m = s * invN;
        float v = q * invN - m * m;
        float inv = rsqrtf(v + BEPS);
        float sc = g[c] * inv;
        scale[c] = sc;
        shift[c] = be[c] - m * sc;
    }
}

// ---------------- fused BN fold: weights (grid head) + bias (grid tail) -----
__global__ __launch_bounds__(256) void fold_fused(
    const float* __restrict__ w, const float* __restrict__ scale,
    const float* __restrict__ shift, const float* __restrict__ bias,
    ushort_t* __restrict__ wout, float* __restrict__ effb,
    int Ci, int lgCi, int K, int Kp, int Co, int WB) {
    if ((int)blockIdx.x < WB) {
        int idx = blockIdx.x * 256 + threadIdx.x;
        if (idx >= Co * Kp) return;
        int co = idx / Kp, k = idx - co * Kp;
        ushort_t o = 0;
        if (k < K) {
            int tap = k >> lgCi;
            int ci = k & (Ci - 1);
            o = f2bf(w[((long long)co * Ci + ci) * 9 + tap] * scale[ci]);
        }
        wout[idx] = o;
    } else {
        int co = ((int)blockIdx.x - WB) * 4 + (threadIdx.x >> 6);
        int lane = threadIdx.x & 63;
        if (co >= Co) return;
        const int CK = Ci * 9;
        const float* wr = w + (long long)co * CK;
        float acc = 0.f;
        for (int k = lane; k < CK; k += 64) acc = fmaf(wr[k], shift[k / 9], acc);
#pragma unroll
        for (int off = 32; off > 0; off >>= 1) acc += __shfl_down(acc, off, 64);
        if (lane == 0) effb[co] = acc + bias[co];
    }
}

// ---------------- BN apply conv5 NHWC out -> xB bf16 [32][25088] ------------
__global__ void bn_apply_x(const ushort_t* __restrict__ y, const float* __restrict__ scale,
                           const float* __restrict__ shift, ushort_t* __restrict__ xB) {
    int idx = blockIdx.x * blockDim.x + threadIdx.x;
    if (idx >= 802816) return;
    int b = idx / 25088, k = idx - b * 25088;
    int c = k / 49, p = k - c * 49;
    float v = bf2f(y[((long long)b * 49 + p) * 512 + c]);
    xB[idx] = f2bf(fmaf(v, scale[c], shift[c]));
}

// ---------------- fc1 split-K MFMA GEMM (W fp32 -> bf16 inline) -------------
__global__ __launch_bounds__(256) void fc1_mfma(
    const float* __restrict__ w, const ushort_t* __restrict__ xB,
    float* __restrict__ part) {
    const int K = 25088;
    __shared__ __align__(16) ushort_t As[64 * 256];
    __shared__ __align__(16) ushort_t Bs[32 * 256];
    const int tid = threadIdx.x;
    const int m0 = blockIdx.y * 64;
    const int kbeg = blockIdx.x * FC1_KC;

    {
        const int r = tid >> 2;
        const int kq = (tid & 3) * 64;
        const int m = m0 + r;
        const bool mv = (m < 1000);
        const float* wr = w + (long long)m * K + kbeg + kq;
        const int sw = (r & 7) << 3;
#pragma unroll
        for (int g = 0; g < 8; ++g) {
            short8v o = {0, 0, 0, 0, 0, 0, 0, 0};
            if (mv) {
                float4 f0 = *(const float4*)(wr + g * 8);
                float4 f1 = *(const float4*)(wr + g * 8 + 4);
                o[0] = (short)f2bf(f0.x); o[1] = (short)f2bf(f0.y);
                o[2] = (short)f2bf(f0.z); o[3] = (short)f2bf(f0.w);
                o[4] = (short)f2bf(f1.x); o[5] = (short)f2bf(f1.y);
                o[6] = (short)f2bf(f1.z); o[7] = (short)f2bf(f1.w);
            }
            *(short8v*)&As[r * 256 + ((kq + g * 8) ^ sw)] = o;
        }
    }
    {
        const int b = tid >> 3;
        const int kq = (tid & 7) * 32;
        const ushort_t* xr = xB + (long long)b * K + kbeg + kq;
        const int sw = (b & 7) << 3;
#pragma unroll
        for (int g = 0; g < 4; ++g) {
            short8v v = *(const short8v*)(xr + g * 8);
            *(short8v*)&Bs[b * 256 + ((kq + g * 8) ^ sw)] = v;
        }
    }
    __syncthreads();
    const int wv = tid >> 6, lane = tid & 63;
    const int lm = lane & 15, lk = lane >> 4;
    const int wm = wv * 16;
    f32x4 acc0 = {}, acc1 = {};
    const int ra = wm + lm;
    const int swa = (ra & 7) << 3;
    const int swb = (lm & 7) << 3;
#pragma unroll
    for (int s = 0; s < 8; ++s) {
        int kb = s * 32 + lk * 8;
        short8v av = *(const short8v*)&As[ra * 256 + (kb ^ swa)];
        short8v b0 = *(const short8v*)&Bs[lm * 256 + (kb ^ swb)];
        short8v b1 = *(const short8v*)&Bs[(16 + lm) * 256 + (kb ^ swb)];
        acc0 = __builtin_amdgcn_mfma_f32_16x16x32_bf16(av, b0, acc0, 0, 0, 0);
        acc1 = __builtin_amdgcn_mfma_f32_16x16x32_bf16(av, b1, acc1, 0, 0, 0);
    }
    float* pb = part + ((long long)blockIdx.y * FC1_KS + blockIdx.x) * 2048;
#pragma unroll
    for (int r = 0; r < 4; ++r) {
        pb[(wm + lk * 4 + r) * 32 + lm] = acc0[r];
        pb[(wm + lk * 4 + r) * 32 + 16 + lm] = acc1[r];
    }
}

__global__ void fc1_reduce(const float* __restrict__ part, const float* __restrict__ bias,
                           float* __restrict__ z) {
    int idx = blockIdx.x * blockDim.x + threadIdx.x;
    if (idx >= 32000) return;
    int o = idx >> 5, b = idx & 31;
    int mt = o >> 6, mr = o & 63;
    const float* p = part + ((long long)mt * FC1_KS) * 2048 + mr * 32 + b;
    float s0 = 0.f, s1 = 0.f;
    int ks = 0;
    for (; ks + 1 < FC1_KS; ks += 2) {
        s0 += p[(long long)ks * 2048];
        s1 += p[(long long)(ks + 1) * 2048];
    }
    for (; ks < FC1_KS; ++ks) s0 += p[(long long)ks * 2048];
    z[b * 1000 + o] = fmaxf(s0 + s1 + bias[o], 0.f);
}

// ---------------- fc2 -------------------------------------------------------
__global__ __launch_bounds__(256) void fc2_v2(const float* __restrict__ z,
                                              const float* __restrict__ w,
                                              const float* __restrict__ bias,
                                              float* __restrict__ ys) {
    int gid = blockIdx.x * 4 + (threadIdx.x >> 6);
    int lane = threadIdx.x & 63;
    if (gid >= 960) return;
    int b = gid / 30, o = gid - b * 30;
    const float* zr = z + (long long)b * 1000;
    const float* wr = w + (long long)o * 1000;
    float acc = 0.f;
    for (int k = lane; k < 1000; k += 64) acc = fmaf(zr[k], wr[k], acc);
    for (int off = 32; off > 0; off >>= 1) acc += __shfl_down(acc, off, 64);
    if (lane == 0) ys[gid] = acc + bias[o];
}

// ---------------- spline eval: inline coef compute + image + table ----------
__global__ __launch_bounds__(256) void eval_all(
    const float4* __restrict__ batch4, const float* __restrict__ ysraw,
    const float* __restrict__ matrix, float4* __restrict__ out4,
    float* __restrict__ outt) {
    __shared__ float mat[100];
    __shared__ float4 coefs[864];
    const int tid = threadIdx.x;
    const float h = 1.0f / 9.0f;
    if (tid < 100) mat[tid] = matrix[tid];
    __syncthreads();
    if (tid < 96) {
        int b = tid / 3, ch = tid - b * 3;
        float ya[10];
#pragma unroll
        for (int j = 0; j < 10; ++j)
            ya[j] = ysraw[b * 30 + ch * 10 + j] / 100.0f + (float)j / 9.0f;
        float M[10];
#pragma unroll
        for (int i = 0; i < 10; ++i) {
            float acc = 0.f;
#pragma unroll
            for (int j = 0; j < 10; ++j) acc = fmaf(mat[i * 10 + j], ya[j], acc);
            M[i] = acc;
        }
#pragma unroll
        for (int k = 0; k < 9; ++k) {
            float a = (M[k + 1] - M[k]) / (6.0f * h);
            float bb = M[k] * 0.5f;
            float cc = (ya[k + 1] - ya[k]) / h - (M[k + 1] + 2.0f * M[k]) * (h / 6.0f);
            float dd = ya[k];
            coefs[tid * 9 + k] = make_float4(a, bb, cc, dd);
        }
    }
    __syncthreads();
    int idx = blockIdx.x * 256 + tid;
    if (idx < 1572864) {
        int plane = idx >> 14;
        float4 xv4 = batch4[idx];
        float xin[4] = {xv4.x, xv4.y, xv4.z, xv4.w};
        float xout[4];
#pragma unroll
        for (int e = 0; e < 4; ++e) {
            float xv = xin[e];
            int xi = (int)floorf(xv / h);
            xi = min(max(xi, 0), 8);
            float xf = xv - (float)xi * h;
            float4 cf = coefs[plane * 9 + xi];
            xout[e] = fmaf(fmaf(fmaf(cf.x, xf, cf.y), xf, cf.z), xf, cf.w);
        }
        out4[idx] = make_float4(xout[0], xout[1], xout[2], xout[3]);
    } else {
        int t = idx - 1572864;
        if (t < 96 * 255) {
            int plane = t / 255;
            int j = t - plane * 255;
            float xv = (float)j / 255.0f;
            int xi = (int)floorf(xv / h);
            xi = min(max(xi, 0), 8);
            float xf = xv - (float)xi * h;
            float4 cf = coefs[plane * 9 + xi];
            outt[t] = fmaf(fmaf(fmaf(cf.x, xf, cf.y), xf, cf.z), xf, cf.w);
        }
    }
}

extern "C" void kernel_launch(void* const* d_in, const int* in_sizes, int n_in,
                              void* d_out, int out_size, void* d_ws, size_t ws_size,
                              hipStream_t stream) {
    const int B = 32;
    const float* batch = (const float*)d_in[0];
    const float* cw[5] = {(const float*)d_in[1], (const float*)d_in[5], (const float*)d_in[9],
                          (const float*)d_in[13], (const float*)d_in[17]};
    const float* cb[5] = {(const float*)d_in[2], (const float*)d_in[6], (const float*)d_in[10],
                          (const float*)d_in[14], (const float*)d_in[18]};
    const float* bg[5] = {(const float*)d_in[3], (const float*)d_in[7], (const float*)d_in[11],
                          (const float*)d_in[15], (const float*)d_in[19]};
    const float* bb[5] = {(const float*)d_in[4], (const float*)d_in[8], (const float*)d_in[12],
                          (const float*)d_in[16], (const float*)d_in[20]};
    const float* l1w = (const float*)d_in[21];
    const float* l1b = (const float*)d_in[22];
    const float* l2w = (const float*)d_in[23];
    const float* l2b = (const float*)d_in[24];
    const float* matrix = (const float*)d_in[25];

    float* f = (float*)d_ws;
    const size_t A_F = 8258048;
    const size_t Bq_F = 4064256;
    const size_t W_F = 589824;
    ushort_t* bufA = (ushort_t*)f;
    ushort_t* bufB = (ushort_t*)(f + A_F);
    ushort_t* Wf_bf = (ushort_t*)(f + A_F + Bq_F);
    float* effb  = f + A_F + Bq_F + W_F;   // 512
    float* scale = effb + 512;             // 512
    float* shift = scale + 512;            // 512
    float* part  = shift + 512;            // 524,288
    float* x5    = part + 524288;          // 802,816 (bf16 xB)
    float* pacc  = x5 + 802816;            // 3,686,400
    float* z1    = pacc + 3686400;         // 32,000
    float* ysb   = z1 + 32000;             // 960

    const int Ci[5]   = {3, 32, 64, 128, 256};
    const int lgCi[5] = {0, 5, 6, 7, 8};
    const int Co[5]   = {32, 64, 128, 256, 512};
    const int Hi[5]   = {256, 127, 63, 31, 15};
    const int Ho[5]   = {127, 63, 31, 15, 7};
    const int Zl[5]   = {1, 1, 1, 1, 3};

    ushort_t* bufs[2] = {bufA, bufB};

    // layer 1: conv + fused stats partials
    conv1_direct<<<C1NB, 256, 0, stream>>>(batch, cw[0], cb[0], bufA, part);
    stats_final_w<<<8, 256, 0, stream>>>(part, bg[0], bb[0], scale, shift, 32, C1NB,
                                         1.0f / (float)(B * 16129));

    // layers 2..5
    const ushort_t* cur = bufA;
    for (int l = 1; l < 5; ++l) {
        ushort_t* outb = bufs[l % 2];
        int K = Ci[l] * 9;
        int Kp = (K + 63) & ~63;
        int WB = (Co[l] * Kp + 255) / 256;
        int BBk = (Co[l] + 3) / 4;
        fold_fused<<<WB + BBk, 256, 0, stream>>>(cw[l], scale, shift, cb[l], Wf_bf, effb,
                                                 Ci[l], lgCi[l], K, Kp, Co[l], WB);
        int N = B * Ho[l] * Ho[l];
        int Z = Zl[l];
        int kcount = Kp / Z;
        dim3 grid((N + 127) / 128, Co[l] / 64, Z);
        if (Z == 1) {
            conv_mfma<<<grid, 256, 0, stream>>>(cur, Wf_bf, effb, outb, nullptr, part,
                                                B, Ci[l], lgCi[l], Hi[l], Hi[l], Co[l],
                                                Ho[l], Ho[l], K, Kp, kcount, grid.x);
            stats_final_w<<<(Co[l] + 3) / 4, 256, 0, stream>>>(
                part, bg[l], bb[l], scale, shift, Co[l], grid.x, 1.0f / (float)N);
        } else {
            conv_mfma<<<grid, 256, 0, stream>>>(cur, Wf_bf, effb, nullptr, pacc, nullptr,
                                                B, Ci[l], lgCi[l], Hi[l], Hi[l], Co[l],
                                                Ho[l], Ho[l], K, Kp, kcount, 0);
            long long total = (long long)N * Co[l];
            convz_stats<<<512, 256, 0, stream>>>(pacc, effb, outb, part, total, Co[l], Z);
            stats_final_w<<<(Co[l] + 3) / 4, 256, 0, stream>>>(
                part, bg[l], bb[l], scale, shift, Co[l], 512, 1.0f / (float)N);
        }
        cur = outb;
    }

    ushort_t* xB = (ushort_t*)x5;
    bn_apply_x<<<(802816 + 255) / 256, 256, 0, stream>>>(cur, scale, shift, xB);
    {
        dim3 grid(FC1_KS, 16);
        fc1_mfma<<<grid, 256, 0, stream>>>(l1w, xB, pacc);
    }
    fc1_reduce<<<(32000 + 255) / 256, 256, 0, stream>>>(pacc, l1b, z1);
    fc2_v2<<<240, 256, 0, stream>>>(z1, l2w, l2b, ysb);

    float* out = (float*)d_out;
    int evtot = 1572864 + 96 * 255;
    eval_all<<<(evtot + 255) / 256, 256, 0, stream>>>((const float4*)batch, ysb, matrix,
                                                      (float4*)out, out + 6291456);
}

// Round 16
// 235.641 us; speedup vs baseline: 3.9183x; 1.0072x over previous
//
#include <hip/hip_runtime.h>
#include <hip/hip_bf16.h>

#define BEPS 1e-5f
#define FC1_KS 98
#define FC1_KC 256
#define C1NB 2017

typedef __attribute__((ext_vector_type(8))) short short8v;
typedef __attribute__((ext_vector_type(4))) float f32x4;
typedef unsigned short ushort_t;

__device__ __forceinline__ float bf2f(ushort_t u) {
    unsigned int x = ((unsigned int)u) << 16;
    return __builtin_bit_cast(float, x);
}
__device__ __forceinline__ ushort_t f2bf(float v) {
    __hip_bfloat16 h = __float2bfloat16(v);
    return *(ushort_t*)&h;
}

// ---------------- conv1: direct fp32, NHWC bf16 out, fused BN-stats ---------
__global__ __launch_bounds__(256) void conv1_direct(
    const float* __restrict__ in, const float* __restrict__ w,
    const float* __restrict__ bias, ushort_t* __restrict__ out,
    float* __restrict__ part) {
    __shared__ float ws[864];
    __shared__ float bs[32];
    __shared__ float tp[256 * 36];
    __shared__ float ps[8][32], pq[8][32];
    const int tid = threadIdx.x;
    for (int i = tid; i < 864; i += 256) ws[i] = w[i];
    if (tid < 32) bs[tid] = bias[tid];
    __syncthreads();

    const int TOT = 32 * 16129;
    int p = blockIdx.x * 256 + tid;
    const bool valid = (p < TOT);
    int pc = valid ? p : (TOT - 1);
    int b = pc / 16129, pp = pc - b * 16129;
    int i = pp / 127, j = pp - i * 127;
    const float* ib = in + ((long long)b * 3) * 65536 + (2 * i) * 256 + 2 * j;
    float patch[27];
#pragma unroll
    for (int ci = 0; ci < 3; ++ci)
#pragma unroll
        for (int di = 0; di < 3; ++di) {
            const float* rp = ib + ci * 65536 + di * 256;
            float2 v01 = *(const float2*)rp;
            patch[ci * 9 + di * 3 + 0] = v01.x;
            patch[ci * 9 + di * 3 + 1] = v01.y;
            patch[ci * 9 + di * 3 + 2] = rp[2];
        }

    float vals[32];
#pragma unroll
    for (int co = 0; co < 32; co += 4) {
        float a0 = bs[co], a1 = bs[co + 1], a2 = bs[co + 2], a3 = bs[co + 3];
#pragma unroll
        for (int t = 0; t < 27; ++t) {
            float pv = patch[t];
            a0 = fmaf(pv, ws[(co + 0) * 27 + t], a0);
            a1 = fmaf(pv, ws[(co + 1) * 27 + t], a1);
            a2 = fmaf(pv, ws[(co + 2) * 27 + t], a2);
            a3 = fmaf(pv, ws[(co + 3) * 27 + t], a3);
        }
        vals[co + 0] = fmaxf(a0, 0.f);
        vals[co + 1] = fmaxf(a1, 0.f);
        vals[co + 2] = fmaxf(a2, 0.f);
        vals[co + 3] = fmaxf(a3, 0.f);
    }
    if (valid) {
        ushort_t res[32];
#pragma unroll
        for (int c = 0; c < 32; ++c) res[c] = f2bf(vals[c]);
        ushort_t* ob = out + (long long)p * 32;
#pragma unroll
        for (int v = 0; v < 4; ++v)
            *(short8v*)&ob[v * 8] = *(const short8v*)&res[v * 8];
    } else {
#pragma unroll
        for (int c = 0; c < 32; ++c) vals[c] = 0.f;
    }
#pragma unroll
    for (int v = 0; v < 8; ++v)
        *(float4*)&tp[tid * 36 + v * 4] = make_float4(vals[v * 4], vals[v * 4 + 1],
                                                      vals[v * 4 + 2], vals[v * 4 + 3]);
    __syncthreads();
    {
        const int c = tid & 31, s = tid >> 5;
        float sm = 0.f, sq = 0.f;
#pragma unroll 8
        for (int q = 0; q < 32; ++q) {
            float v = tp[(s * 32 + q) * 36 + c];
            sm += v;
            sq = fmaf(v, v, sq);
        }
        ps[s][c] = sm;
        pq[s][c] = sq;
    }
    __syncthreads();
    if (tid < 32) {
        float sm = 0.f, sq = 0.f;
#pragma unroll
        for (int s = 0; s < 8; ++s) { sm += ps[s][tid]; sq += pq[s][tid]; }
        part[((long long)tid * C1NB + blockIdx.x) * 2 + 0] = sm;
        part[((long long)tid * C1NB + blockIdx.x) * 2 + 1] = sq;
    }
}

// ---------------- l2/l3: 512-thr, 64co x 256px tile, fused stats ------------
__global__ __launch_bounds__(512) void conv_mfma512(
    const ushort_t* __restrict__ in, const ushort_t* __restrict__ wf,
    const float* __restrict__ effb, ushort_t* __restrict__ out,
    float* __restrict__ spart,
    int B, int Ci, int lgCi, int Hi, int Wi, int Co, int Ho, int Wo,
    int K, int Kp, int kcount, int Spart) {
    const int HoWo = Ho * Wo;
    const int N = B * HoWo;
    __shared__ __align__(16) ushort_t As[64 * 64];
    __shared__ __align__(16) ushort_t Bs[256 * 64];
    const int tid = threadIdx.x;
    const int m0 = blockIdx.y * 64;
    const int n0 = blockIdx.x * 256;

    // A staging: 64 rows x 8 thr x 8 k
    const int rowA = tid >> 3;
    const int kqA = (tid & 7) * 8;
    const ushort_t* wrowA = wf + (long long)(m0 + rowA) * Kp + kqA;
    const int swA = (rowA & 7) << 3;
    // B staging: 256 rows x 2 thr x 32 k
    const int rowB = tid >> 1;
    const int kqB = (tid & 1) * 32;
    const int n = n0 + rowB;
    const int nn = (n < N) ? n : (N - 1);
    const int pb = nn / HoWo, pp = nn - pb * HoWo;
    const int pi = pp / Wo, pj = pp - pi * Wo;
    const long long base0 = ((long long)pb * Hi + 2 * pi) * Wi + 2 * pj;
    const int swB = (rowB & 7) << 3;

    const int w = tid >> 6;            // 0..7
    const int lane = tid & 63;
    const int wco = (w >> 2) * 32;     // 0/32
    const int wpx = (w & 3) * 64;      // 0/64/128/192
    const int lm = lane & 15, lk = lane >> 4;

    short8v rA0, rB[4];
    rA0 = *(const short8v*)(wrowA);
#pragma unroll
    for (int ch = 0; ch < 2; ++ch) {
        int c16 = kqB + ch * 16;
        int kg = c16;
        int tap = kg >> lgCi;
        tap = tap > 8 ? 8 : tap;
        int ci0 = kg & (Ci - 1);
        int dy = tap / 3, dx = tap - dy * 3;
        const ushort_t* src = in + (base0 + dy * Wi + dx) * Ci + ci0;
        rB[ch * 2] = *(const short8v*)src;
        rB[ch * 2 + 1] = *(const short8v*)(src + 8);
    }

    f32x4 acc[2][4] = {};
    for (int k0 = 0; k0 < kcount; k0 += 64) {
        *(short8v*)&As[rowA * 64 + (kqA ^ swA)] = rA0;
#pragma unroll
        for (int ch = 0; ch < 2; ++ch) {
            int c16 = kqB + ch * 16;
            *(short8v*)&Bs[rowB * 64 + ((c16 + 0) ^ swB)] = rB[ch * 2];
            *(short8v*)&Bs[rowB * 64 + ((c16 + 8) ^ swB)] = rB[ch * 2 + 1];
        }
        __syncthreads();
        int k1 = k0 + 64;
        if (k1 < kcount) {
            rA0 = *(const short8v*)(wrowA + k1);
#pragma unroll
            for (int ch = 0; ch < 2; ++ch) {
                int c16 = kqB + ch * 16;
                int kg = k1 + c16;
                int tap = kg >> lgCi;
                tap = tap > 8 ? 8 : tap;
                int ci0 = kg & (Ci - 1);
                int dy = tap / 3, dx = tap - dy * 3;
                const ushort_t* src = in + (base0 + dy * Wi + dx) * Ci + ci0;
                rB[ch * 2] = *(const short8v*)src;
                rB[ch * 2 + 1] = *(const short8v*)(src + 8);
            }
        }
#pragma unroll
        for (int kk = 0; kk < 2; ++kk) {
            const int kb = kk * 32 + lk * 8;
            const int ra0 = wco + lm, ra1 = wco + 16 + lm;
            short8v a0 = *(const short8v*)&As[ra0 * 64 + (kb ^ ((ra0 & 7) << 3))];
            short8v a1 = *(const short8v*)&As[ra1 * 64 + (kb ^ ((ra1 & 7) << 3))];
            const int rb0 = wpx + lm, rb1 = wpx + 16 + lm;
            const int rb2 = wpx + 32 + lm, rb3 = wpx + 48 + lm;
            short8v b0 = *(const short8v*)&Bs[rb0 * 64 + (kb ^ ((rb0 & 7) << 3))];
            short8v b1 = *(const short8v*)&Bs[rb1 * 64 + (kb ^ ((rb1 & 7) << 3))];
            short8v b2 = *(const short8v*)&Bs[rb2 * 64 + (kb ^ ((rb2 & 7) << 3))];
            short8v b3 = *(const short8v*)&Bs[rb3 * 64 + (kb ^ ((rb3 & 7) << 3))];
            acc[0][0] = __builtin_amdgcn_mfma_f32_16x16x32_bf16(a0, b0, acc[0][0], 0, 0, 0);
            acc[0][1] = __builtin_amdgcn_mfma_f32_16x16x32_bf16(a0, b1, acc[0][1], 0, 0, 0);
            acc[0][2] = __builtin_amdgcn_mfma_f32_16x16x32_bf16(a0, b2, acc[0][2], 0, 0, 0);
            acc[0][3] = __builtin_amdgcn_mfma_f32_16x16x32_bf16(a0, b3, acc[0][3], 0, 0, 0);
            acc[1][0] = __builtin_amdgcn_mfma_f32_16x16x32_bf16(a1, b0, acc[1][0], 0, 0, 0);
            acc[1][1] = __builtin_amdgcn_mfma_f32_16x16x32_bf16(a1, b1, acc[1][1], 0, 0, 0);
            acc[1][2] = __builtin_amdgcn_mfma_f32_16x16x32_bf16(a1, b2, acc[1][2], 0, 0, 0);
            acc[1][3] = __builtin_amdgcn_mfma_f32_16x16x32_bf16(a1, b3, acc[1][3], 0, 0, 0);
        }
        __syncthreads();
    }
    float ssum[2][4] = {}, ssq[2][4] = {};
#pragma unroll
    for (int nb = 0; nb < 4; ++nb) {
        int np = n0 + wpx + nb * 16 + lm;
        bool val = (np < N);
#pragma unroll
        for (int amr = 0; amr < 2; ++amr) {
            int cobase = m0 + wco + amr * 16 + lk * 4;
            float4 eb = *(const float4*)&effb[cobase];
            float v0 = fmaxf(acc[amr][nb][0] + eb.x, 0.f);
            float v1 = fmaxf(acc[amr][nb][1] + eb.y, 0.f);
            float v2 = fmaxf(acc[amr][nb][2] + eb.z, 0.f);
            float v3 = fmaxf(acc[amr][nb][3] + eb.w, 0.f);
            if (val) {
                ushort4 u;
                u.x = f2bf(v0); u.y = f2bf(v1); u.z = f2bf(v2); u.w = f2bf(v3);
                *(ushort4*)&out[(long long)np * Co + cobase] = u;
                ssum[amr][0] += v0; ssq[amr][0] = fmaf(v0, v0, ssq[amr][0]);
                ssum[amr][1] += v1; ssq[amr][1] = fmaf(v1, v1, ssq[amr][1]);
                ssum[amr][2] += v2; ssq[amr][2] = fmaf(v2, v2, ssq[amr][2]);
                ssum[amr][3] += v3; ssq[amr][3] = fmaf(v3, v3, ssq[amr][3]);
            }
        }
    }
#pragma unroll
    for (int mm = 1; mm < 16; mm <<= 1) {
#pragma unroll
        for (int amr = 0; amr < 2; ++amr)
#pragma unroll
            for (int r = 0; r < 4; ++r) {
                ssum[amr][r] += __shfl_xor(ssum[amr][r], mm, 64);
                ssq[amr][r] += __shfl_xor(ssq[amr][r], mm, 64);
            }
    }
    __shared__ float lss[8][32], lsq[8][32];
    if (lm == 0) {
#pragma unroll
        for (int amr = 0; amr < 2; ++amr)
#pragma unroll
            for (int r = 0; r < 4; ++r) {
                lss[w][amr * 16 + lk * 4 + r] = ssum[amr][r];
                lsq[w][amr * 16 + lk * 4 + r] = ssq[amr][r];
            }
    }
    __syncthreads();
    if (tid < 64) {
        int half = tid >> 5, c32 = tid & 31;
        float s = 0.f, q = 0.f;
#pragma unroll
        for (int qv = 0; qv < 4; ++qv) {
            s += lss[half * 4 + qv][c32];
            q += lsq[half * 4 + qv][c32];
        }
        int c = m0 + half * 32 + c32;
        spart[((long long)c * Spart + blockIdx.x) * 2 + 0] = s;
        spart[((long long)c * Spart + blockIdx.x) * 2 + 1] = q;
    }
}

// ---------------- l4/l5: 256-thr, 64co x 128px tile -------------------------
__global__ __launch_bounds__(256) void conv_mfma(
    const ushort_t* __restrict__ in, const ushort_t* __restrict__ wf,
    const float* __restrict__ effb, ushort_t* __restrict__ out,
    float* __restrict__ pacc, float* __restrict__ spart,
    int B, int Ci, int lgCi, int Hi, int Wi, int Co, int Ho, int Wo,
    int K, int Kp, int kcount, int Spart) {
    const int HoWo = Ho * Wo;
    const int N = B * HoWo;
    __shared__ __align__(16) ushort_t As[64 * 64];
    __shared__ __align__(16) ushort_t Bs[128 * 64];
    const int tid = threadIdx.x;
    const int m0 = blockIdx.y * 64;
    const int n0 = blockIdx.x * 128;
    const int kbeg = blockIdx.z * kcount;

    const int rowA = tid >> 2;
    const int kqA = (tid & 3) * 16;
    const ushort_t* wrowA = wf + (long long)(m0 + rowA) * Kp + kbeg + kqA;
    const int swA = (rowA & 7) << 3;
    const int rowB = tid >> 1;
    const int kqB = (tid & 1) * 32;
    const int n = n0 + rowB;
    const int nn = (n < N) ? n : (N - 1);
    const int pb = nn / HoWo, pp = nn - pb * HoWo;
    const int pi = pp / Wo, pj = pp - pi * Wo;
    const long long base0 = ((long long)pb * Hi + 2 * pi) * Wi + 2 * pj;
    const int swB = (rowB & 7) << 3;

    const int w = tid >> 6;
    const int lane = tid & 63;
    const int wco = (w >> 1) * 32, wpx = (w & 1) * 64;
    const int lm = lane & 15, lk = lane >> 4;

    short8v rA0, rA1, rB[4];
    rA0 = *(const short8v*)(wrowA);
    rA1 = *(const short8v*)(wrowA + 8);
#pragma unroll
    for (int ch = 0; ch < 2; ++ch) {
        int c16 = kqB + ch * 16;
        int kg = kbeg + c16;
        int tap = kg >> lgCi;
        tap = tap > 8 ? 8 : tap;
        int ci0 = kg & (Ci - 1);
        int dy = tap / 3, dx = tap - dy * 3;
        const ushort_t* src = in + (base0 + dy * Wi + dx) * Ci + ci0;
        rB[ch * 2] = *(const short8v*)src;
        rB[ch * 2 + 1] = *(const short8v*)(src + 8);
    }

    f32x4 acc[2][4] = {};
    for (int k0 = 0; k0 < kcount; k0 += 64) {
        *(short8v*)&As[rowA * 64 + ((kqA + 0) ^ swA)] = rA0;
        *(short8v*)&As[rowA * 64 + ((kqA + 8) ^ swA)] = rA1;
#pragma unroll
        for (int ch = 0; ch < 2; ++ch) {
            int c16 = kqB + ch * 16;
            *(short8v*)&Bs[rowB * 64 + ((c16 + 0) ^ swB)] = rB[ch * 2];
            *(short8v*)&Bs[rowB * 64 + ((c16 + 8) ^ swB)] = rB[ch * 2 + 1];
        }
        __syncthreads();
        int k1 = k0 + 64;
        if (k1 < kcount) {
            rA0 = *(const short8v*)(wrowA + k1);
            rA1 = *(const short8v*)(wrowA + k1 + 8);
#pragma unroll
            for (int ch = 0; ch < 2; ++ch) {
                int c16 = kqB + ch * 16;
                int kg = kbeg + k1 + c16;
                int tap = kg >> lgCi;
                tap = tap > 8 ? 8 : tap;
                int ci0 = kg & (Ci - 1);
                int dy = tap / 3, dx = tap - dy * 3;
                const ushort_t* src = in + (base0 + dy * Wi + dx) * Ci + ci0;
                rB[ch * 2] = *(const short8v*)src;
                rB[ch * 2 + 1] = *(const short8v*)(src + 8);
            }
        }
#pragma unroll
        for (int kk = 0; kk < 2; ++kk) {
            const int kb = kk * 32 + lk * 8;
            const int ra0 = wco + lm, ra1 = wco + 16 + lm;
            short8v a0 = *(const short8v*)&As[ra0 * 64 + (kb ^ ((ra0 & 7) << 3))];
            short8v a1 = *(const short8v*)&As[ra1 * 64 + (kb ^ ((ra1 & 7) << 3))];
            const int rb0 = wpx + lm, rb1 = wpx + 16 + lm;
            const int rb2 = wpx + 32 + lm, rb3 = wpx + 48 + lm;
            short8v b0 = *(const short8v*)&Bs[rb0 * 64 + (kb ^ ((rb0 & 7) << 3))];
            short8v b1 = *(const short8v*)&Bs[rb1 * 64 + (kb ^ ((rb1 & 7) << 3))];
            short8v b2 = *(const short8v*)&Bs[rb2 * 64 + (kb ^ ((rb2 & 7) << 3))];
            short8v b3 = *(const short8v*)&Bs[rb3 * 64 + (kb ^ ((rb3 & 7) << 3))];
            acc[0][0] = __builtin_amdgcn_mfma_f32_16x16x32_bf16(a0, b0, acc[0][0], 0, 0, 0);
            acc[0][1] = __builtin_amdgcn_mfma_f32_16x16x32_bf16(a0, b1, acc[0][1], 0, 0, 0);
            acc[0][2] = __builtin_amdgcn_mfma_f32_16x16x32_bf16(a0, b2, acc[0][2], 0, 0, 0);
            acc[0][3] = __builtin_amdgcn_mfma_f32_16x16x32_bf16(a0, b3, acc[0][3], 0, 0, 0);
            acc[1][0] = __builtin_amdgcn_mfma_f32_16x16x32_bf16(a1, b0, acc[1][0], 0, 0, 0);
            acc[1][1] = __builtin_amdgcn_mfma_f32_16x16x32_bf16(a1, b1, acc[1][1], 0, 0, 0);
            acc[1][2] = __builtin_amdgcn_mfma_f32_16x16x32_bf16(a1, b2, acc[1][2], 0, 0, 0);
            acc[1][3] = __builtin_amdgcn_mfma_f32_16x16x32_bf16(a1, b3, acc[1][3], 0, 0, 0);
        }
        __syncthreads();
    }
    if (pacc) {
        float* pbuf = pacc + ((long long)blockIdx.z * N) * Co;
#pragma unroll
        for (int nb = 0; nb < 4; ++nb) {
            int np = n0 + wpx + nb * 16 + lm;
            if (np >= N) continue;
#pragma unroll
            for (int amr = 0; amr < 2; ++amr) {
                int cobase = m0 + wco + amr * 16 + lk * 4;
                float4 vv = make_float4(acc[amr][nb][0], acc[amr][nb][1],
                                        acc[amr][nb][2], acc[amr][nb][3]);
                *(float4*)&pbuf[(long long)np * Co + cobase] = vv;
            }
        }
    } else {
        float ssum[2][4] = {}, ssq[2][4] = {};
#pragma unroll
        for (int nb = 0; nb < 4; ++nb) {
            int np = n0 + wpx + nb * 16 + lm;
            bool val = (np < N);
#pragma unroll
            for (int amr = 0; amr < 2; ++amr) {
                int cobase = m0 + wco + amr * 16 + lk * 4;
                float4 eb = *(const float4*)&effb[cobase];
                float v0 = fmaxf(acc[amr][nb][0] + eb.x, 0.f);
                float v1 = fmaxf(acc[amr][nb][1] + eb.y, 0.f);
                float v2 = fmaxf(acc[amr][nb][2] + eb.z, 0.f);
                float v3 = fmaxf(acc[amr][nb][3] + eb.w, 0.f);
                if (val) {
                    ushort4 u;
                    u.x = f2bf(v0); u.y = f2bf(v1); u.z = f2bf(v2); u.w = f2bf(v3);
                    *(ushort4*)&out[(long long)np * Co + cobase] = u;
                    ssum[amr][0] += v0; ssq[amr][0] = fmaf(v0, v0, ssq[amr][0]);
                    ssum[amr][1] += v1; ssq[amr][1] = fmaf(v1, v1, ssq[amr][1]);
                    ssum[amr][2] += v2; ssq[amr][2] = fmaf(v2, v2, ssq[amr][2]);
                    ssum[amr][3] += v3; ssq[amr][3] = fmaf(v3, v3, ssq[amr][3]);
                }
            }
        }
#pragma unroll
        for (int mm = 1; mm < 16; mm <<= 1) {
#pragma unroll
            for (int amr = 0; amr < 2; ++amr)
#pragma unroll
                for (int r = 0; r < 4; ++r) {
                    ssum[amr][r] += __shfl_xor(ssum[amr][r], mm, 64);
                    ssq[amr][r] += __shfl_xor(ssq[amr][r], mm, 64);
                }
        }
        __shared__ float lss[4][32], lsq[4][32];
        if (lm == 0) {
#pragma unroll
            for (int amr = 0; amr < 2; ++amr)
#pragma unroll
                for (int r = 0; r < 4; ++r) {
                    lss[w][amr * 16 + lk * 4 + r] = ssum[amr][r];
                    lsq[w][amr * 16 + lk * 4 + r] = ssq[amr][r];
                }
        }
        __syncthreads();
        if (tid < 64) {
            int half = tid >> 5, c32 = tid & 31;
            float s = lss[half * 2][c32] + lss[half * 2 + 1][c32];
            float q = lsq[half * 2][c32] + lsq[half * 2 + 1][c32];
            int c = m0 + half * 32 + c32;
            spart[((long long)c * Spart + blockIdx.x) * 2 + 0] = s;
            spart[((long long)c * Spart + blockIdx.x) * 2 + 1] = q;
        }
    }
}

// ---- K-split reduce + bias + relu + stats partials (l5), grid-stride -------
__global__ __launch_bounds__(256) void convz_stats(
    const float* __restrict__ pacc, const float* __restrict__ effb,
    ushort_t* __restrict__ out, float* __restrict__ part,
    long long total, int Co, int Z) {
    const int tid = threadIdx.x;
    const int c0 = (tid * 8) & (Co - 1);
    float eb[8];
    {
        float4 e0 = *(const float4*)&effb[c0];
        float4 e1 = *(const float4*)&effb[c0 + 4];
        eb[0] = e0.x; eb[1] = e0.y; eb[2] = e0.z; eb[3] = e0.w;
        eb[4] = e1.x; eb[5] = e1.y; eb[6] = e1.z; eb[7] = e1.w;
    }
    float sum[8] = {}, sq[8] = {};
    const long long nchunk = total >> 11;
    for (long long g = blockIdx.x; g < nchunk; g += 512) {
        long long off = (g << 11) + tid * 8;
        float v[8];
#pragma unroll
        for (int j = 0; j < 8; ++j) v[j] = eb[j];
        for (int z = 0; z < Z; ++z) {
            const float* pz = pacc + (long long)z * total + off;
            float4 a = *(const float4*)pz;
            float4 b2 = *(const float4*)(pz + 4);
            v[0] += a.x; v[1] += a.y; v[2] += a.z; v[3] += a.w;
            v[4] += b2.x; v[5] += b2.y; v[6] += b2.z; v[7] += b2.w;
        }
        short8v o;
#pragma unroll
        for (int j = 0; j < 8; ++j) {
            float r = fmaxf(v[j], 0.f);
            o[j] = (short)f2bf(r);
            sum[j] += r;
            sq[j] = fmaf(r, r, sq[j]);
        }
        *(short8v*)&out[off] = o;
    }
    __shared__ float rs[256][8], rq[256][8];
#pragma unroll
    for (int j = 0; j < 8; ++j) { rs[tid][j] = sum[j]; rq[tid][j] = sq[j]; }
    __syncthreads();
    const int G = Co >> 3;
    const int TPG = 256 / G;
    for (int c = tid; c < Co; c += 256) {
        int grp = c >> 3, j = c & 7;
        float s = 0.f, q = 0.f;
        for (int i = 0; i < TPG; ++i) {
            s += rs[grp + i * G][j];
            q += rq[grp + i * G][j];
        }
        part[(c * 512 + blockIdx.x) * 2 + 0] = s;
        part[(c * 512 + blockIdx.x) * 2 + 1] = q;
    }
}

// wave-parallel stats finalize
__global__ __launch_bounds__(256) void stats_final_w(
    const float* __restrict__ part, const float* __restrict__ g,
    const float* __restrict__ be, float* __restrict__ scale,
    float* __restrict__ shift, int C, int S, float invN) {
    int c = blockIdx.x * 4 + (threadIdx.x >> 6);
    int lane = threadIdx.x & 63;
    if (c >= C) return;
    float s = 0.f, q = 0.f;
    for (int i = lane; i < S; i += 64) {
        s += part[((long long)c * S + i) * 2 + 0];
        q += part[((long long)c * S + i) * 2 + 1];
    }
#pragma unroll
    for (int off = 32; off > 0; off >>= 1) {
        s += __shfl_down(s, off, 64);
        q += __shfl_down(q, off, 64);
    }
    if (lane == 0) {
        float m = s * invN;
        float v = q * invN - m * m;
        float inv = rsqrtf(v + BEPS);
        float sc = g[c] * inv;
        scale[c] = sc;
        shift[c] = be[c] - m * sc;
    }
}

// ---------------- fused BN fold: weights (grid head) + bias (grid tail) -----
__global__ __launch_bounds__(256) void fold_fused(
    const float* __restrict__ w, const float* __restrict__ scale,
    const float* __restrict__ shift, const float* __restrict__ bias,
    ushort_t* __restrict__ wout, float* __restrict__ effb,
    int Ci, int lgCi, int K, int Kp, int Co, int WB) {
    if ((int)blockIdx.x < WB) {
        int idx = blockIdx.x * 256 + threadIdx.x;
        if (idx >= Co * Kp) return;
        int co = idx / Kp, k = idx - co * Kp;
        ushort_t o = 0;
        if (k < K) {
            int tap = k >> lgCi;
            int ci = k & (Ci - 1);
            o = f2bf(w[((long long)co * Ci + ci) * 9 + tap] * scale[ci]);
        }
        wout[idx] = o;
    } else {
        int co = ((int)blockIdx.x - WB) * 4 + (threadIdx.x >> 6);
        int lane = threadIdx.x & 63;
        if (co >= Co) return;
        const int CK = Ci * 9;
        const float* wr = w + (long long)co * CK;
        float acc = 0.f;
        for (int k = lane; k < CK; k += 64) acc = fmaf(wr[k], shift[k / 9], acc);
#pragma unroll
        for (int off = 32; off > 0; off >>= 1) acc += __shfl_down(acc, off, 64);
        if (lane == 0) effb[co] = acc + bias[co];
    }
}

// ---------------- BN apply conv5 NHWC out -> xB bf16 [32][25088] ------------
__global__ void bn_apply_x(const ushort_t* __restrict__ y, const float* __restrict__ scale,
                           const float* __restrict__ shift, ushort_t* __restrict__ xB) {
    int idx = blockIdx.x * blockDim.x + threadIdx.x;
    if (idx >= 802816) return;
    int b = idx / 25088, k = idx - b * 25088;
    int c = k / 49, p = k - c * 49;
    float v = bf2f(y[((long long)b * 49 + p) * 512 + c]);
    xB[idx] = f2bf(fmaf(v, scale[c], shift[c]));
}

// ---------------- fc1 split-K MFMA GEMM (W fp32 -> bf16 inline) -------------
__global__ __launch_bounds__(256) void fc1_mfma(
    const float* __restrict__ w, const ushort_t* __restrict__ xB,
    float* __restrict__ part) {
    const int K = 25088;
    __shared__ __align__(16) ushort_t As[64 * 256];
    __shared__ __align__(16) ushort_t Bs[32 * 256];
    const int tid = threadIdx.x;
    const int m0 = blockIdx.y * 64;
    const int kbeg = blockIdx.x * FC1_KC;

    {
        const int r = tid >> 2;
        const int kq = (tid & 3) * 64;
        const int m = m0 + r;
        const bool mv = (m < 1000);
        const float* wr = w + (long long)m * K + kbeg + kq;
        const int sw = (r & 7) << 3;
#pragma unroll
        for (int g = 0; g < 8; ++g) {
            short8v o = {0, 0, 0, 0, 0, 0, 0, 0};
            if (mv) {
                float4 f0 = *(const float4*)(wr + g * 8);
                float4 f1 = *(const float4*)(wr + g * 8 + 4);
                o[0] = (short)f2bf(f0.x); o[1] = (short)f2bf(f0.y);
                o[2] = (short)f2bf(f0.z); o[3] = (short)f2bf(f0.w);
                o[4] = (short)f2bf(f1.x); o[5] = (short)f2bf(f1.y);
                o[6] = (short)f2bf(f1.z); o[7] = (short)f2bf(f1.w);
            }
            *(short8v*)&As[r * 256 + ((kq + g * 8) ^ sw)] = o;
        }
    }
    {
        const int b = tid >> 3;
        const int kq = (tid & 7) * 32;
        const ushort_t* xr = xB + (long long)b * K + kbeg + kq;
        const int sw = (b & 7) << 3;
#pragma unroll
        for (int g = 0; g < 4; ++g) {
            short8v v = *(const short8v*)(xr + g * 8);
            *(short8v*)&Bs[b * 256 + ((kq + g * 8) ^ sw)] = v;
        }
    }
    __syncthreads();
    const int wv = tid >> 6, lane = tid & 63;
    const int lm = lane & 15, lk = lane >> 4;
    const int wm = wv * 16;
    f32x4 acc0 = {}, acc1 = {};
    const int ra = wm + lm;
    const int swa = (ra & 7) << 3;
    const int swb = (lm & 7) << 3;
#pragma unroll
    for (int s = 0; s < 8; ++s) {
        int kb = s * 32 + lk * 8;
        short8v av = *(const short8v*)&As[ra * 256 + (kb ^ swa)];
        short8v b0 = *(const short8v*)&Bs[lm * 256 + (kb ^ swb)];
        short8v b1 = *(const short8v*)&Bs[(16 + lm) * 256 + (kb ^ swb)];
        acc0 = __builtin_amdgcn_mfma_f32_16x16x32_bf16(av, b0, acc0, 0, 0, 0);
        acc1 = __builtin_amdgcn_mfma_f32_16x16x32_bf16(av, b1, acc1, 0, 0, 0);
    }
    float* pb = part + ((long long)blockIdx.y * FC1_KS + blockIdx.x) * 2048;
#pragma unroll
    for (int r = 0; r < 4; ++r) {
        pb[(wm + lk * 4 + r) * 32 + lm] = acc0[r];
        pb[(wm + lk * 4 + r) * 32 + 16 + lm] = acc1[r];
    }
}

__global__ void fc1_reduce(const float* __restrict__ part, const float* __restrict__ bias,
                           float* __restrict__ z) {
    int idx = blockIdx.x * blockDim.x + threadIdx.x;
    if (idx >= 32000) return;
    int o = idx >> 5, b = idx & 31;
    int mt = o >> 6, mr = o & 63;
    const float* p = part + ((long long)mt * FC1_KS) * 2048 + mr * 32 + b;
    float s0 = 0.f, s1 = 0.f;
    int ks = 0;
    for (; ks + 1 < FC1_KS; ks += 2) {
        s0 += p[(long long)ks * 2048];
        s1 += p[(long long)(ks + 1) * 2048];
    }
    for (; ks < FC1_KS; ++ks) s0 += p[(long long)ks * 2048];
    z[b * 1000 + o] = fmaxf(s0 + s1 + bias[o], 0.f);
}

// ---------------- fc2 -------------------------------------------------------
__global__ __launch_bounds__(256) void fc2_v2(const float* __restrict__ z,
                                              const float* __restrict__ w,
                                              const float* __restrict__ bias,
                                              float* __restrict__ ys) {
    int gid = blockIdx.x * 4 + (threadIdx.x >> 6);
    int lane = threadIdx.x & 63;
    if (gid >= 960) return;
    int b = gid / 30, o = gid - b * 30;
    const float* zr = z + (long long)b * 1000;
    const float* wr = w + (long long)o * 1000;
    float acc = 0.f;
    for (int k = lane; k < 1000; k += 64) acc = fmaf(zr[k], wr[k], acc);
    for (int off = 32; off > 0; off >>= 1) acc += __shfl_down(acc, off, 64);
    if (lane == 0) ys[gid] = acc + bias[o];
}

// ---------------- spline eval: inline coef compute + image + table ----------
__global__ __launch_bounds__(256) void eval_all(
    const float4* __restrict__ batch4, const float* __restrict__ ysraw,
    const float* __restrict__ matrix, float4* __restrict__ out4,
    float* __restrict__ outt) {
    __shared__ float mat[100];
    __shared__ float4 coefs[864];
    const int tid = threadIdx.x;
    const float h = 1.0f / 9.0f;
    if (tid < 100) mat[tid] = matrix[tid];
    __syncthreads();
    if (tid < 96) {
        int b = tid / 3, ch = tid - b * 3;
        float ya[10];
#pragma unroll
        for (int j = 0; j < 10; ++j)
            ya[j] = ysraw[b * 30 + ch * 10 + j] / 100.0f + (float)j / 9.0f;
        float M[10];
#pragma unroll
        for (int i = 0; i < 10; ++i) {
            float acc = 0.f;
#pragma unroll
            for (int j = 0; j < 10; ++j) acc = fmaf(mat[i * 10 + j], ya[j], acc);
            M[i] = acc;
        }
#pragma unroll
        for (int k = 0; k < 9; ++k) {
            float a = (M[k + 1] - M[k]) / (6.0f * h);
            float bb = M[k] * 0.5f;
            float cc = (ya[k + 1] - ya[k]) / h - (M[k + 1] + 2.0f * M[k]) * (h / 6.0f);
            float dd = ya[k];
            coefs[tid * 9 + k] = make_float4(a, bb, cc, dd);
        }
    }
    __syncthreads();
    int idx = blockIdx.x * 256 + tid;
    if (idx < 1572864) {
        int plane = idx >> 14;
        float4 xv4 = batch4[idx];
        float xin[4] = {xv4.x, xv4.y, xv4.z, xv4.w};
        float xout[4];
#pragma unroll
        for (int e = 0; e < 4; ++e) {
            float xv = xin[e];
            int xi = (int)floorf(xv / h);
            xi = min(max(xi, 0), 8);
            float xf = xv - (float)xi * h;
            float4 cf = coefs[plane * 9 + xi];
            xout[e] = fmaf(fmaf(fmaf(cf.x, xf, cf.y), xf, cf.z), xf, cf.w);
        }
        out4[idx] = make_float4(xout[0], xout[1], xout[2], xout[3]);
    } else {
        int t = idx - 1572864;
        if (t < 96 * 255) {
            int plane = t / 255;
            int j = t - plane * 255;
            float xv = (float)j / 255.0f;
            int xi = (int)floorf(xv / h);
            xi = min(max(xi, 0), 8);
            float xf = xv - (float)xi * h;
            float4 cf = coefs[plane * 9 + xi];
            outt[t] = fmaf(fmaf(fmaf(cf.x, xf, cf.y), xf, cf.z), xf, cf.w);
        }
    }
}

extern "C" void kernel_launch(void* const* d_in, const int* in_sizes, int n_in,
                              void* d_out, int out_size, void* d_ws, size_t ws_size,
                              hipStream_t stream) {
    const int B = 32;
    const float* batch = (const float*)d_in[0];
    const float* cw[5] = {(const float*)d_in[1], (const float*)d_in[5], (const float*)d_in[9],
                          (const float*)d_in[13], (const float*)d_in[17]};
    const float* cb[5] = {(const float*)d_in[2], (const float*)d_in[6], (const float*)d_in[10],
                          (const float*)d_in[14], (const float*)d_in[18]};
    const float* bg[5] = {(const float*)d_in[3], (const float*)d_in[7], (const float*)d_in[11],
                          (const float*)d_in[15], (const float*)d_in[19]};
    const float* bb[5] = {(const float*)d_in[4], (const float*)d_in[8], (const float*)d_in[12],
                          (const float*)d_in[16], (const float*)d_in[20]};
    const float* l1w = (const float*)d_in[21];
    const float* l1b = (const float*)d_in[22];
    const float* l2w = (const float*)d_in[23];
    const float* l2b = (const float*)d_in[24];
    const float* matrix = (const float*)d_in[25];

    float* f = (float*)d_ws;
    const size_t A_F = 8258048;
    const size_t Bq_F = 4064256;
    const size_t W_F = 589824;
    ushort_t* bufA = (ushort_t*)f;
    ushort_t* bufB = (ushort_t*)(f + A_F);
    ushort_t* Wf_bf = (ushort_t*)(f + A_F + Bq_F);
    float* effb  = f + A_F + Bq_F + W_F;   // 512
    float* scale = effb + 512;             // 512
    float* shift = scale + 512;            // 512
    float* part  = shift + 512;            // 524,288
    float* x5    = part + 524288;          // 802,816 (bf16 xB)
    float* pacc  = x5 + 802816;            // 3,686,400
    float* z1    = pacc + 3686400;         // 32,000
    float* ysb   = z1 + 32000;             // 960

    const int Ci[5]   = {3, 32, 64, 128, 256};
    const int lgCi[5] = {0, 5, 6, 7, 8};
    const int Co[5]   = {32, 64, 128, 256, 512};
    const int Hi[5]   = {256, 127, 63, 31, 15};
    const int Ho[5]   = {127, 63, 31, 15, 7};
    const int Zl[5]   = {1, 1, 1, 1, 3};

    ushort_t* bufs[2] = {bufA, bufB};

    // layer 1: conv + fused stats partials
    conv1_direct<<<C1NB, 256, 0, stream>>>(batch, cw[0], cb[0], bufA, part);
    stats_final_w<<<8, 256, 0, stream>>>(part, bg[0], bb[0], scale, shift, 32, C1NB,
                                         1.0f / (float)(B * 16129));

    // layers 2..5
    const ushort_t* cur = bufA;
    for (int l = 1; l < 5; ++l) {
        ushort_t* outb = bufs[l % 2];
        int K = Ci[l] * 9;
        int Kp = (K + 63) & ~63;
        int WB = (Co[l] * Kp + 255) / 256;
        int BBk = (Co[l] + 3) / 4;
        fold_fused<<<WB + BBk, 256, 0, stream>>>(cw[l], scale, shift, cb[l], Wf_bf, effb,
                                                 Ci[l], lgCi[l], K, Kp, Co[l], WB);
        int N = B * Ho[l] * Ho[l];
        int Z = Zl[l];
        int kcount = Kp / Z;
        if (l <= 2) {
            // wide tile: 64co x 256px, 512 threads, fused stats
            dim3 grid((N + 255) / 256, Co[l] / 64, 1);
            conv_mfma512<<<grid, 512, 0, stream>>>(cur, Wf_bf, effb, outb, part,
                                                   B, Ci[l], lgCi[l], Hi[l], Hi[l], Co[l],
                                                   Ho[l], Ho[l], K, Kp, Kp, grid.x);
            stats_final_w<<<(Co[l] + 3) / 4, 256, 0, stream>>>(
                part, bg[l], bb[l], scale, shift, Co[l], grid.x, 1.0f / (float)N);
        } else if (Z == 1) {
            dim3 grid((N + 127) / 128, Co[l] / 64, 1);
            conv_mfma<<<grid, 256, 0, stream>>>(cur, Wf_bf, effb, outb, nullptr, part,
                                                B, Ci[l], lgCi[l], Hi[l], Hi[l], Co[l],
                                                Ho[l], Ho[l], K, Kp, kcount, grid.x);
            stats_final_w<<<(Co[l] + 3) / 4, 256, 0, stream>>>(
                part, bg[l], bb[l], scale, shift, Co[l], grid.x, 1.0f / (float)N);
        } else {
            dim3 grid((N + 127) / 128, Co[l] / 64, Z);
            conv_mfma<<<grid, 256, 0, stream>>>(cur, Wf_bf, effb, nullptr, pacc, nullptr,
                                                B, Ci[l], lgCi[l], Hi[l], Hi[l], Co[l],
                                                Ho[l], Ho[l], K, Kp, kcount, 0);
            long long total = (long long)N * Co[l];
            convz_stats<<<512, 256, 0, stream>>>(pacc, effb, outb, part, total, Co[l], Z);
            stats_final_w<<<(Co[l] + 3) / 4, 256, 0, stream>>>(
                part, bg[l], bb[l], scale, shift, Co[l], 512, 1.0f / (float)N);
        }
        cur = outb;
    }

    ushort_t* xB = (ushort_t*)x5;
    bn_apply_x<<<(802816 + 255) / 256, 256, 0, stream>>>(cur, scale, shift, xB);
    {
        dim3 grid(FC1_KS, 16);
        fc1_mfma<<<grid, 256, 0, stream>>>(l1w, xB, pacc);
    }
    fc1_reduce<<<(32000 + 255) / 256, 256, 0, stream>>>(pacc, l1b, z1);
    fc2_v2<<<240, 256, 0, stream>>>(z1, l2w, l2b, ysb);

    float* out = (float*)d_out;
    int evtot = 1572864 + 96 * 255;
    eval_all<<<(evtot + 255) / 256, 256, 0, stream>>>((const float4*)batch, ysb, matrix,
                                                      (float4*)out, out + 6291456);
}